// Round 1
// baseline (1062.041 us; speedup 1.0000x reference)
//
#include <hip/hip_runtime.h>
#include <math.h>

constexpr int B = 8, C = 128, H = 64, W = 64;
constexpr int NWIN = 8, HEADS = 8, QKDIM = 128, KVPW = 4, TOPK = 16;
constexpr int P2 = NWIN * NWIN;   // 64 windows
constexpr float SCALE = 0.0883883476483184405f; // 128^-0.5

// workspace offsets (in floats)
constexpr size_t NPIX   = (size_t)B * H * W;            // 32768
constexpr size_t OFF_T1C = 0;                            // NHWC (B,H,W,128)
constexpr size_t OFF_T2C = OFF_T1C + NPIX * 128;
constexpr size_t OFF_X   = OFF_T2C + NPIX * 128;         // relu(LN(catconv))
constexpr size_t OFF_Q   = OFF_X   + NPIX * 128;         // q  (B,H,W,128)
constexpr size_t OFF_KV  = OFF_Q   + NPIX * 128;         // kv (B,H,W,256)
constexpr size_t OFF_KVP = OFF_KV  + NPIX * 256;         // kv_pix (B,64,16,256)
constexpr size_t OFF_QW  = OFF_KVP + (size_t)B * P2 * 16 * 256;
constexpr size_t OFF_KW  = OFF_QW  + (size_t)B * P2 * 128;
constexpr size_t OFF_RIDX= OFF_KW  + (size_t)B * P2 * 128;      // int
constexpr size_t OFF_WCT = OFF_RIDX+ (size_t)B * P2 * TOPK;     // catW^T [9*256][128]
constexpr size_t OFF_QKVT= OFF_WCT + (size_t)9 * 256 * 128;     // [128][384]
constexpr size_t OFF_WOT = OFF_QKVT+ (size_t)128 * 384;         // [128][128]
constexpr size_t OFF_O   = OFF_T1C;  // alias: attention output reuses t1c

// ---------------------------------------------------------------- transpose
__global__ void transpose_weights(const float* __restrict__ qkv_w,
                                  const float* __restrict__ wo_w,
                                  const float* __restrict__ cat_w,
                                  float* __restrict__ qkvT,
                                  float* __restrict__ woT,
                                  float* __restrict__ wcatT) {
    int idx = blockIdx.x * 256 + threadIdx.x;
    if (idx < 128 * 384) {           // qkvT[k][n] = qkv_w[n][k]
        int k = idx / 384, n = idx % 384;
        qkvT[idx] = qkv_w[n * 128 + k];
    }
    if (idx < 128 * 128) {           // woT[k][n] = wo_w[n][k]
        int k = idx / 128, n = idx % 128;
        woT[idx] = wo_w[n * 128 + k];
    }
    if (idx < 2304 * 128) {          // wcatT[(dd*256+ci)][co]
        int co = idx & 127;
        int r  = idx >> 7;
        int ci = r & 255;
        int dd = r >> 8;             // dy*3+dx
        wcatT[idx] = cat_w[(co * 256 + ci) * 9 + dd];
    }
}

// --------------------------------------- depthwise 3x3 + residual, NCHW->NHWC
__global__ __launch_bounds__(256) void pos_conv_k(const float* __restrict__ in,
                                                  const float* __restrict__ w,
                                                  const float* __restrict__ bias,
                                                  float* __restrict__ outNHWC) {
    __shared__ float tile[32][33];
    int b = blockIdx.z / H, y = blockIdx.z % H;
    int c0 = blockIdx.y * 32, x0 = blockIdx.x * 32;
    int tx = threadIdx.x & 31, tg = threadIdx.x >> 5;   // 8 groups
    for (int i = 0; i < 4; i++) {
        int cl = tg * 4 + i, c = c0 + cl;
        const float* base = in + (size_t)(b * C + c) * H * W;
        float acc = base[y * W + x0 + tx];              // residual (center)
        float wv[9];
#pragma unroll
        for (int j = 0; j < 9; j++) wv[j] = w[c * 9 + j];
#pragma unroll
        for (int dy = 0; dy < 3; dy++) {
            int yy = y + dy - 1;
            if (yy < 0 || yy >= H) continue;
#pragma unroll
            for (int dx = 0; dx < 3; dx++) {
                int xx = x0 + tx + dx - 1;
                if (xx < 0 || xx >= W) continue;
                acc += base[yy * W + xx] * wv[dy * 3 + dx];
            }
        }
        tile[cl][tx] = acc + bias[c];
    }
    __syncthreads();
    for (int i = 0; i < 4; i++) {
        int xl = tg * 4 + i;
        outNHWC[((size_t)(b * H + y) * W + x0 + xl) * 128 + c0 + tx] = tile[tx][xl];
    }
}

// ---------------------------- cat-conv 256->128 3x3 + LayerNorm(1e-5) + ReLU
__global__ __launch_bounds__(128) void catconv_ln_k(const float* __restrict__ t1c,
                                                    const float* __restrict__ t2c,
                                                    const float* __restrict__ wcatT,
                                                    const float* __restrict__ cat_b,
                                                    const float* __restrict__ g,
                                                    const float* __restrict__ beta,
                                                    float* __restrict__ xbuf) {
    __shared__ float tile[3][10][256];
    __shared__ float res[8][128];
    int b = blockIdx.z, y = blockIdx.y, x0 = blockIdx.x * 8;
    int t = threadIdx.x;
    for (int e = t; e < 3 * 10 * 256; e += 128) {
        int c = e & 255, xi = (e >> 8) % 10, r = e / 2560;
        int yy = y + r - 1, xx = x0 + xi - 1;
        float v = 0.f;
        if (yy >= 0 && yy < H && xx >= 0 && xx < W) {
            size_t pix = (size_t)(b * H + yy) * W + xx;
            v = (c < 128) ? t1c[pix * 128 + c] : t2c[pix * 128 + (c - 128)];
        }
        tile[r][xi][c] = v;
    }
    __syncthreads();
    float acc[8];
#pragma unroll
    for (int p = 0; p < 8; p++) acc[p] = 0.f;
    for (int dy = 0; dy < 3; dy++) {
        for (int ci = 0; ci < 256; ci++) {
            float tv[10];
#pragma unroll
            for (int q = 0; q < 10; q++) tv[q] = tile[dy][q][ci];
            float w0 = wcatT[((dy * 3 + 0) * 256 + ci) * 128 + t];
            float w1 = wcatT[((dy * 3 + 1) * 256 + ci) * 128 + t];
            float w2 = wcatT[((dy * 3 + 2) * 256 + ci) * 128 + t];
#pragma unroll
            for (int p = 0; p < 8; p++)
                acc[p] += tv[p] * w0 + tv[p + 1] * w1 + tv[p + 2] * w2;
        }
    }
    float cb = cat_b[t];
#pragma unroll
    for (int p = 0; p < 8; p++) res[p][t] = acc[p] + cb;
    __syncthreads();
    int lane = t & 63, wvi = t >> 6;
    for (int p = wvi * 4; p < wvi * 4 + 4; p++) {
        float v0 = res[p][lane], v1 = res[p][lane + 64];
        float s = v0 + v1;
#pragma unroll
        for (int m = 32; m > 0; m >>= 1) s += __shfl_xor(s, m, 64);
        float mean = s * (1.f / 128.f);
        float d0 = v0 - mean, d1 = v1 - mean;
        float vs = d0 * d0 + d1 * d1;
#pragma unroll
        for (int m = 32; m > 0; m >>= 1) vs += __shfl_xor(vs, m, 64);
        float inv = rsqrtf(vs * (1.f / 128.f) + 1e-5f);
        size_t pix = (size_t)(b * H + y) * W + x0 + p;
        float o0 = d0 * inv * g[lane] + beta[lane];
        float o1 = d1 * inv * g[lane + 64] + beta[lane + 64];
        xbuf[pix * 128 + lane] = fmaxf(o0, 0.f);
        xbuf[pix * 128 + lane + 64] = fmaxf(o1, 0.f);
    }
}

// ------------------------------------------- LayerNorm(1e-6) + projection
__global__ __launch_bounds__(128) void ln_gemm_k(const float* __restrict__ in,
                                                 const float* __restrict__ g,
                                                 const float* __restrict__ beta,
                                                 float eps,
                                                 const float* __restrict__ wT, // [128][384]
                                                 int colOff,
                                                 const float* __restrict__ bias,
                                                 float* __restrict__ out, int outStride) {
    __shared__ float a[8][128];
    int t = threadIdx.x;
    size_t p0 = (size_t)blockIdx.x * 8;
    for (int p = 0; p < 8; p++) a[p][t] = in[(p0 + p) * 128 + t];
    __syncthreads();
    int lane = t & 63, wvi = t >> 6;
    for (int p = wvi * 4; p < wvi * 4 + 4; p++) {
        float v0 = a[p][lane], v1 = a[p][lane + 64];
        float s = v0 + v1;
#pragma unroll
        for (int m = 32; m > 0; m >>= 1) s += __shfl_xor(s, m, 64);
        float mean = s * (1.f / 128.f);
        float d0 = v0 - mean, d1 = v1 - mean;
        float vs = d0 * d0 + d1 * d1;
#pragma unroll
        for (int m = 32; m > 0; m >>= 1) vs += __shfl_xor(vs, m, 64);
        float inv = rsqrtf(vs * (1.f / 128.f) + eps);
        a[p][lane]      = d0 * inv * g[lane] + beta[lane];
        a[p][lane + 64] = d1 * inv * g[lane + 64] + beta[lane + 64];
    }
    __syncthreads();
    int col = colOff + blockIdx.y * 128 + t;
    float acc[8];
#pragma unroll
    for (int p = 0; p < 8; p++) acc[p] = 0.f;
    for (int k = 0; k < 128; k += 4) {
        float w0 = wT[(k + 0) * 384 + col];
        float w1 = wT[(k + 1) * 384 + col];
        float w2 = wT[(k + 2) * 384 + col];
        float w3 = wT[(k + 3) * 384 + col];
#pragma unroll
        for (int p = 0; p < 8; p++) {
            const float4 av = *reinterpret_cast<const float4*>(&a[p][k]);
            acc[p] += av.x * w0 + av.y * w1 + av.z * w2 + av.w * w3;
        }
    }
    float bv = bias[col];
    int oc = blockIdx.y * 128 + t;
    for (int p = 0; p < 8; p++) out[(p0 + p) * outStride + oc] = acc[p] + bv;
}

// --------------------------------------------- window pooling (kv_pix, means)
__global__ __launch_bounds__(256) void pool_k(const float* __restrict__ q,
                                              const float* __restrict__ kv,
                                              float* __restrict__ kv_pix,
                                              float* __restrict__ q_win,
                                              float* __restrict__ k_win) {
    int b = blockIdx.y, wdw = blockIdx.x;
    int wi = wdw >> 3, wj = wdw & 7;
    int t = threadIdx.x;
    float tot = 0.f;
    for (int ry = 0; ry < 4; ry++)
        for (int rx = 0; rx < 4; rx++) {
            float s = 0.f;
            for (int fy = 0; fy < 2; fy++)
                for (int fx = 0; fx < 2; fx++) {
                    int y = wi * 8 + ry * 2 + fy, x = wj * 8 + rx * 2 + fx;
                    s += kv[((size_t)(b * H + y) * W + x) * 256 + t];
                }
            kv_pix[((size_t)(b * 64 + wdw) * 16 + ry * 4 + rx) * 256 + t] = s * 0.25f;
            tot += s;
        }
    if (t < 128) {
        k_win[(size_t)(b * 64 + wdw) * 128 + t] = tot * (1.f / 64.f);
        float qs = 0.f;
        for (int iy = 0; iy < 8; iy++)
            for (int ix = 0; ix < 8; ix++) {
                int y = wi * 8 + iy, x = wj * 8 + ix;
                qs += q[((size_t)(b * H + y) * W + x) * 128 + t];
            }
        q_win[(size_t)(b * 64 + wdw) * 128 + t] = qs * (1.f / 64.f);
    }
}

// ------------------------------------------------ routing logits + top-16
__global__ __launch_bounds__(64) void route_k(const float* __restrict__ q_win,
                                              const float* __restrict__ k_win,
                                              int* __restrict__ r_idx) {
    int b = blockIdx.y, p = blockIdx.x, j = threadIdx.x;
    const float* qp = q_win + (size_t)(b * 64 + p) * 128;
    const float* kp = k_win + (size_t)(b * 64 + j) * 128;
    float lg = 0.f;
    for (int c = 0; c < 128; c++) lg += qp[c] * kp[c];
    lg *= SCALE;
    for (int it = 0; it < TOPK; it++) {
        float v = lg; int idx = j;
#pragma unroll
        for (int m = 32; m > 0; m >>= 1) {
            float ov = __shfl_xor(v, m, 64);
            int   oi = __shfl_xor(idx, m, 64);
            if (ov > v || (ov == v && oi < idx)) { v = ov; idx = oi; }
        }
        if (j == 0) r_idx[(size_t)(b * 64 + p) * TOPK + it] = idx;
        if (j == idx) lg = -__builtin_inff();
    }
}

// -------------------------------------------------------- routed attention
__global__ __launch_bounds__(256) void attn_k(const float* __restrict__ q,
                                              const float* __restrict__ kv_pix,
                                              const int* __restrict__ r_idx,
                                              float* __restrict__ o) {
    __shared__ float Kh[256][20];
    __shared__ float Vh[256][20];
    __shared__ float part[4][64][20];
    __shared__ float rmax[4][64], rsum[4][64];
    __shared__ int ridx[16];
    int b = blockIdx.y, p = blockIdx.x;
    int wi = p >> 3, wj = p & 7;
    int t = threadIdx.x;
    int lane = t & 63, wv = t >> 6;
    if (t < 16) ridx[t] = r_idx[(size_t)(b * 64 + p) * TOPK + t];
    __syncthreads();
    int region = ridx[t >> 4], pos = t & 15;
    size_t kvbase = ((size_t)((b * 64 + region) * 16) + pos) * 256;
    int qy = wi * 8 + (lane >> 3), qx = wj * 8 + (lane & 7);
    size_t qpix = ((size_t)(b * H + qy) * W + qx) * 128;

    for (int m = 0; m < HEADS; m++) {
        __syncthreads();
#pragma unroll
        for (int d = 0; d < 16; d += 4) {
            *reinterpret_cast<float4*>(&Kh[t][d]) =
                *reinterpret_cast<const float4*>(&kv_pix[kvbase + m * 16 + d]);
            *reinterpret_cast<float4*>(&Vh[t][d]) =
                *reinterpret_cast<const float4*>(&kv_pix[kvbase + 128 + m * 16 + d]);
        }
        float qreg[16];
#pragma unroll
        for (int d = 0; d < 16; d += 4) {
            float4 qv = *reinterpret_cast<const float4*>(&q[qpix + m * 16 + d]);
            qreg[d] = qv.x * SCALE; qreg[d + 1] = qv.y * SCALE;
            qreg[d + 2] = qv.z * SCALE; qreg[d + 3] = qv.w * SCALE;
        }
        __syncthreads();
        float s[64];
#pragma unroll
        for (int kk = 0; kk < 64; kk++) {
            int k = wv * 64 + kk;
            float a0 = 0.f;
#pragma unroll
            for (int d = 0; d < 16; d += 4) {
                const float4 kvv = *reinterpret_cast<const float4*>(&Kh[k][d]);
                a0 += qreg[d] * kvv.x + qreg[d + 1] * kvv.y + qreg[d + 2] * kvv.z + qreg[d + 3] * kvv.w;
            }
            s[kk] = a0;
        }
        float mx = -3.0e38f;
#pragma unroll
        for (int kk = 0; kk < 64; kk++) mx = fmaxf(mx, s[kk]);
        rmax[wv][lane] = mx;
        __syncthreads();
        mx = fmaxf(fmaxf(rmax[0][lane], rmax[1][lane]), fmaxf(rmax[2][lane], rmax[3][lane]));
        float sm = 0.f;
#pragma unroll
        for (int kk = 0; kk < 64; kk++) { s[kk] = __expf(s[kk] - mx); sm += s[kk]; }
        rsum[wv][lane] = sm;
        __syncthreads();
        float denom = rsum[0][lane] + rsum[1][lane] + rsum[2][lane] + rsum[3][lane];
        float po[16];
#pragma unroll
        for (int d = 0; d < 16; d++) po[d] = 0.f;
#pragma unroll
        for (int kk = 0; kk < 64; kk++) {
            int k = wv * 64 + kk;
#pragma unroll
            for (int d = 0; d < 16; d += 4) {
                const float4 vv = *reinterpret_cast<const float4*>(&Vh[k][d]);
                po[d] += s[kk] * vv.x; po[d + 1] += s[kk] * vv.y;
                po[d + 2] += s[kk] * vv.z; po[d + 3] += s[kk] * vv.w;
            }
        }
#pragma unroll
        for (int d = 0; d < 16; d += 4)
            *reinterpret_cast<float4*>(&part[wv][lane][d]) = make_float4(po[d], po[d+1], po[d+2], po[d+3]);
        __syncthreads();
        if (wv == 0) {
            float invd = 1.f / denom;
#pragma unroll
            for (int d = 0; d < 16; d++) {
                float tot = part[0][lane][d] + part[1][lane][d] + part[2][lane][d] + part[3][lane][d];
                o[qpix + m * 16 + d] = tot * invd;
            }
        }
    }
}

// ------------------------------------------------- LePE depthwise 5x5, o +=
__global__ __launch_bounds__(128) void lepe_k(const float* __restrict__ kv,
                                              const float* __restrict__ w,
                                              const float* __restrict__ bias,
                                              float* __restrict__ o) {
    int x = blockIdx.x, y = blockIdx.y, b = blockIdx.z;
    int c = threadIdx.x;
    float acc = bias[c];
#pragma unroll
    for (int dy = 0; dy < 5; dy++) {
        int yy = y + dy - 2;
        if (yy < 0 || yy >= H) continue;
#pragma unroll
        for (int dx = 0; dx < 5; dx++) {
            int xx = x + dx - 2;
            if (xx < 0 || xx >= W) continue;
            acc += kv[((size_t)(b * H + yy) * W + xx) * 256 + 128 + c] * w[c * 25 + dy * 5 + dx];
        }
    }
    size_t pix = (size_t)(b * H + y) * W + x;
    o[pix * 128 + c] += acc;
}

// ---------------------------------- (o @ Wo^T + b) + x, write NCHW output
__global__ __launch_bounds__(128) void epilogue_k(const float* __restrict__ o,
                                                  const float* __restrict__ xbuf,
                                                  const float* __restrict__ woT,
                                                  const float* __restrict__ wo_b,
                                                  float* __restrict__ out) {
    __shared__ float ot[16][128];
    __shared__ float res[128][17];
    int b = blockIdx.z, y = blockIdx.y, x0 = blockIdx.x * 16;
    int t = threadIdx.x;
    size_t pixBase = (size_t)(b * H + y) * W + x0;
    for (int p = 0; p < 16; p++) ot[p][t] = o[(pixBase + p) * 128 + t];
    __syncthreads();
    float acc[16];
    float wb = wo_b[t];
#pragma unroll
    for (int p = 0; p < 16; p++) acc[p] = wb + xbuf[(pixBase + p) * 128 + t];
    for (int k = 0; k < 128; k += 4) {
        float w0 = woT[(k + 0) * 128 + t];
        float w1 = woT[(k + 1) * 128 + t];
        float w2 = woT[(k + 2) * 128 + t];
        float w3 = woT[(k + 3) * 128 + t];
#pragma unroll
        for (int p = 0; p < 16; p++) {
            const float4 av = *reinterpret_cast<const float4*>(&ot[p][k]);
            acc[p] += av.x * w0 + av.y * w1 + av.z * w2 + av.w * w3;
        }
    }
#pragma unroll
    for (int p = 0; p < 16; p++) res[t][p] = acc[p];
    __syncthreads();
    int xi = t & 15, cg = t >> 4;
    for (int i = 0; i < 16; i++) {
        int c = cg * 16 + i;
        out[((size_t)(b * C + c) * H + y) * W + x0 + xi] = res[c][xi];
    }
}

extern "C" void kernel_launch(void* const* d_in, const int* in_sizes, int n_in,
                              void* d_out, int out_size, void* d_ws, size_t ws_size,
                              hipStream_t stream) {
    const float* t1      = (const float*)d_in[0];
    const float* t2      = (const float*)d_in[1];
    const float* pos_w   = (const float*)d_in[2];
    const float* pos_b   = (const float*)d_in[3];
    const float* cat_w   = (const float*)d_in[4];
    const float* cat_b   = (const float*)d_in[5];
    const float* ln_cat_g= (const float*)d_in[6];
    const float* ln_cat_b= (const float*)d_in[7];
    const float* ln1_g   = (const float*)d_in[8];
    const float* ln1_b   = (const float*)d_in[9];
    const float* qkv_w   = (const float*)d_in[10];
    const float* qkv_b   = (const float*)d_in[11];
    const float* lepe_w  = (const float*)d_in[12];
    const float* lepe_b  = (const float*)d_in[13];
    const float* wo_w    = (const float*)d_in[14];
    const float* wo_b    = (const float*)d_in[15];

    float* ws    = (float*)d_ws;
    float* t1c   = ws + OFF_T1C;
    float* t2c   = ws + OFF_T2C;
    float* xbuf  = ws + OFF_X;
    float* qbuf  = ws + OFF_Q;
    float* kvbuf = ws + OFF_KV;
    float* kvpix = ws + OFF_KVP;
    float* qwin  = ws + OFF_QW;
    float* kwin  = ws + OFF_KW;
    int*   ridx  = (int*)(ws + OFF_RIDX);
    float* wcatT = ws + OFF_WCT;
    float* qkvT  = ws + OFF_QKVT;
    float* woT   = ws + OFF_WOT;
    float* obuf  = ws + OFF_O;   // alias of t1c (t1c dead after ln_gemm q)
    float* out   = (float*)d_out;

    transpose_weights<<<dim3((2304 * 128 + 255) / 256), 256, 0, stream>>>(
        qkv_w, wo_w, cat_w, qkvT, woT, wcatT);
    pos_conv_k<<<dim3(2, 4, B * H), 256, 0, stream>>>(t1, pos_w, pos_b, t1c);
    pos_conv_k<<<dim3(2, 4, B * H), 256, 0, stream>>>(t2, pos_w, pos_b, t2c);
    catconv_ln_k<<<dim3(8, 64, 8), 128, 0, stream>>>(
        t1c, t2c, wcatT, cat_b, ln_cat_g, ln_cat_b, xbuf);
    ln_gemm_k<<<dim3(4096, 1), 128, 0, stream>>>(
        t1c, ln1_g, ln1_b, 1e-6f, qkvT, 0, qkv_b, qbuf, 128);
    ln_gemm_k<<<dim3(4096, 2), 128, 0, stream>>>(
        t2c, ln1_g, ln1_b, 1e-6f, qkvT, 128, qkv_b, kvbuf, 256);
    pool_k<<<dim3(64, B), 256, 0, stream>>>(qbuf, kvbuf, kvpix, qwin, kwin);
    route_k<<<dim3(64, B), 64, 0, stream>>>(qwin, kwin, ridx);
    attn_k<<<dim3(64, B), 256, 0, stream>>>(qbuf, kvpix, ridx, obuf);
    lepe_k<<<dim3(W, H, B), 128, 0, stream>>>(kvbuf, lepe_w, lepe_b, obuf);
    epilogue_k<<<dim3(4, 64, 8), 128, 0, stream>>>(obuf, xbuf, woT, wo_b, out);
}

// Round 2
// 489.244 us; speedup vs baseline: 2.1708x; 2.1708x over previous
//
#include <hip/hip_runtime.h>
#include <math.h>

typedef unsigned short ushort_t;
typedef __attribute__((ext_vector_type(4))) float f32x4;
typedef __attribute__((ext_vector_type(8))) short bf16x8;

constexpr int B = 8, C = 128, H = 64, W = 64;
constexpr int NWIN = 8, HEADS = 8, QKDIM = 128, KVPW = 4, TOPK = 16;
constexpr int P2 = NWIN * NWIN;   // 64 windows
constexpr float SCALE = 0.0883883476483184405f; // 128^-0.5

// workspace offsets (in floats)
constexpr size_t NPIX   = (size_t)B * H * W;            // 32768
constexpr size_t OFF_T1C = 0;                            // NHWC (B,H,W,128)
constexpr size_t OFF_T2C = OFF_T1C + NPIX * 128;
constexpr size_t OFF_X   = OFF_T2C + NPIX * 128;         // relu(LN(catconv))
constexpr size_t OFF_Q   = OFF_X   + NPIX * 128;         // q  (B,H,W,128)
constexpr size_t OFF_KV  = OFF_Q   + NPIX * 128;         // kv (B,H,W,256)
constexpr size_t OFF_KVP = OFF_KV  + NPIX * 256;         // kv_pix (B,64,16,256)
constexpr size_t OFF_QW  = OFF_KVP + (size_t)B * P2 * 16 * 256;
constexpr size_t OFF_KW  = OFF_QW  + (size_t)B * P2 * 128;
constexpr size_t OFF_RIDX= OFF_KW  + (size_t)B * P2 * 128;      // int
constexpr size_t OFF_WCB = OFF_RIDX+ (size_t)B * P2 * TOPK;     // wcatB bf16 [36][128][72]
constexpr size_t OFF_QKVT= OFF_WCB + (size_t)9 * 256 * 128;     // [128][384]
constexpr size_t OFF_WOT = OFF_QKVT+ (size_t)128 * 384;         // [128][128]
constexpr size_t OFF_O   = OFF_T1C;  // alias: attention output reuses t1c

// catconv MFMA geometry
constexpr int HALO_B = 10 * 18 * 144;          // 25920 B (bf16 [10][18][72])
constexpr int WT_B   = 128 * 144;              // 18432 B (bf16 [128][72])
constexpr int NSTAGE = 36;                     // 4 ci-quarters x 9 taps

__device__ inline ushort_t f2bf(float f) {
    unsigned u = __float_as_uint(f);
    unsigned r = u + 0x7FFFu + ((u >> 16) & 1u);
    return (ushort_t)(r >> 16);
}

// ---------------------------------------------------------------- transpose
__global__ void transpose_weights(const float* __restrict__ qkv_w,
                                  const float* __restrict__ wo_w,
                                  const float* __restrict__ cat_w,
                                  float* __restrict__ qkvT,
                                  float* __restrict__ woT,
                                  ushort_t* __restrict__ wcatB) {
    int idx = blockIdx.x * 256 + threadIdx.x;
    if (idx < 128 * 384) {           // qkvT[k][n] = qkv_w[n][k]
        int k = idx / 384, n = idx % 384;
        qkvT[idx] = qkv_w[n * 128 + k];
    }
    if (idx < 128 * 128) {           // woT[k][n] = wo_w[n][k]
        int k = idx / 128, n = idx % 128;
        woT[idx] = wo_w[n * 128 + k];
    }
    if (idx < 36 * 128 * 72) {       // wcatB[stage][co][ci72] bf16, stage = qq*9+dd
        int ci = idx % 72;
        int r  = idx / 72;
        int co = r & 127;
        int sdd = r >> 7;            // 0..35
        int qq = sdd / 9, dd = sdd - qq * 9;
        float v = 0.f;
        if (ci < 64)
            v = cat_w[((size_t)co * 256 + qq * 64 + ci) * 9 + dd];
        wcatB[idx] = f2bf(v);
    }
}

// --------------------------------------- depthwise 3x3 + residual, NCHW->NHWC
__global__ __launch_bounds__(256) void pos_conv_k(const float* __restrict__ in,
                                                  const float* __restrict__ w,
                                                  const float* __restrict__ bias,
                                                  float* __restrict__ outNHWC) {
    __shared__ float tile[32][33];
    int b = blockIdx.z / H, y = blockIdx.z % H;
    int c0 = blockIdx.y * 32, x0 = blockIdx.x * 32;
    int tx = threadIdx.x & 31, tg = threadIdx.x >> 5;   // 8 groups
    for (int i = 0; i < 4; i++) {
        int cl = tg * 4 + i, c = c0 + cl;
        const float* base = in + (size_t)(b * C + c) * H * W;
        float acc = base[y * W + x0 + tx];              // residual (center)
        float wv[9];
#pragma unroll
        for (int j = 0; j < 9; j++) wv[j] = w[c * 9 + j];
#pragma unroll
        for (int dy = 0; dy < 3; dy++) {
            int yy = y + dy - 1;
            if (yy < 0 || yy >= H) continue;
#pragma unroll
            for (int dx = 0; dx < 3; dx++) {
                int xx = x0 + tx + dx - 1;
                if (xx < 0 || xx >= W) continue;
                acc += base[yy * W + xx] * wv[dy * 3 + dx];
            }
        }
        tile[cl][tx] = acc + bias[c];
    }
    __syncthreads();
    for (int i = 0; i < 4; i++) {
        int xl = tg * 4 + i;
        outNHWC[((size_t)(b * H + y) * W + x0 + xl) * 128 + c0 + tx] = tile[tx][xl];
    }
}

// ------------------ cat-conv 256->128 3x3 as implicit-GEMM MFMA + fused LN+ReLU
__device__ inline void stage_halo(int qq, int b, int y0, int x0, int t,
                                  const float* __restrict__ t1c,
                                  const float* __restrict__ t2c,
                                  unsigned char* smem) {
    const float* src = (qq < 2 ? t1c : t2c) + (qq & 1) * 64;
    for (int e = t; e < 180 * 16; e += 256) {
        int pix = e >> 4, c4 = e & 15;
        int hy = pix / 18, hx = pix - hy * 18;
        int gy = y0 - 1 + hy, gx = x0 - 1 + hx;
        float4 v = make_float4(0.f, 0.f, 0.f, 0.f);
        if (gy >= 0 && gy < H && gx >= 0 && gx < W)
            v = *reinterpret_cast<const float4*>(
                src + ((size_t)(b * H + gy) * W + gx) * 128 + c4 * 4);
        uint2 pk;
        pk.x = (unsigned)f2bf(v.x) | ((unsigned)f2bf(v.y) << 16);
        pk.y = (unsigned)f2bf(v.z) | ((unsigned)f2bf(v.w) << 16);
        *reinterpret_cast<uint2*>(smem + pix * 144 + c4 * 8) = pk;
    }
}

__global__ __launch_bounds__(256) void catconv_mfma_k(
        const float* __restrict__ t1c, const float* __restrict__ t2c,
        const ushort_t* __restrict__ wcatB,
        const float* __restrict__ cat_b,
        const float* __restrict__ g, const float* __restrict__ beta,
        float* __restrict__ xbuf) {
    __shared__ __align__(16) unsigned char smem[HALO_B + 2 * WT_B];
    int t = threadIdx.x;
    int lane = t & 63, wv = t >> 6;
    int wr = wv >> 1, wc = wv & 1;
    int l15 = lane & 15, lg = lane >> 4;
    int b = blockIdx.z, y0 = blockIdx.y * 8, x0 = blockIdx.x * 16;

    f32x4 acc[4][4];
#pragma unroll
    for (int r = 0; r < 4; r++)
#pragma unroll
        for (int cf = 0; cf < 4; cf++)
            acc[r][cf] = (f32x4){0.f, 0.f, 0.f, 0.f};

    // prologue: fetch stage-0 weights into registers
    unsigned long long wreg[9];
    {
        const unsigned long long* wsrc = (const unsigned long long*)wcatB;
#pragma unroll
        for (int j = 0; j < 9; j++) wreg[j] = wsrc[t + j * 256];
    }

    for (int s = 0; s < NSTAGE; s++) {
        if ((s % 9) == 0) {
            __syncthreads();                       // all waves done with old halo
            stage_halo(s / 9, b, y0, x0, t, t1c, t2c, smem);
        }
        // commit prefetched weights for stage s
        {
            unsigned char* wdst = smem + HALO_B + (s & 1) * WT_B;
#pragma unroll
            for (int j = 0; j < 9; j++)
                *reinterpret_cast<unsigned long long*>(wdst + (t + j * 256) * 8) = wreg[j];
        }
        // prefetch stage s+1 weights into registers (overlaps compute below)
        if (s + 1 < NSTAGE) {
            const unsigned long long* wsrc =
                (const unsigned long long*)(wcatB + (size_t)(s + 1) * 128 * 72);
#pragma unroll
            for (int j = 0; j < 9; j++) wreg[j] = wsrc[t + j * 256];
        }
        __syncthreads();                           // halo + weights visible

        int dd = s % 9;
        int dy = dd / 3, dx = dd - dy * 3;
        const unsigned char* wb = smem + HALO_B + (s & 1) * WT_B;
#pragma unroll
        for (int kk = 0; kk < 2; kk++) {
            bf16x8 af[4], bfr[4];
#pragma unroll
            for (int r = 0; r < 4; r++)
                af[r] = *reinterpret_cast<const bf16x8*>(
                    smem + ((wr * 4 + r + dy) * 18 + l15 + dx) * 144 + kk * 64 + lg * 16);
#pragma unroll
            for (int cf = 0; cf < 4; cf++)
                bfr[cf] = *reinterpret_cast<const bf16x8*>(
                    wb + (wc * 64 + cf * 16 + l15) * 144 + kk * 64 + lg * 16);
#pragma unroll
            for (int r = 0; r < 4; r++)
#pragma unroll
                for (int cf = 0; cf < 4; cf++)
                    acc[r][cf] = __builtin_amdgcn_mfma_f32_16x16x32_bf16(
                        af[r], bfr[cf], acc[r][cf], 0, 0, 0);
        }
    }

    // ------- fused bias + LayerNorm(1e-5) + ReLU epilogue via LDS reuse -------
    __syncthreads();
    float* res = (float*)smem;                     // [64][132]
    float* mstat = (float*)(smem + 64 * 132 * 4);  // mean[64], inv[64]
    for (int h = 0; h < 2; h++) {
        if (wr == h) {
#pragma unroll
            for (int cf = 0; cf < 4; cf++) {
                int n = wc * 64 + cf * 16 + l15;
                float cb = cat_b[n];
#pragma unroll
                for (int r = 0; r < 4; r++)
#pragma unroll
                    for (int i = 0; i < 4; i++)
                        res[(r * 16 + lg * 4 + i) * 132 + n] = acc[r][cf][i] + cb;
            }
        }
        __syncthreads();
        int pix = t >> 2, sub = t & 3;
        float s1 = 0.f;
#pragma unroll
        for (int j = 0; j < 32; j++) s1 += res[pix * 132 + sub + j * 4];
        s1 += __shfl_xor(s1, 1, 64);
        s1 += __shfl_xor(s1, 2, 64);
        float mean = s1 * (1.f / 128.f);
        float s2 = 0.f;
#pragma unroll
        for (int j = 0; j < 32; j++) {
            float d = res[pix * 132 + sub + j * 4] - mean;
            s2 += d * d;
        }
        s2 += __shfl_xor(s2, 1, 64);
        s2 += __shfl_xor(s2, 2, 64);
        float inv = rsqrtf(s2 * (1.f / 128.f) + 1e-5f);
        if (sub == 0) { mstat[pix] = mean; mstat[64 + pix] = inv; }
        __syncthreads();
        int c = t & 127, pr = t >> 7;
        float gg = g[c], bb = beta[c];
        for (int j = 0; j < 32; j++) {
            int p2 = j * 2 + pr;
            float v = (res[p2 * 132 + c] - mstat[p2]) * mstat[64 + p2] * gg + bb;
            int gp = h * 64 + p2;
            int py = gp >> 4, px = gp & 15;
            xbuf[((size_t)(b * H + y0 + py) * W + x0 + px) * 128 + c] = fmaxf(v, 0.f);
        }
        __syncthreads();
    }
}

// ------------------------------------------- LayerNorm(1e-6) + projection
__global__ __launch_bounds__(128) void ln_gemm_k(const float* __restrict__ in,
                                                 const float* __restrict__ g,
                                                 const float* __restrict__ beta,
                                                 float eps,
                                                 const float* __restrict__ wT, // [128][384]
                                                 int colOff,
                                                 const float* __restrict__ bias,
                                                 float* __restrict__ out, int outStride) {
    __shared__ float a[8][128];
    int t = threadIdx.x;
    size_t p0 = (size_t)blockIdx.x * 8;
    for (int p = 0; p < 8; p++) a[p][t] = in[(p0 + p) * 128 + t];
    __syncthreads();
    int lane = t & 63, wvi = t >> 6;
    for (int p = wvi * 4; p < wvi * 4 + 4; p++) {
        float v0 = a[p][lane], v1 = a[p][lane + 64];
        float s = v0 + v1;
#pragma unroll
        for (int m = 32; m > 0; m >>= 1) s += __shfl_xor(s, m, 64);
        float mean = s * (1.f / 128.f);
        float d0 = v0 - mean, d1 = v1 - mean;
        float vs = d0 * d0 + d1 * d1;
#pragma unroll
        for (int m = 32; m > 0; m >>= 1) vs += __shfl_xor(vs, m, 64);
        float inv = rsqrtf(vs * (1.f / 128.f) + eps);
        a[p][lane]      = d0 * inv * g[lane] + beta[lane];
        a[p][lane + 64] = d1 * inv * g[lane + 64] + beta[lane + 64];
    }
    __syncthreads();
    int col = colOff + blockIdx.y * 128 + t;
    float acc[8];
#pragma unroll
    for (int p = 0; p < 8; p++) acc[p] = 0.f;
    for (int k = 0; k < 128; k += 4) {
        float w0 = wT[(k + 0) * 384 + col];
        float w1 = wT[(k + 1) * 384 + col];
        float w2 = wT[(k + 2) * 384 + col];
        float w3 = wT[(k + 3) * 384 + col];
#pragma unroll
        for (int p = 0; p < 8; p++) {
            const float4 av = *reinterpret_cast<const float4*>(&a[p][k]);
            acc[p] += av.x * w0 + av.y * w1 + av.z * w2 + av.w * w3;
        }
    }
    float bv = bias[col];
    int oc = blockIdx.y * 128 + t;
    for (int p = 0; p < 8; p++) out[(p0 + p) * outStride + oc] = acc[p] + bv;
}

// --------------------------------------------- window pooling (kv_pix, means)
__global__ __launch_bounds__(256) void pool_k(const float* __restrict__ q,
                                              const float* __restrict__ kv,
                                              float* __restrict__ kv_pix,
                                              float* __restrict__ q_win,
                                              float* __restrict__ k_win) {
    int b = blockIdx.y, wdw = blockIdx.x;
    int wi = wdw >> 3, wj = wdw & 7;
    int t = threadIdx.x;
    float tot = 0.f;
    for (int ry = 0; ry < 4; ry++)
        for (int rx = 0; rx < 4; rx++) {
            float s = 0.f;
            for (int fy = 0; fy < 2; fy++)
                for (int fx = 0; fx < 2; fx++) {
                    int y = wi * 8 + ry * 2 + fy, x = wj * 8 + rx * 2 + fx;
                    s += kv[((size_t)(b * H + y) * W + x) * 256 + t];
                }
            kv_pix[((size_t)(b * 64 + wdw) * 16 + ry * 4 + rx) * 256 + t] = s * 0.25f;
            tot += s;
        }
    if (t < 128) {
        k_win[(size_t)(b * 64 + wdw) * 128 + t] = tot * (1.f / 64.f);
        float qs = 0.f;
        for (int iy = 0; iy < 8; iy++)
            for (int ix = 0; ix < 8; ix++) {
                int y = wi * 8 + iy, x = wj * 8 + ix;
                qs += q[((size_t)(b * H + y) * W + x) * 128 + t];
            }
        q_win[(size_t)(b * 64 + wdw) * 128 + t] = qs * (1.f / 64.f);
    }
}

// ------------------------------------------------ routing logits + top-16
__global__ __launch_bounds__(64) void route_k(const float* __restrict__ q_win,
                                              const float* __restrict__ k_win,
                                              int* __restrict__ r_idx) {
    int b = blockIdx.y, p = blockIdx.x, j = threadIdx.x;
    const float* qp = q_win + (size_t)(b * 64 + p) * 128;
    const float* kp = k_win + (size_t)(b * 64 + j) * 128;
    float lg = 0.f;
    for (int c = 0; c < 128; c++) lg += qp[c] * kp[c];
    lg *= SCALE;
    for (int it = 0; it < TOPK; it++) {
        float v = lg; int idx = j;
#pragma unroll
        for (int m = 32; m > 0; m >>= 1) {
            float ov = __shfl_xor(v, m, 64);
            int   oi = __shfl_xor(idx, m, 64);
            if (ov > v || (ov == v && oi < idx)) { v = ov; idx = oi; }
        }
        if (j == 0) r_idx[(size_t)(b * 64 + p) * TOPK + it] = idx;
        if (j == idx) lg = -__builtin_inff();
    }
}

// -------------------------------------------------------- routed attention
__global__ __launch_bounds__(256) void attn_k(const float* __restrict__ q,
                                              const float* __restrict__ kv_pix,
                                              const int* __restrict__ r_idx,
                                              float* __restrict__ o) {
    __shared__ float Kh[256][20];
    __shared__ float Vh[256][20];
    __shared__ float part[4][64][20];
    __shared__ float rmax[4][64], rsum[4][64];
    __shared__ int ridx[16];
    int b = blockIdx.y, p = blockIdx.x;
    int wi = p >> 3, wj = p & 7;
    int t = threadIdx.x;
    int lane = t & 63, wv = t >> 6;
    if (t < 16) ridx[t] = r_idx[(size_t)(b * 64 + p) * TOPK + t];
    __syncthreads();
    int region = ridx[t >> 4], pos = t & 15;
    size_t kvbase = ((size_t)((b * 64 + region) * 16) + pos) * 256;
    int qy = wi * 8 + (lane >> 3), qx = wj * 8 + (lane & 7);
    size_t qpix = ((size_t)(b * H + qy) * W + qx) * 128;

    for (int m = 0; m < HEADS; m++) {
        __syncthreads();
#pragma unroll
        for (int d = 0; d < 16; d += 4) {
            *reinterpret_cast<float4*>(&Kh[t][d]) =
                *reinterpret_cast<const float4*>(&kv_pix[kvbase + m * 16 + d]);
            *reinterpret_cast<float4*>(&Vh[t][d]) =
                *reinterpret_cast<const float4*>(&kv_pix[kvbase + 128 + m * 16 + d]);
        }
        float qreg[16];
#pragma unroll
        for (int d = 0; d < 16; d += 4) {
            float4 qv = *reinterpret_cast<const float4*>(&q[qpix + m * 16 + d]);
            qreg[d] = qv.x * SCALE; qreg[d + 1] = qv.y * SCALE;
            qreg[d + 2] = qv.z * SCALE; qreg[d + 3] = qv.w * SCALE;
        }
        __syncthreads();
        float s[64];
#pragma unroll
        for (int kk = 0; kk < 64; kk++) {
            int k = wv * 64 + kk;
            float a0 = 0.f;
#pragma unroll
            for (int d = 0; d < 16; d += 4) {
                const float4 kvv = *reinterpret_cast<const float4*>(&Kh[k][d]);
                a0 += qreg[d] * kvv.x + qreg[d + 1] * kvv.y + qreg[d + 2] * kvv.z + qreg[d + 3] * kvv.w;
            }
            s[kk] = a0;
        }
        float mx = -3.0e38f;
#pragma unroll
        for (int kk = 0; kk < 64; kk++) mx = fmaxf(mx, s[kk]);
        rmax[wv][lane] = mx;
        __syncthreads();
        mx = fmaxf(fmaxf(rmax[0][lane], rmax[1][lane]), fmaxf(rmax[2][lane], rmax[3][lane]));
        float sm = 0.f;
#pragma unroll
        for (int kk = 0; kk < 64; kk++) { s[kk] = __expf(s[kk] - mx); sm += s[kk]; }
        rsum[wv][lane] = sm;
        __syncthreads();
        float denom = rsum[0][lane] + rsum[1][lane] + rsum[2][lane] + rsum[3][lane];
        float po[16];
#pragma unroll
        for (int d = 0; d < 16; d++) po[d] = 0.f;
#pragma unroll
        for (int kk = 0; kk < 64; kk++) {
            int k = wv * 64 + kk;
#pragma unroll
            for (int d = 0; d < 16; d += 4) {
                const float4 vv = *reinterpret_cast<const float4*>(&Vh[k][d]);
                po[d] += s[kk] * vv.x; po[d + 1] += s[kk] * vv.y;
                po[d + 2] += s[kk] * vv.z; po[d + 3] += s[kk] * vv.w;
            }
        }
#pragma unroll
        for (int d = 0; d < 16; d += 4)
            *reinterpret_cast<float4*>(&part[wv][lane][d]) = make_float4(po[d], po[d+1], po[d+2], po[d+3]);
        __syncthreads();
        if (wv == 0) {
            float invd = 1.f / denom;
#pragma unroll
            for (int d = 0; d < 16; d++) {
                float tot = part[0][lane][d] + part[1][lane][d] + part[2][lane][d] + part[3][lane][d];
                o[qpix + m * 16 + d] = tot * invd;
            }
        }
    }
}

// ------------------------------------------------- LePE depthwise 5x5, o +=
__global__ __launch_bounds__(128) void lepe_k(const float* __restrict__ kv,
                                              const float* __restrict__ w,
                                              const float* __restrict__ bias,
                                              float* __restrict__ o) {
    int x = blockIdx.x, y = blockIdx.y, b = blockIdx.z;
    int c = threadIdx.x;
    float acc = bias[c];
#pragma unroll
    for (int dy = 0; dy < 5; dy++) {
        int yy = y + dy - 2;
        if (yy < 0 || yy >= H) continue;
#pragma unroll
        for (int dx = 0; dx < 5; dx++) {
            int xx = x + dx - 2;
            if (xx < 0 || xx >= W) continue;
            acc += kv[((size_t)(b * H + yy) * W + xx) * 256 + 128 + c] * w[c * 25 + dy * 5 + dx];
        }
    }
    size_t pix = (size_t)(b * H + y) * W + x;
    o[pix * 128 + c] += acc;
}

// ---------------------------------- (o @ Wo^T + b) + x, write NCHW output
__global__ __launch_bounds__(128) void epilogue_k(const float* __restrict__ o,
                                                  const float* __restrict__ xbuf,
                                                  const float* __restrict__ woT,
                                                  const float* __restrict__ wo_b,
                                                  float* __restrict__ out) {
    __shared__ float ot[16][128];
    __shared__ float res[128][17];
    int b = blockIdx.z, y = blockIdx.y, x0 = blockIdx.x * 16;
    int t = threadIdx.x;
    size_t pixBase = (size_t)(b * H + y) * W + x0;
    for (int p = 0; p < 16; p++) ot[p][t] = o[(pixBase + p) * 128 + t];
    __syncthreads();
    float acc[16];
    float wb = wo_b[t];
#pragma unroll
    for (int p = 0; p < 16; p++) acc[p] = wb + xbuf[(pixBase + p) * 128 + t];
    for (int k = 0; k < 128; k += 4) {
        float w0 = woT[(k + 0) * 128 + t];
        float w1 = woT[(k + 1) * 128 + t];
        float w2 = woT[(k + 2) * 128 + t];
        float w3 = woT[(k + 3) * 128 + t];
#pragma unroll
        for (int p = 0; p < 16; p++) {
            const float4 av = *reinterpret_cast<const float4*>(&ot[p][k]);
            acc[p] += av.x * w0 + av.y * w1 + av.z * w2 + av.w * w3;
        }
    }
#pragma unroll
    for (int p = 0; p < 16; p++) res[t][p] = acc[p];
    __syncthreads();
    int xi = t & 15, cg = t >> 4;
    for (int i = 0; i < 16; i++) {
        int c = cg * 16 + i;
        out[((size_t)(b * C + c) * H + y) * W + x0 + xi] = res[c][xi];
    }
}

extern "C" void kernel_launch(void* const* d_in, const int* in_sizes, int n_in,
                              void* d_out, int out_size, void* d_ws, size_t ws_size,
                              hipStream_t stream) {
    const float* t1      = (const float*)d_in[0];
    const float* t2      = (const float*)d_in[1];
    const float* pos_w   = (const float*)d_in[2];
    const float* pos_b   = (const float*)d_in[3];
    const float* cat_w   = (const float*)d_in[4];
    const float* cat_b   = (const float*)d_in[5];
    const float* ln_cat_g= (const float*)d_in[6];
    const float* ln_cat_b= (const float*)d_in[7];
    const float* ln1_g   = (const float*)d_in[8];
    const float* ln1_b   = (const float*)d_in[9];
    const float* qkv_w   = (const float*)d_in[10];
    const float* qkv_b   = (const float*)d_in[11];
    const float* lepe_w  = (const float*)d_in[12];
    const float* lepe_b  = (const float*)d_in[13];
    const float* wo_w    = (const float*)d_in[14];
    const float* wo_b    = (const float*)d_in[15];

    float* ws    = (float*)d_ws;
    float* t1c   = ws + OFF_T1C;
    float* t2c   = ws + OFF_T2C;
    float* xbuf  = ws + OFF_X;
    float* qbuf  = ws + OFF_Q;
    float* kvbuf = ws + OFF_KV;
    float* kvpix = ws + OFF_KVP;
    float* qwin  = ws + OFF_QW;
    float* kwin  = ws + OFF_KW;
    int*   ridx  = (int*)(ws + OFF_RIDX);
    ushort_t* wcatB = (ushort_t*)(ws + OFF_WCB);
    float* qkvT  = ws + OFF_QKVT;
    float* woT   = ws + OFF_WOT;
    float* obuf  = ws + OFF_O;   // alias of t1c (t1c dead after ln_gemm q)
    float* out   = (float*)d_out;

    transpose_weights<<<dim3((36 * 128 * 72 + 255) / 256), 256, 0, stream>>>(
        qkv_w, wo_w, cat_w, qkvT, woT, wcatB);
    pos_conv_k<<<dim3(2, 4, B * H), 256, 0, stream>>>(t1, pos_w, pos_b, t1c);
    pos_conv_k<<<dim3(2, 4, B * H), 256, 0, stream>>>(t2, pos_w, pos_b, t2c);
    catconv_mfma_k<<<dim3(4, 8, 8), 256, 0, stream>>>(
        t1c, t2c, wcatB, cat_b, ln_cat_g, ln_cat_b, xbuf);
    ln_gemm_k<<<dim3(4096, 1), 128, 0, stream>>>(
        t1c, ln1_g, ln1_b, 1e-6f, qkvT, 0, qkv_b, qbuf, 128);
    ln_gemm_k<<<dim3(4096, 2), 128, 0, stream>>>(
        t2c, ln1_g, ln1_b, 1e-6f, qkvT, 128, qkv_b, kvbuf, 256);
    pool_k<<<dim3(64, B), 256, 0, stream>>>(qbuf, kvbuf, kvpix, qwin, kwin);
    route_k<<<dim3(64, B), 64, 0, stream>>>(qwin, kwin, ridx);
    attn_k<<<dim3(64, B), 256, 0, stream>>>(qbuf, kvpix, ridx, obuf);
    lepe_k<<<dim3(W, H, B), 128, 0, stream>>>(kvbuf, lepe_w, lepe_b, obuf);
    epilogue_k<<<dim3(4, 64, 8), 128, 0, stream>>>(obuf, xbuf, woT, wo_b, out);
}

// Round 3
// 375.482 us; speedup vs baseline: 2.8285x; 1.3030x over previous
//
#include <hip/hip_runtime.h>
#include <math.h>

typedef unsigned short ushort_t;
typedef __attribute__((ext_vector_type(4))) float f32x4;
typedef __attribute__((ext_vector_type(16))) float f32x16;
typedef __attribute__((ext_vector_type(8))) short bf16x8;

constexpr int B = 8, C = 128, H = 64, W = 64;
constexpr int HEADS = 8, TOPK = 16;
constexpr int P2 = 64;
constexpr float SCALE = 0.0883883476483184405f; // 128^-0.5

// workspace offsets (in floats)
constexpr size_t NPIX    = (size_t)B * H * W;            // 32768
constexpr size_t OFF_T1C = 0;                            // NHWC fp32 (B,H,W,128)
constexpr size_t OFF_T2C = OFF_T1C + NPIX * 128;
constexpr size_t OFF_X   = OFF_T2C + NPIX * 128;         // relu(LN(catconv)) fp32
constexpr size_t OFF_QB  = OFF_X   + NPIX * 128;         // q*SCALE bf16 (NPIX*128 shorts)
constexpr size_t OFF_KV  = OFF_QB  + NPIX * 64;          // kv fp32 (B,H,W,256)
constexpr size_t OFF_KVP = OFF_KV  + NPIX * 256;         // kv_pix fp32 (B,64,16,256)
constexpr size_t OFF_KVPT= OFF_KVP + (size_t)B * P2 * 16 * 256; // v^T bf16 [B,64,128,16]
constexpr size_t OFF_M1  = OFF_KVPT+ (size_t)B * P2 * 128 * 16 / 2;
constexpr size_t OFF_M2  = OFF_M1  + (size_t)B * P2 * 128;
constexpr size_t OFF_QW  = OFF_M2  + (size_t)B * P2 * 128;
constexpr size_t OFF_KW  = OFF_QW  + (size_t)B * P2 * 128;
constexpr size_t OFF_RIDX= OFF_KW  + (size_t)B * P2 * 128;      // int
constexpr size_t OFF_WCB = OFF_RIDX+ (size_t)B * P2 * TOPK;     // wcatB bf16 [36][128][72]
constexpr size_t OFF_QKVB= OFF_WCB + (size_t)9 * 256 * 128;     // qkv_w bf16 [384][128]
constexpr size_t OFF_WOT = OFF_QKVB+ (size_t)384 * 128 / 2;     // [128][128] fp32
constexpr size_t OFF_O   = OFF_T1C;  // attention output aliases t1c

// catconv MFMA geometry
constexpr int HALO_B = 10 * 18 * 144;
constexpr int WT_B   = 128 * 144;
constexpr int NSTAGE = 36;

__device__ inline ushort_t f2bf(float f) {
    unsigned u = __float_as_uint(f);
    unsigned r = u + 0x7FFFu + ((u >> 16) & 1u);
    return (ushort_t)(r >> 16);
}

// ---------------------------------------------------------------- weights prep
__global__ void transpose_weights(const float* __restrict__ qkv_w,
                                  const float* __restrict__ wo_w,
                                  const float* __restrict__ cat_w,
                                  ushort_t* __restrict__ qkvB,
                                  float* __restrict__ woT,
                                  ushort_t* __restrict__ wcatB) {
    int idx = blockIdx.x * 256 + threadIdx.x;
    if (idx < 384 * 128) {           // qkvB[n][k] bf16 (same layout as qkv_w)
        qkvB[idx] = f2bf(qkv_w[idx]);
    }
    if (idx < 128 * 128) {           // woT[k][n] = wo_w[n][k]
        int k = idx / 128, n = idx % 128;
        woT[idx] = wo_w[n * 128 + k];
    }
    if (idx < 36 * 128 * 72) {       // wcatB[stage][co][ci72] bf16, stage = qq*9+dd
        int ci = idx % 72;
        int r  = idx / 72;
        int co = r & 127;
        int sdd = r >> 7;
        int qq = sdd / 9, dd = sdd - qq * 9;
        float v = 0.f;
        if (ci < 64)
            v = cat_w[((size_t)co * 256 + qq * 64 + ci) * 9 + dd];
        wcatB[idx] = f2bf(v);
    }
}

// --------------------------------------- depthwise 3x3 + residual, NCHW->NHWC
__global__ __launch_bounds__(256) void pos_conv_k(const float* __restrict__ in,
                                                  const float* __restrict__ w,
                                                  const float* __restrict__ bias,
                                                  float* __restrict__ outNHWC) {
    __shared__ float tile[32][33];
    int b = blockIdx.z / H, y = blockIdx.z % H;
    int c0 = blockIdx.y * 32, x0 = blockIdx.x * 32;
    int tx = threadIdx.x & 31, tg = threadIdx.x >> 5;
    for (int i = 0; i < 4; i++) {
        int cl = tg * 4 + i, c = c0 + cl;
        const float* base = in + (size_t)(b * C + c) * H * W;
        float acc = base[y * W + x0 + tx];
        float wv[9];
#pragma unroll
        for (int j = 0; j < 9; j++) wv[j] = w[c * 9 + j];
#pragma unroll
        for (int dy = 0; dy < 3; dy++) {
            int yy = y + dy - 1;
            if (yy < 0 || yy >= H) continue;
#pragma unroll
            for (int dx = 0; dx < 3; dx++) {
                int xx = x0 + tx + dx - 1;
                if (xx < 0 || xx >= W) continue;
                acc += base[yy * W + xx] * wv[dy * 3 + dx];
            }
        }
        tile[cl][tx] = acc + bias[c];
    }
    __syncthreads();
    for (int i = 0; i < 4; i++) {
        int xl = tg * 4 + i;
        outNHWC[((size_t)(b * H + y) * W + x0 + xl) * 128 + c0 + tx] = tile[tx][xl];
    }
}

// ------------------ cat-conv 256->128 3x3 implicit-GEMM MFMA + fused LN+ReLU
__device__ inline void stage_halo(int qq, int b, int y0, int x0, int t,
                                  const float* __restrict__ t1c,
                                  const float* __restrict__ t2c,
                                  unsigned char* smem) {
    const float* src = (qq < 2 ? t1c : t2c) + (qq & 1) * 64;
    for (int e = t; e < 180 * 16; e += 256) {
        int pix = e >> 4, c4 = e & 15;
        int hy = pix / 18, hx = pix - hy * 18;
        int gy = y0 - 1 + hy, gx = x0 - 1 + hx;
        float4 v = make_float4(0.f, 0.f, 0.f, 0.f);
        if (gy >= 0 && gy < H && gx >= 0 && gx < W)
            v = *reinterpret_cast<const float4*>(
                src + ((size_t)(b * H + gy) * W + gx) * 128 + c4 * 4);
        uint2 pk;
        pk.x = (unsigned)f2bf(v.x) | ((unsigned)f2bf(v.y) << 16);
        pk.y = (unsigned)f2bf(v.z) | ((unsigned)f2bf(v.w) << 16);
        *reinterpret_cast<uint2*>(smem + pix * 144 + c4 * 8) = pk;
    }
}

__global__ __launch_bounds__(256) void catconv_mfma_k(
        const float* __restrict__ t1c, const float* __restrict__ t2c,
        const ushort_t* __restrict__ wcatB,
        const float* __restrict__ cat_b,
        const float* __restrict__ g, const float* __restrict__ beta,
        float* __restrict__ xbuf) {
    __shared__ __align__(16) unsigned char smem[HALO_B + 2 * WT_B];
    int t = threadIdx.x;
    int lane = t & 63, wv = t >> 6;
    int wr = wv >> 1, wc = wv & 1;
    int l15 = lane & 15, lg = lane >> 4;
    int b = blockIdx.z, y0 = blockIdx.y * 8, x0 = blockIdx.x * 16;

    f32x4 acc[4][4];
#pragma unroll
    for (int r = 0; r < 4; r++)
#pragma unroll
        for (int cf = 0; cf < 4; cf++)
            acc[r][cf] = (f32x4){0.f, 0.f, 0.f, 0.f};

    unsigned long long wreg[9];
    {
        const unsigned long long* wsrc = (const unsigned long long*)wcatB;
#pragma unroll
        for (int j = 0; j < 9; j++) wreg[j] = wsrc[t + j * 256];
    }

    for (int s = 0; s < NSTAGE; s++) {
        if ((s % 9) == 0) {
            __syncthreads();
            stage_halo(s / 9, b, y0, x0, t, t1c, t2c, smem);
        }
        {
            unsigned char* wdst = smem + HALO_B + (s & 1) * WT_B;
#pragma unroll
            for (int j = 0; j < 9; j++)
                *reinterpret_cast<unsigned long long*>(wdst + (t + j * 256) * 8) = wreg[j];
        }
        if (s + 1 < NSTAGE) {
            const unsigned long long* wsrc =
                (const unsigned long long*)(wcatB + (size_t)(s + 1) * 128 * 72);
#pragma unroll
            for (int j = 0; j < 9; j++) wreg[j] = wsrc[t + j * 256];
        }
        __syncthreads();

        int dd = s % 9;
        int dy = dd / 3, dx = dd - dy * 3;
        const unsigned char* wb = smem + HALO_B + (s & 1) * WT_B;
#pragma unroll
        for (int kk = 0; kk < 2; kk++) {
            bf16x8 af[4], bfr[4];
#pragma unroll
            for (int r = 0; r < 4; r++)
                af[r] = *reinterpret_cast<const bf16x8*>(
                    smem + ((wr * 4 + r + dy) * 18 + l15 + dx) * 144 + kk * 64 + lg * 16);
#pragma unroll
            for (int cf = 0; cf < 4; cf++)
                bfr[cf] = *reinterpret_cast<const bf16x8*>(
                    wb + (wc * 64 + cf * 16 + l15) * 144 + kk * 64 + lg * 16);
#pragma unroll
            for (int r = 0; r < 4; r++)
#pragma unroll
                for (int cf = 0; cf < 4; cf++)
                    acc[r][cf] = __builtin_amdgcn_mfma_f32_16x16x32_bf16(
                        af[r], bfr[cf], acc[r][cf], 0, 0, 0);
        }
    }

    __syncthreads();
    float* res = (float*)smem;
    float* mstat = (float*)(smem + 64 * 132 * 4);
    for (int h = 0; h < 2; h++) {
        if (wr == h) {
#pragma unroll
            for (int cf = 0; cf < 4; cf++) {
                int n = wc * 64 + cf * 16 + l15;
                float cb = cat_b[n];
#pragma unroll
                for (int r = 0; r < 4; r++)
#pragma unroll
                    for (int i = 0; i < 4; i++)
                        res[(r * 16 + lg * 4 + i) * 132 + n] = acc[r][cf][i] + cb;
            }
        }
        __syncthreads();
        int pix = t >> 2, sub = t & 3;
        float s1 = 0.f;
#pragma unroll
        for (int j = 0; j < 32; j++) s1 += res[pix * 132 + sub + j * 4];
        s1 += __shfl_xor(s1, 1, 64);
        s1 += __shfl_xor(s1, 2, 64);
        float mean = s1 * (1.f / 128.f);
        float s2 = 0.f;
#pragma unroll
        for (int j = 0; j < 32; j++) {
            float d = res[pix * 132 + sub + j * 4] - mean;
            s2 += d * d;
        }
        s2 += __shfl_xor(s2, 1, 64);
        s2 += __shfl_xor(s2, 2, 64);
        float inv = rsqrtf(s2 * (1.f / 128.f) + 1e-5f);
        if (sub == 0) { mstat[pix] = mean; mstat[64 + pix] = inv; }
        __syncthreads();
        int c = t & 127, pr = t >> 7;
        float gg = g[c], bb = beta[c];
        for (int j = 0; j < 32; j++) {
            int p2 = j * 2 + pr;
            float v = (res[p2 * 132 + c] - mstat[p2]) * mstat[64 + p2] * gg + bb;
            int gp = h * 64 + p2;
            int py = gp >> 4, px = gp & 15;
            xbuf[((size_t)(b * H + y0 + py) * W + x0 + px) * 128 + c] = fmaxf(v, 0.f);
        }
        __syncthreads();
    }
}

// ------------------------ LN(1e-6) + QKV projection, bf16 MFMA (M=64 per block)
template<int NPW, bool QOUT>
__global__ __launch_bounds__(256) void ln_qkv_mfma_k(
        const float* __restrict__ in,
        const float* __restrict__ g, const float* __restrict__ beta,
        const ushort_t* __restrict__ wB,   // bf16 [384][128]
        int nOff,
        const float* __restrict__ bias,
        ushort_t* __restrict__ outQ,
        float* __restrict__ outKV) {
    __shared__ __align__(16) unsigned char ash[64 * 272];
    int t = threadIdx.x;
    int lane = t & 63, wv = t >> 6;
    size_t p0 = (size_t)blockIdx.x * 64;
    {
        int row = t >> 2, sub = t & 3;
        const float* src = in + (p0 + row) * 128 + sub * 32;
        float4 v[8];
        float s = 0.f;
#pragma unroll
        for (int j = 0; j < 8; j++) {
            v[j] = *reinterpret_cast<const float4*>(src + j * 4);
            s += v[j].x + v[j].y + v[j].z + v[j].w;
        }
        s += __shfl_xor(s, 1, 64); s += __shfl_xor(s, 2, 64);
        float mean = s * (1.f / 128.f);
        float s2 = 0.f;
#pragma unroll
        for (int j = 0; j < 8; j++) {
            float dx = v[j].x - mean, dy = v[j].y - mean;
            float dz = v[j].z - mean, dw = v[j].w - mean;
            s2 += dx * dx + dy * dy + dz * dz + dw * dw;
        }
        s2 += __shfl_xor(s2, 1, 64); s2 += __shfl_xor(s2, 2, 64);
        float inv = rsqrtf(s2 * (1.f / 128.f) + 1e-6f);
#pragma unroll
        for (int j = 0; j < 8; j++) {
            int c = sub * 32 + j * 4;
            float4 gv = *reinterpret_cast<const float4*>(g + c);
            float4 bv = *reinterpret_cast<const float4*>(beta + c);
            float o0 = (v[j].x - mean) * inv * gv.x + bv.x;
            float o1 = (v[j].y - mean) * inv * gv.y + bv.y;
            float o2 = (v[j].z - mean) * inv * gv.z + bv.z;
            float o3 = (v[j].w - mean) * inv * gv.w + bv.w;
            uint2 pk;
            pk.x = (unsigned)f2bf(o0) | ((unsigned)f2bf(o1) << 16);
            pk.y = (unsigned)f2bf(o2) | ((unsigned)f2bf(o3) << 16);
            *reinterpret_cast<uint2*>(ash + row * 272 + c * 2) = pk;
        }
    }
    __syncthreads();
    int l15 = lane & 15, lg = lane >> 4;
    f32x4 acc[4][NPW];
#pragma unroll
    for (int mt = 0; mt < 4; mt++)
#pragma unroll
        for (int nn = 0; nn < NPW; nn++)
            acc[mt][nn] = (f32x4){0.f, 0.f, 0.f, 0.f};
#pragma unroll
    for (int ks = 0; ks < 4; ks++) {
        bf16x8 af[4];
#pragma unroll
        for (int mt = 0; mt < 4; mt++)
            af[mt] = *reinterpret_cast<const bf16x8*>(
                ash + (mt * 16 + l15) * 272 + ks * 64 + lg * 16);
#pragma unroll
        for (int nn = 0; nn < NPW; nn++) {
            int n = nOff + (wv * NPW + nn) * 16 + l15;
            bf16x8 bfr = *reinterpret_cast<const bf16x8*>(
                wB + (size_t)n * 128 + ks * 32 + lg * 8);
#pragma unroll
            for (int mt = 0; mt < 4; mt++)
                acc[mt][nn] = __builtin_amdgcn_mfma_f32_16x16x32_bf16(
                    af[mt], bfr, acc[mt][nn], 0, 0, 0);
        }
    }
#pragma unroll
    for (int nn = 0; nn < NPW; nn++) {
        int cg = (wv * NPW + nn) * 16 + l15;
        float bv = bias[nOff + cg];
#pragma unroll
        for (int mt = 0; mt < 4; mt++) {
#pragma unroll
            for (int i = 0; i < 4; i++) {
                size_t pix = p0 + mt * 16 + lg * 4 + i;
                float val = acc[mt][nn][i] + bv;
                if (QOUT) outQ[pix * 128 + cg] = f2bf(val * SCALE);
                else      outKV[pix * 256 + cg] = val;
            }
        }
    }
}

// ------------------- exact fp32 window means of LN (routing path)
__global__ __launch_bounds__(256) void win_mean_k(
        const float* __restrict__ t1c, const float* __restrict__ t2c,
        const float* __restrict__ g, const float* __restrict__ beta,
        float* __restrict__ m1, float* __restrict__ m2) {
    __shared__ float mws[4][128];
    int b = blockIdx.y, win = blockIdx.x;
    int wi = win >> 3, wj = win & 7;
    int t = threadIdx.x, lane = t & 63, wv = t >> 6;
    int pixw = lane >> 2, sub = lane & 3;
    int p = wv * 16 + pixw;
    int y = wi * 8 + (p >> 3), x = wj * 8 + (p & 7);
    size_t base = ((size_t)(b * H + y) * W + x) * 128 + sub * 32;
    for (int which = 0; which < 2; which++) {
        const float* src = (which == 0 ? t1c : t2c) + base;
        float4 v[8];
        float s = 0.f;
#pragma unroll
        for (int j = 0; j < 8; j++) {
            v[j] = *reinterpret_cast<const float4*>(src + j * 4);
            s += v[j].x + v[j].y + v[j].z + v[j].w;
        }
        s += __shfl_xor(s, 1, 64); s += __shfl_xor(s, 2, 64);
        float mean = s * (1.f / 128.f);
        float s2 = 0.f;
#pragma unroll
        for (int j = 0; j < 8; j++) {
            float dx = v[j].x - mean, dy = v[j].y - mean;
            float dz = v[j].z - mean, dw = v[j].w - mean;
            s2 += dx * dx + dy * dy + dz * dz + dw * dw;
        }
        s2 += __shfl_xor(s2, 1, 64); s2 += __shfl_xor(s2, 2, 64);
        float inv = rsqrtf(s2 * (1.f / 128.f) + 1e-6f);
#pragma unroll
        for (int j = 0; j < 8; j++) {
            int c = sub * 32 + j * 4;
            float4 gv = *reinterpret_cast<const float4*>(g + c);
            float4 bv = *reinterpret_cast<const float4*>(beta + c);
            v[j].x = (v[j].x - mean) * inv * gv.x + bv.x;
            v[j].y = (v[j].y - mean) * inv * gv.y + bv.y;
            v[j].z = (v[j].z - mean) * inv * gv.z + bv.z;
            v[j].w = (v[j].w - mean) * inv * gv.w + bv.w;
        }
        // reduce across the wave's 16 pixels (lane bits 2..5)
#pragma unroll
        for (int m = 4; m <= 32; m <<= 1) {
#pragma unroll
            for (int j = 0; j < 8; j++) {
                v[j].x += __shfl_xor(v[j].x, m, 64);
                v[j].y += __shfl_xor(v[j].y, m, 64);
                v[j].z += __shfl_xor(v[j].z, m, 64);
                v[j].w += __shfl_xor(v[j].w, m, 64);
            }
        }
        if (pixw == 0) {
#pragma unroll
            for (int j = 0; j < 8; j++)
                *reinterpret_cast<float4*>(&mws[wv][sub * 32 + j * 4]) = v[j];
        }
        __syncthreads();
        if (t < 128) {
            float mval = (mws[0][t] + mws[1][t] + mws[2][t] + mws[3][t]) * (1.f / 64.f);
            (which ? m2 : m1)[((size_t)b * 64 + win) * 128 + t] = mval;
        }
        __syncthreads();
    }
}

// ------------------- fp32 q_win/k_win projection (routing path, exact)
__global__ __launch_bounds__(256) void route_gemm_k(
        const float* __restrict__ m1, const float* __restrict__ m2,
        const float* __restrict__ qkv_w, const float* __restrict__ qkv_b,
        float* __restrict__ qwin, float* __restrict__ kwin) {
    __shared__ float msh[2][8][128];
    int b = blockIdx.y, ch = blockIdx.x;
    int t = threadIdx.x;
    for (int i = t; i < 8 * 128; i += 256) {
        int r = i >> 7, c = i & 127;
        msh[0][r][c] = m1[((size_t)b * 64 + ch * 8 + r) * 128 + c];
        msh[1][r][c] = m2[((size_t)b * 64 + ch * 8 + r) * 128 + c];
    }
    __syncthreads();
    int c = t;
    int which = c >> 7;
    const float* wrow = qkv_w + (size_t)c * 128;
    float acc[8];
#pragma unroll
    for (int r = 0; r < 8; r++) acc[r] = 0.f;
    for (int k = 0; k < 128; k++) {
        float wv_ = wrow[k];
#pragma unroll
        for (int r = 0; r < 8; r++) acc[r] += msh[which][r][k] * wv_;
    }
    float bv = qkv_b[c];
#pragma unroll
    for (int r = 0; r < 8; r++) {
        size_t o = ((size_t)b * 64 + ch * 8 + r) * 128 + (c & 127);
        (which ? kwin : qwin)[o] = acc[r] + bv;
    }
}

// --------------------------------------------- window pooling (kv_pix + v^T bf16)
__global__ __launch_bounds__(256) void pool_k(const float* __restrict__ kv,
                                              float* __restrict__ kv_pix,
                                              ushort_t* __restrict__ kvpT) {
    int b = blockIdx.y, wdw = blockIdx.x;
    int wi = wdw >> 3, wj = wdw & 7;
    int t = threadIdx.x;
    float vals[16];
    for (int ry = 0; ry < 4; ry++)
        for (int rx = 0; rx < 4; rx++) {
            float s = 0.f;
            for (int fy = 0; fy < 2; fy++)
                for (int fx = 0; fx < 2; fx++) {
                    int y = wi * 8 + ry * 2 + fy, x = wj * 8 + rx * 2 + fx;
                    s += kv[((size_t)(b * H + y) * W + x) * 256 + t];
                }
            float mv = s * 0.25f;
            kv_pix[((size_t)(b * 64 + wdw) * 16 + ry * 4 + rx) * 256 + t] = mv;
            vals[ry * 4 + rx] = mv;
        }
    if (t >= 128) {
        union { ushort_t u16[16]; uint4 u4[2]; } pk;
#pragma unroll
        for (int i = 0; i < 16; i++) pk.u16[i] = f2bf(vals[i]);
        size_t base = (((size_t)(b * 64 + wdw)) * 128 + (t - 128)) * 16;
        *reinterpret_cast<uint4*>(kvpT + base) = pk.u4[0];
        *reinterpret_cast<uint4*>(kvpT + base + 8) = pk.u4[1];
    }
}

// ------------------------------------------------ routing logits + top-16
__global__ __launch_bounds__(64) void route_k(const float* __restrict__ q_win,
                                              const float* __restrict__ k_win,
                                              int* __restrict__ r_idx) {
    int b = blockIdx.y, p = blockIdx.x, j = threadIdx.x;
    const float* qp = q_win + (size_t)(b * 64 + p) * 128;
    const float* kp = k_win + (size_t)(b * 64 + j) * 128;
    float lg = 0.f;
    for (int c = 0; c < 128; c++) lg += qp[c] * kp[c];
    lg *= SCALE;
    for (int it = 0; it < TOPK; it++) {
        float v = lg; int idx = j;
#pragma unroll
        for (int m = 32; m > 0; m >>= 1) {
            float ov = __shfl_xor(v, m, 64);
            int   oi = __shfl_xor(idx, m, 64);
            if (ov > v || (ov == v && oi < idx)) { v = ov; idx = oi; }
        }
        if (j == 0) r_idx[(size_t)(b * 64 + p) * TOPK + it] = idx;
        if (j == idx) lg = -__builtin_inff();
    }
}

// -------------------------------------------------- routed attention, bf16 MFMA
__global__ __launch_bounds__(256) void attn_mfma_k(
        const ushort_t* __restrict__ qb,     // bf16 q*SCALE [B,H,W,128]
        const float* __restrict__ kv_pix,    // fp32 [B,64,16,256]
        const ushort_t* __restrict__ kvpT,   // bf16 [B,64,128,16]
        const int* __restrict__ r_idx,
        float* __restrict__ o) {
    __shared__ __align__(16) unsigned char qsh[64 * 272];
    __shared__ __align__(16) unsigned char Ksh[2][256 * 48];
    __shared__ __align__(16) unsigned char VTsh[2][16 * 528];
    __shared__ int ridx_sh[16];
    __shared__ float denom_sh[4][32];

    int b = blockIdx.y, p = blockIdx.x;
    int wi = p >> 3, wj = p & 7;
    int t = threadIdx.x;
    int lane = t & 63, wv = t >> 6;
    int l31 = lane & 31, hi = lane >> 5;

    if (t < 16) ridx_sh[t] = r_idx[(size_t)(b * 64 + p) * TOPK + t];
    for (int i = t; i < 64 * 16; i += 256) {
        int row = i >> 4, seg = i & 15;
        int y = wi * 8 + (row >> 3), x = wj * 8 + (row & 7);
        *reinterpret_cast<uint4*>(qsh + row * 272 + seg * 16) =
            *reinterpret_cast<const uint4*>(qb + ((size_t)(b * H + y) * W + x) * 128 + seg * 8);
    }
    __syncthreads();

    int hh = wv >> 1, qt = wv & 1;

    for (int pair = 0; pair < 4; pair++) {
        __syncthreads();
        // stage K (2 heads): [kp][16d] bf16, row stride 48B
        for (int i = t; i < 2048; i += 256) {
            int h2 = i >> 10, kp = (i >> 2) & 255, q4 = i & 3;
            int reg = ridx_sh[kp >> 4], pos = kp & 15;
            int h = pair * 2 + h2;
            float4 v = *reinterpret_cast<const float4*>(
                kv_pix + (((size_t)(b * 64 + reg) * 16 + pos) * 256) + h * 16 + q4 * 4);
            uint2 pk;
            pk.x = (unsigned)f2bf(v.x) | ((unsigned)f2bf(v.y) << 16);
            pk.y = (unsigned)f2bf(v.z) | ((unsigned)f2bf(v.w) << 16);
            *reinterpret_cast<uint2*>(&Ksh[h2][kp * 48 + q4 * 8]) = pk;
        }
        // stage V^T (2 heads): [d][256 kp] bf16, row stride 528B
        for (int i = t; i < 2048; i += 256) {
            int h2 = i >> 10, d = (i >> 6) & 15, ck = i & 63;
            int sel = ck >> 2, p4 = (ck & 3) * 4;
            int reg = ridx_sh[sel];
            int h = pair * 2 + h2;
            uint2 v = *reinterpret_cast<const uint2*>(
                kvpT + (((size_t)(b * 64 + reg) * 128) + h * 16 + d) * 16 + p4);
            *reinterpret_cast<uint2*>(&VTsh[h2][d * 528 + (sel * 16 + p4) * 2]) = v;
        }
        __syncthreads();

        int h = pair * 2 + hh;
        bf16x8 qf = *reinterpret_cast<const bf16x8*>(
            qsh + (qt * 32 + l31) * 272 + h * 32 + hi * 16);
        float m_run = -INFINITY, l_run = 0.f;
        f32x16 opv;
#pragma unroll
        for (int r = 0; r < 16; r++) opv[r] = 0.f;
        f32x16 zf;
#pragma unroll
        for (int r = 0; r < 16; r++) zf[r] = 0.f;

        for (int t8 = 0; t8 < 8; t8++) {
            bf16x8 kf = *reinterpret_cast<const bf16x8*>(
                &Ksh[hh][(t8 * 32 + l31) * 48 + hi * 16]);
            f32x16 S = __builtin_amdgcn_mfma_f32_32x32x16_bf16(kf, qf, zf, 0, 0, 0);
            float tm = S[0];
#pragma unroll
            for (int r = 1; r < 16; r++) tm = fmaxf(tm, S[r]);
            tm = fmaxf(tm, __shfl_xor(tm, 32, 64));
            float m_new = fmaxf(m_run, tm);
            float corr = __expf(m_run - m_new);
            float p_[16], psum = 0.f;
#pragma unroll
            for (int r = 0; r < 16; r++) { p_[r] = __expf(S[r] - m_new); psum += p_[r]; }
            psum += __shfl_xor(psum, 32, 64);
            l_run = l_run * corr + psum;
            m_run = m_new;
#pragma unroll
            for (int r = 0; r < 16; r++) opv[r] *= corr;
            unsigned w_[8], pw_[8];
#pragma unroll
            for (int j = 0; j < 8; j++)
                w_[j] = (__float_as_uint(p_[2 * j]) >> 16) |
                        (__float_as_uint(p_[2 * j + 1]) & 0xFFFF0000u);
#pragma unroll
            for (int j = 0; j < 8; j++) pw_[j] = __shfl_xor(w_[j], 32, 64);
            union { unsigned u[4]; bf16x8 v; } fa0, fa1;
            fa0.u[0] = hi ? pw_[2] : w_[0];
            fa0.u[1] = hi ? pw_[3] : w_[1];
            fa0.u[2] = hi ? w_[2]  : pw_[0];
            fa0.u[3] = hi ? w_[3]  : pw_[1];
            fa1.u[0] = hi ? pw_[6] : w_[4];
            fa1.u[1] = hi ? pw_[7] : w_[5];
            fa1.u[2] = hi ? w_[6]  : pw_[4];
            fa1.u[3] = hi ? w_[7]  : pw_[5];
            const unsigned char* vb = &VTsh[hh][(l31 & 15) * 528 + t8 * 64];
            bf16x8 bf0 = *reinterpret_cast<const bf16x8*>(vb + hi * 16);
            bf16x8 bf1 = *reinterpret_cast<const bf16x8*>(vb + 32 + hi * 16);
            opv = __builtin_amdgcn_mfma_f32_32x32x16_bf16(fa0.v, bf0, opv, 0, 0, 0);
            opv = __builtin_amdgcn_mfma_f32_32x32x16_bf16(fa1.v, bf1, opv, 0, 0, 0);
        }
        denom_sh[wv][l31] = l_run;   // both hi-halves write identical value
        if (l31 < 16) {
#pragma unroll
            for (int r = 0; r < 16; r++) {
                int qr = (r & 3) + 8 * (r >> 2) + 4 * hi;
                float invd = 1.f / denom_sh[wv][qr];
                int q = qt * 32 + qr;
                int y = wi * 8 + (q >> 3), x = wj * 8 + (q & 7);
                o[((size_t)(b * H + y) * W + x) * 128 + h * 16 + l31] = opv[r] * invd;
            }
        }
    }
}

// ------------------------------------------------- LePE depthwise 5x5, o +=
__global__ __launch_bounds__(128) void lepe_k(const float* __restrict__ kv,
                                              const float* __restrict__ w,
                                              const float* __restrict__ bias,
                                              float* __restrict__ o) {
    int x = blockIdx.x, y = blockIdx.y, b = blockIdx.z;
    int c = threadIdx.x;
    float acc = bias[c];
#pragma unroll
    for (int dy = 0; dy < 5; dy++) {
        int yy = y + dy - 2;
        if (yy < 0 || yy >= H) continue;
#pragma unroll
        for (int dx = 0; dx < 5; dx++) {
            int xx = x + dx - 2;
            if (xx < 0 || xx >= W) continue;
            acc += kv[((size_t)(b * H + yy) * W + xx) * 256 + 128 + c] * w[c * 25 + dy * 5 + dx];
        }
    }
    size_t pix = (size_t)(b * H + y) * W + x;
    o[pix * 128 + c] += acc;
}

// ---------------------------------- (o @ Wo^T + b) + x, write NCHW output
__global__ __launch_bounds__(128) void epilogue_k(const float* __restrict__ o,
                                                  const float* __restrict__ xbuf,
                                                  const float* __restrict__ woT,
                                                  const float* __restrict__ wo_b,
                                                  float* __restrict__ out) {
    __shared__ float ot[16][128];
    __shared__ float res[128][17];
    int b = blockIdx.z, y = blockIdx.y, x0 = blockIdx.x * 16;
    int t = threadIdx.x;
    size_t pixBase = (size_t)(b * H + y) * W + x0;
    for (int p = 0; p < 16; p++) ot[p][t] = o[(pixBase + p) * 128 + t];
    __syncthreads();
    float acc[16];
    float wb = wo_b[t];
#pragma unroll
    for (int p = 0; p < 16; p++) acc[p] = wb + xbuf[(pixBase + p) * 128 + t];
    for (int k = 0; k < 128; k += 4) {
        float w0 = woT[(k + 0) * 128 + t];
        float w1 = woT[(k + 1) * 128 + t];
        float w2 = woT[(k + 2) * 128 + t];
        float w3 = woT[(k + 3) * 128 + t];
#pragma unroll
        for (int p = 0; p < 16; p++) {
            const float4 av = *reinterpret_cast<const float4*>(&ot[p][k]);
            acc[p] += av.x * w0 + av.y * w1 + av.z * w2 + av.w * w3;
        }
    }
#pragma unroll
    for (int p = 0; p < 16; p++) res[t][p] = acc[p];
    __syncthreads();
    int xi = t & 15, cg = t >> 4;
    for (int i = 0; i < 16; i++) {
        int c = cg * 16 + i;
        out[((size_t)(b * C + c) * H + y) * W + x0 + xi] = res[c][xi];
    }
}

extern "C" void kernel_launch(void* const* d_in, const int* in_sizes, int n_in,
                              void* d_out, int out_size, void* d_ws, size_t ws_size,
                              hipStream_t stream) {
    const float* t1      = (const float*)d_in[0];
    const float* t2      = (const float*)d_in[1];
    const float* pos_w   = (const float*)d_in[2];
    const float* pos_b   = (const float*)d_in[3];
    const float* cat_w   = (const float*)d_in[4];
    const float* cat_b   = (const float*)d_in[5];
    const float* ln_cat_g= (const float*)d_in[6];
    const float* ln_cat_b= (const float*)d_in[7];
    const float* ln1_g   = (const float*)d_in[8];
    const float* ln1_b   = (const float*)d_in[9];
    const float* qkv_w   = (const float*)d_in[10];
    const float* qkv_b   = (const float*)d_in[11];
    const float* lepe_w  = (const float*)d_in[12];
    const float* lepe_b  = (const float*)d_in[13];
    const float* wo_w    = (const float*)d_in[14];
    const float* wo_b    = (const float*)d_in[15];

    float* ws    = (float*)d_ws;
    float* t1c   = ws + OFF_T1C;
    float* t2c   = ws + OFF_T2C;
    float* xbuf  = ws + OFF_X;
    ushort_t* qbuf = (ushort_t*)(ws + OFF_QB);
    float* kvbuf = ws + OFF_KV;
    float* kvpix = ws + OFF_KVP;
    ushort_t* kvpT = (ushort_t*)(ws + OFF_KVPT);
    float* m1    = ws + OFF_M1;
    float* m2    = ws + OFF_M2;
    float* qwin  = ws + OFF_QW;
    float* kwin  = ws + OFF_KW;
    int*   ridx  = (int*)(ws + OFF_RIDX);
    ushort_t* wcatB = (ushort_t*)(ws + OFF_WCB);
    ushort_t* qkvB  = (ushort_t*)(ws + OFF_QKVB);
    float* woT   = ws + OFF_WOT;
    float* obuf  = ws + OFF_O;   // alias of t1c
    float* out   = (float*)d_out;

    transpose_weights<<<dim3((36 * 128 * 72 + 255) / 256), 256, 0, stream>>>(
        qkv_w, wo_w, cat_w, qkvB, woT, wcatB);
    pos_conv_k<<<dim3(2, 4, B * H), 256, 0, stream>>>(t1, pos_w, pos_b, t1c);
    pos_conv_k<<<dim3(2, 4, B * H), 256, 0, stream>>>(t2, pos_w, pos_b, t2c);
    catconv_mfma_k<<<dim3(4, 8, 8), 256, 0, stream>>>(
        t1c, t2c, wcatB, cat_b, ln_cat_g, ln_cat_b, xbuf);
    win_mean_k<<<dim3(64, B), 256, 0, stream>>>(t1c, t2c, ln1_g, ln1_b, m1, m2);
    route_gemm_k<<<dim3(8, B), 256, 0, stream>>>(m1, m2, qkv_w, qkv_b, qwin, kwin);
    route_k<<<dim3(64, B), 64, 0, stream>>>(qwin, kwin, ridx);
    ln_qkv_mfma_k<2, true><<<dim3(512), 256, 0, stream>>>(
        t1c, ln1_g, ln1_b, qkvB, 0, qkv_b, qbuf, nullptr);
    ln_qkv_mfma_k<4, false><<<dim3(512), 256, 0, stream>>>(
        t2c, ln1_g, ln1_b, qkvB, 128, qkv_b, nullptr, kvbuf);
    pool_k<<<dim3(64, B), 256, 0, stream>>>(kvbuf, kvpix, kvpT);
    attn_mfma_k<<<dim3(64, B), 256, 0, stream>>>(qbuf, kvpix, kvpT, ridx, obuf);
    lepe_k<<<dim3(W, H, B), 128, 0, stream>>>(kvbuf, lepe_w, lepe_b, obuf);
    epilogue_k<<<dim3(4, 64, 8), 128, 0, stream>>>(obuf, xbuf, woT, wo_b, out);
}

// Round 4
// 291.095 us; speedup vs baseline: 3.6484x; 1.2899x over previous
//
#include <hip/hip_runtime.h>
#include <math.h>

typedef unsigned short ushort_t;
typedef __attribute__((ext_vector_type(4))) float f32x4;
typedef __attribute__((ext_vector_type(16))) float f32x16;
typedef __attribute__((ext_vector_type(8))) short bf16x8;

constexpr int B = 8, C = 128, H = 64, W = 64;
constexpr int HEADS = 8, TOPK = 16;
constexpr int P2 = 64;
constexpr float SCALE = 0.0883883476483184405f; // 128^-0.5

// workspace offsets (in floats)
constexpr size_t NPIX    = (size_t)B * H * W;            // 32768
constexpr size_t OFF_T1C = 0;                            // NHWC fp32 (B,H,W,128)
constexpr size_t OFF_T2C = OFF_T1C + NPIX * 128;
constexpr size_t OFF_X   = OFF_T2C + NPIX * 128;         // relu(LN(catconv)) fp32
constexpr size_t OFF_QB  = OFF_X   + NPIX * 128;         // q*SCALE bf16 (NPIX*128 shorts)
constexpr size_t OFF_KV  = OFF_QB  + NPIX * 64;          // kv fp32 (B,H,W,256)
constexpr size_t OFF_KVP = OFF_KV  + NPIX * 256;         // kv_pix fp32 (B,64,16,256)
constexpr size_t OFF_KVPT= OFF_KVP + (size_t)B * P2 * 16 * 256; // v^T bf16 [B,64,128,16]
constexpr size_t OFF_M1  = OFF_KVPT+ (size_t)B * P2 * 128 * 16 / 2;
constexpr size_t OFF_M2  = OFF_M1  + (size_t)B * P2 * 128;
constexpr size_t OFF_QW  = OFF_M2  + (size_t)B * P2 * 128;
constexpr size_t OFF_KW  = OFF_QW  + (size_t)B * P2 * 128;
constexpr size_t OFF_RIDX= OFF_KW  + (size_t)B * P2 * 128;      // int
constexpr size_t OFF_WCB = OFF_RIDX+ (size_t)B * P2 * TOPK;     // wcatB bf16 [36][128][72]
constexpr size_t OFF_QKVB= OFF_WCB + (size_t)9 * 256 * 128;     // qkv_w bf16 [384][128]
constexpr size_t OFF_WOT = OFF_QKVB+ (size_t)384 * 128 / 2;     // [128][128] fp32
constexpr size_t OFF_O   = OFF_T1C;  // attention output aliases t1c
constexpr size_t OFF_VPL = OFF_T2C;  // v planes fp32 [B][C][64][64] alias t2c (dead)
constexpr size_t OFF_LEP = OFF_KV;   // lepe planes fp32 [B][C][64][64] alias kvbuf (dead)

// catconv MFMA geometry
constexpr int HALO_B = 10 * 18 * 144;
constexpr int WT_B   = 128 * 144;
constexpr int NSTAGE = 36;

__device__ inline ushort_t f2bf(float f) {
    unsigned u = __float_as_uint(f);
    unsigned r = u + 0x7FFFu + ((u >> 16) & 1u);
    return (ushort_t)(r >> 16);
}

// ---------------------------------------------------------------- weights prep
__global__ void transpose_weights(const float* __restrict__ qkv_w,
                                  const float* __restrict__ wo_w,
                                  const float* __restrict__ cat_w,
                                  ushort_t* __restrict__ qkvB,
                                  float* __restrict__ woT,
                                  ushort_t* __restrict__ wcatB) {
    int idx = blockIdx.x * 256 + threadIdx.x;
    if (idx < 384 * 128) {           // qkvB[n][k] bf16 (same layout as qkv_w)
        qkvB[idx] = f2bf(qkv_w[idx]);
    }
    if (idx < 128 * 128) {           // woT[k][n] = wo_w[n][k]
        int k = idx / 128, n = idx % 128;
        woT[idx] = wo_w[n * 128 + k];
    }
    if (idx < 36 * 128 * 72) {       // wcatB[stage][co][ci72] bf16, stage = qq*9+dd
        int ci = idx % 72;
        int r  = idx / 72;
        int co = r & 127;
        int sdd = r >> 7;
        int qq = sdd / 9, dd = sdd - qq * 9;
        float v = 0.f;
        if (ci < 64)
            v = cat_w[((size_t)co * 256 + qq * 64 + ci) * 9 + dd];
        wcatB[idx] = f2bf(v);
    }
}

// --------------------------------------- depthwise 3x3 + residual, NCHW->NHWC
__global__ __launch_bounds__(256) void pos_conv_k(const float* __restrict__ in,
                                                  const float* __restrict__ w,
                                                  const float* __restrict__ bias,
                                                  float* __restrict__ outNHWC) {
    __shared__ float tile[32][33];
    int b = blockIdx.z / H, y = blockIdx.z % H;
    int c0 = blockIdx.y * 32, x0 = blockIdx.x * 32;
    int tx = threadIdx.x & 31, tg = threadIdx.x >> 5;
    for (int i = 0; i < 4; i++) {
        int cl = tg * 4 + i, c = c0 + cl;
        const float* base = in + (size_t)(b * C + c) * H * W;
        float acc = base[y * W + x0 + tx];
        float wv[9];
#pragma unroll
        for (int j = 0; j < 9; j++) wv[j] = w[c * 9 + j];
#pragma unroll
        for (int dy = 0; dy < 3; dy++) {
            int yy = y + dy - 1;
            if (yy < 0 || yy >= H) continue;
#pragma unroll
            for (int dx = 0; dx < 3; dx++) {
                int xx = x0 + tx + dx - 1;
                if (xx < 0 || xx >= W) continue;
                acc += base[yy * W + xx] * wv[dy * 3 + dx];
            }
        }
        tile[cl][tx] = acc + bias[c];
    }
    __syncthreads();
    for (int i = 0; i < 4; i++) {
        int xl = tg * 4 + i;
        outNHWC[((size_t)(b * H + y) * W + x0 + xl) * 128 + c0 + tx] = tile[tx][xl];
    }
}

// ------------------ cat-conv 256->128 3x3 implicit-GEMM MFMA + fused LN+ReLU
__device__ inline void stage_halo(int qq, int b, int y0, int x0, int t,
                                  const float* __restrict__ t1c,
                                  const float* __restrict__ t2c,
                                  unsigned char* smem) {
    const float* src = (qq < 2 ? t1c : t2c) + (qq & 1) * 64;
    for (int e = t; e < 180 * 16; e += 256) {
        int pix = e >> 4, c4 = e & 15;
        int hy = pix / 18, hx = pix - hy * 18;
        int gy = y0 - 1 + hy, gx = x0 - 1 + hx;
        float4 v = make_float4(0.f, 0.f, 0.f, 0.f);
        if (gy >= 0 && gy < H && gx >= 0 && gx < W)
            v = *reinterpret_cast<const float4*>(
                src + ((size_t)(b * H + gy) * W + gx) * 128 + c4 * 4);
        uint2 pk;
        pk.x = (unsigned)f2bf(v.x) | ((unsigned)f2bf(v.y) << 16);
        pk.y = (unsigned)f2bf(v.z) | ((unsigned)f2bf(v.w) << 16);
        *reinterpret_cast<uint2*>(smem + pix * 144 + c4 * 8) = pk;
    }
}

__global__ __launch_bounds__(256) void catconv_mfma_k(
        const float* __restrict__ t1c, const float* __restrict__ t2c,
        const ushort_t* __restrict__ wcatB,
        const float* __restrict__ cat_b,
        const float* __restrict__ g, const float* __restrict__ beta,
        float* __restrict__ xbuf) {
    __shared__ __align__(16) unsigned char smem[HALO_B + 2 * WT_B];
    int t = threadIdx.x;
    int lane = t & 63, wv = t >> 6;
    int wr = wv >> 1, wc = wv & 1;
    int l15 = lane & 15, lg = lane >> 4;
    int b = blockIdx.z, y0 = blockIdx.y * 8, x0 = blockIdx.x * 16;

    f32x4 acc[4][4];
#pragma unroll
    for (int r = 0; r < 4; r++)
#pragma unroll
        for (int cf = 0; cf < 4; cf++)
            acc[r][cf] = (f32x4){0.f, 0.f, 0.f, 0.f};

    unsigned long long wreg[9];
    {
        const unsigned long long* wsrc = (const unsigned long long*)wcatB;
#pragma unroll
        for (int j = 0; j < 9; j++) wreg[j] = wsrc[t + j * 256];
    }

    for (int s = 0; s < NSTAGE; s++) {
        if ((s % 9) == 0) {
            __syncthreads();
            stage_halo(s / 9, b, y0, x0, t, t1c, t2c, smem);
        }
        {
            unsigned char* wdst = smem + HALO_B + (s & 1) * WT_B;
#pragma unroll
            for (int j = 0; j < 9; j++)
                *reinterpret_cast<unsigned long long*>(wdst + (t + j * 256) * 8) = wreg[j];
        }
        if (s + 1 < NSTAGE) {
            const unsigned long long* wsrc =
                (const unsigned long long*)(wcatB + (size_t)(s + 1) * 128 * 72);
#pragma unroll
            for (int j = 0; j < 9; j++) wreg[j] = wsrc[t + j * 256];
        }
        __syncthreads();

        int dd = s % 9;
        int dy = dd / 3, dx = dd - dy * 3;
        const unsigned char* wb = smem + HALO_B + (s & 1) * WT_B;
#pragma unroll
        for (int kk = 0; kk < 2; kk++) {
            bf16x8 af[4], bfr[4];
#pragma unroll
            for (int r = 0; r < 4; r++)
                af[r] = *reinterpret_cast<const bf16x8*>(
                    smem + ((wr * 4 + r + dy) * 18 + l15 + dx) * 144 + kk * 64 + lg * 16);
#pragma unroll
            for (int cf = 0; cf < 4; cf++)
                bfr[cf] = *reinterpret_cast<const bf16x8*>(
                    wb + (wc * 64 + cf * 16 + l15) * 144 + kk * 64 + lg * 16);
#pragma unroll
            for (int r = 0; r < 4; r++)
#pragma unroll
                for (int cf = 0; cf < 4; cf++)
                    acc[r][cf] = __builtin_amdgcn_mfma_f32_16x16x32_bf16(
                        af[r], bfr[cf], acc[r][cf], 0, 0, 0);
        }
    }

    __syncthreads();
    float* res = (float*)smem;
    float* mstat = (float*)(smem + 64 * 132 * 4);
    for (int h = 0; h < 2; h++) {
        if (wr == h) {
#pragma unroll
            for (int cf = 0; cf < 4; cf++) {
                int n = wc * 64 + cf * 16 + l15;
                float cb = cat_b[n];
#pragma unroll
                for (int r = 0; r < 4; r++)
#pragma unroll
                    for (int i = 0; i < 4; i++)
                        res[(r * 16 + lg * 4 + i) * 132 + n] = acc[r][cf][i] + cb;
            }
        }
        __syncthreads();
        int pix = t >> 2, sub = t & 3;
        float s1 = 0.f;
#pragma unroll
        for (int j = 0; j < 32; j++) s1 += res[pix * 132 + sub + j * 4];
        s1 += __shfl_xor(s1, 1, 64);
        s1 += __shfl_xor(s1, 2, 64);
        float mean = s1 * (1.f / 128.f);
        float s2 = 0.f;
#pragma unroll
        for (int j = 0; j < 32; j++) {
            float d = res[pix * 132 + sub + j * 4] - mean;
            s2 += d * d;
        }
        s2 += __shfl_xor(s2, 1, 64);
        s2 += __shfl_xor(s2, 2, 64);
        float inv = rsqrtf(s2 * (1.f / 128.f) + 1e-5f);
        if (sub == 0) { mstat[pix] = mean; mstat[64 + pix] = inv; }
        __syncthreads();
        int c = t & 127, pr = t >> 7;
        float gg = g[c], bb = beta[c];
        for (int j = 0; j < 32; j++) {
            int p2 = j * 2 + pr;
            float v = (res[p2 * 132 + c] - mstat[p2]) * mstat[64 + p2] * gg + bb;
            int gp = h * 64 + p2;
            int py = gp >> 4, px = gp & 15;
            xbuf[((size_t)(b * H + y0 + py) * W + x0 + px) * 128 + c] = fmaxf(v, 0.f);
        }
        __syncthreads();
    }
}

// ------------------------ LN(1e-6) + QKV projection, bf16 MFMA (M=64 per block)
template<int NPW, bool QOUT>
__global__ __launch_bounds__(256) void ln_qkv_mfma_k(
        const float* __restrict__ in,
        const float* __restrict__ g, const float* __restrict__ beta,
        const ushort_t* __restrict__ wB,   // bf16 [384][128]
        int nOff,
        const float* __restrict__ bias,
        ushort_t* __restrict__ outQ,
        float* __restrict__ outKV) {
    __shared__ __align__(16) unsigned char ash[64 * 272];
    int t = threadIdx.x;
    int lane = t & 63, wv = t >> 6;
    size_t p0 = (size_t)blockIdx.x * 64;
    {
        int row = t >> 2, sub = t & 3;
        const float* src = in + (p0 + row) * 128 + sub * 32;
        float4 v[8];
        float s = 0.f;
#pragma unroll
        for (int j = 0; j < 8; j++) {
            v[j] = *reinterpret_cast<const float4*>(src + j * 4);
            s += v[j].x + v[j].y + v[j].z + v[j].w;
        }
        s += __shfl_xor(s, 1, 64); s += __shfl_xor(s, 2, 64);
        float mean = s * (1.f / 128.f);
        float s2 = 0.f;
#pragma unroll
        for (int j = 0; j < 8; j++) {
            float dx = v[j].x - mean, dy = v[j].y - mean;
            float dz = v[j].z - mean, dw = v[j].w - mean;
            s2 += dx * dx + dy * dy + dz * dz + dw * dw;
        }
        s2 += __shfl_xor(s2, 1, 64); s2 += __shfl_xor(s2, 2, 64);
        float inv = rsqrtf(s2 * (1.f / 128.f) + 1e-6f);
#pragma unroll
        for (int j = 0; j < 8; j++) {
            int c = sub * 32 + j * 4;
            float4 gv = *reinterpret_cast<const float4*>(g + c);
            float4 bv = *reinterpret_cast<const float4*>(beta + c);
            float o0 = (v[j].x - mean) * inv * gv.x + bv.x;
            float o1 = (v[j].y - mean) * inv * gv.y + bv.y;
            float o2 = (v[j].z - mean) * inv * gv.z + bv.z;
            float o3 = (v[j].w - mean) * inv * gv.w + bv.w;
            uint2 pk;
            pk.x = (unsigned)f2bf(o0) | ((unsigned)f2bf(o1) << 16);
            pk.y = (unsigned)f2bf(o2) | ((unsigned)f2bf(o3) << 16);
            *reinterpret_cast<uint2*>(ash + row * 272 + c * 2) = pk;
        }
    }
    __syncthreads();
    int l15 = lane & 15, lg = lane >> 4;
    f32x4 acc[4][NPW];
#pragma unroll
    for (int mt = 0; mt < 4; mt++)
#pragma unroll
        for (int nn = 0; nn < NPW; nn++)
            acc[mt][nn] = (f32x4){0.f, 0.f, 0.f, 0.f};
#pragma unroll
    for (int ks = 0; ks < 4; ks++) {
        bf16x8 af[4];
#pragma unroll
        for (int mt = 0; mt < 4; mt++)
            af[mt] = *reinterpret_cast<const bf16x8*>(
                ash + (mt * 16 + l15) * 272 + ks * 64 + lg * 16);
#pragma unroll
        for (int nn = 0; nn < NPW; nn++) {
            int n = nOff + (wv * NPW + nn) * 16 + l15;
            bf16x8 bfr = *reinterpret_cast<const bf16x8*>(
                wB + (size_t)n * 128 + ks * 32 + lg * 8);
#pragma unroll
            for (int mt = 0; mt < 4; mt++)
                acc[mt][nn] = __builtin_amdgcn_mfma_f32_16x16x32_bf16(
                    af[mt], bfr, acc[mt][nn], 0, 0, 0);
        }
    }
#pragma unroll
    for (int nn = 0; nn < NPW; nn++) {
        int cg = (wv * NPW + nn) * 16 + l15;
        float bv = bias[nOff + cg];
#pragma unroll
        for (int mt = 0; mt < 4; mt++) {
#pragma unroll
            for (int i = 0; i < 4; i++) {
                size_t pix = p0 + mt * 16 + lg * 4 + i;
                float val = acc[mt][nn][i] + bv;
                if (QOUT) outQ[pix * 128 + cg] = f2bf(val * SCALE);
                else      outKV[pix * 256 + cg] = val;
            }
        }
    }
}

// ------------------- exact fp32 window means of LN (routing path)
__global__ __launch_bounds__(256) void win_mean_k(
        const float* __restrict__ t1c, const float* __restrict__ t2c,
        const float* __restrict__ g, const float* __restrict__ beta,
        float* __restrict__ m1, float* __restrict__ m2) {
    __shared__ float mws[4][128];
    int b = blockIdx.y, win = blockIdx.x;
    int wi = win >> 3, wj = win & 7;
    int t = threadIdx.x, lane = t & 63, wv = t >> 6;
    int pixw = lane >> 2, sub = lane & 3;
    int p = wv * 16 + pixw;
    int y = wi * 8 + (p >> 3), x = wj * 8 + (p & 7);
    size_t base = ((size_t)(b * H + y) * W + x) * 128 + sub * 32;
    for (int which = 0; which < 2; which++) {
        const float* src = (which == 0 ? t1c : t2c) + base;
        float4 v[8];
        float s = 0.f;
#pragma unroll
        for (int j = 0; j < 8; j++) {
            v[j] = *reinterpret_cast<const float4*>(src + j * 4);
            s += v[j].x + v[j].y + v[j].z + v[j].w;
        }
        s += __shfl_xor(s, 1, 64); s += __shfl_xor(s, 2, 64);
        float mean = s * (1.f / 128.f);
        float s2 = 0.f;
#pragma unroll
        for (int j = 0; j < 8; j++) {
            float dx = v[j].x - mean, dy = v[j].y - mean;
            float dz = v[j].z - mean, dw = v[j].w - mean;
            s2 += dx * dx + dy * dy + dz * dz + dw * dw;
        }
        s2 += __shfl_xor(s2, 1, 64); s2 += __shfl_xor(s2, 2, 64);
        float inv = rsqrtf(s2 * (1.f / 128.f) + 1e-6f);
#pragma unroll
        for (int j = 0; j < 8; j++) {
            int c = sub * 32 + j * 4;
            float4 gv = *reinterpret_cast<const float4*>(g + c);
            float4 bv = *reinterpret_cast<const float4*>(beta + c);
            v[j].x = (v[j].x - mean) * inv * gv.x + bv.x;
            v[j].y = (v[j].y - mean) * inv * gv.y + bv.y;
            v[j].z = (v[j].z - mean) * inv * gv.z + bv.z;
            v[j].w = (v[j].w - mean) * inv * gv.w + bv.w;
        }
#pragma unroll
        for (int m = 4; m <= 32; m <<= 1) {
#pragma unroll
            for (int j = 0; j < 8; j++) {
                v[j].x += __shfl_xor(v[j].x, m, 64);
                v[j].y += __shfl_xor(v[j].y, m, 64);
                v[j].z += __shfl_xor(v[j].z, m, 64);
                v[j].w += __shfl_xor(v[j].w, m, 64);
            }
        }
        if (pixw == 0) {
#pragma unroll
            for (int j = 0; j < 8; j++)
                *reinterpret_cast<float4*>(&mws[wv][sub * 32 + j * 4]) = v[j];
        }
        __syncthreads();
        if (t < 128) {
            float mval = (mws[0][t] + mws[1][t] + mws[2][t] + mws[3][t]) * (1.f / 64.f);
            (which ? m2 : m1)[((size_t)b * 64 + win) * 128 + t] = mval;
        }
        __syncthreads();
    }
}

// ------------------- fp32 q_win/k_win projection (routing path, exact)
__global__ __launch_bounds__(256) void route_gemm_k(
        const float* __restrict__ m1, const float* __restrict__ m2,
        const float* __restrict__ qkv_w, const float* __restrict__ qkv_b,
        float* __restrict__ qwin, float* __restrict__ kwin) {
    __shared__ float msh[2][8][128];
    int b = blockIdx.y, ch = blockIdx.x;
    int t = threadIdx.x;
    for (int i = t; i < 8 * 128; i += 256) {
        int r = i >> 7, c = i & 127;
        msh[0][r][c] = m1[((size_t)b * 64 + ch * 8 + r) * 128 + c];
        msh[1][r][c] = m2[((size_t)b * 64 + ch * 8 + r) * 128 + c];
    }
    __syncthreads();
    int c = t;
    int which = c >> 7;
    const float* wrow = qkv_w + (size_t)c * 128;
    float acc[8];
#pragma unroll
    for (int r = 0; r < 8; r++) acc[r] = 0.f;
    for (int k = 0; k < 128; k++) {
        float wv_ = wrow[k];
#pragma unroll
        for (int r = 0; r < 8; r++) acc[r] += msh[which][r][k] * wv_;
    }
    float bv = qkv_b[c];
#pragma unroll
    for (int r = 0; r < 8; r++) {
        size_t o = ((size_t)b * 64 + ch * 8 + r) * 128 + (c & 127);
        (which ? kwin : qwin)[o] = acc[r] + bv;
    }
}

// --------------------------------------------- window pooling (kv_pix + v^T bf16)
__global__ __launch_bounds__(256) void pool_k(const float* __restrict__ kv,
                                              float* __restrict__ kv_pix,
                                              ushort_t* __restrict__ kvpT) {
    int b = blockIdx.y, wdw = blockIdx.x;
    int wi = wdw >> 3, wj = wdw & 7;
    int t = threadIdx.x;
    float vals[16];
    for (int ry = 0; ry < 4; ry++)
        for (int rx = 0; rx < 4; rx++) {
            float s = 0.f;
            for (int fy = 0; fy < 2; fy++)
                for (int fx = 0; fx < 2; fx++) {
                    int y = wi * 8 + ry * 2 + fy, x = wj * 8 + rx * 2 + fx;
                    s += kv[((size_t)(b * H + y) * W + x) * 256 + t];
                }
            float mv = s * 0.25f;
            kv_pix[((size_t)(b * 64 + wdw) * 16 + ry * 4 + rx) * 256 + t] = mv;
            vals[ry * 4 + rx] = mv;
        }
    if (t >= 128) {
        union { ushort_t u16[16]; uint4 u4[2]; } pk;
#pragma unroll
        for (int i = 0; i < 16; i++) pk.u16[i] = f2bf(vals[i]);
        size_t base = (((size_t)(b * 64 + wdw)) * 128 + (t - 128)) * 16;
        *reinterpret_cast<uint4*>(kvpT + base) = pk.u4[0];
        *reinterpret_cast<uint4*>(kvpT + base + 8) = pk.u4[1];
    }
}

// ------------------------------------------------ routing logits + top-16
__global__ __launch_bounds__(64) void route_k(const float* __restrict__ q_win,
                                              const float* __restrict__ k_win,
                                              int* __restrict__ r_idx) {
    int b = blockIdx.y, p = blockIdx.x, j = threadIdx.x;
    const float* qp = q_win + (size_t)(b * 64 + p) * 128;
    const float* kp = k_win + (size_t)(b * 64 + j) * 128;
    float lg = 0.f;
    for (int c = 0; c < 128; c++) lg += qp[c] * kp[c];
    lg *= SCALE;
    for (int it = 0; it < TOPK; it++) {
        float v = lg; int idx = j;
#pragma unroll
        for (int m = 32; m > 0; m >>= 1) {
            float ov = __shfl_xor(v, m, 64);
            int   oi = __shfl_xor(idx, m, 64);
            if (ov > v || (ov == v && oi < idx)) { v = ov; idx = oi; }
        }
        if (j == 0) r_idx[(size_t)(b * 64 + p) * TOPK + it] = idx;
        if (j == idx) lg = -__builtin_inff();
    }
}

// -------------------------------------------------- routed attention, bf16 MFMA
__global__ __launch_bounds__(256) void attn_mfma_k(
        const ushort_t* __restrict__ qb,     // bf16 q*SCALE [B,H,W,128]
        const float* __restrict__ kv_pix,    // fp32 [B,64,16,256]
        const ushort_t* __restrict__ kvpT,   // bf16 [B,64,128,16]
        const int* __restrict__ r_idx,
        float* __restrict__ o) {
    __shared__ __align__(16) unsigned char qsh[64 * 272];
    __shared__ __align__(16) unsigned char Ksh[2][256 * 48];
    __shared__ __align__(16) unsigned char VTsh[2][16 * 528];
    __shared__ int ridx_sh[16];
    __shared__ float denom_sh[4][32];

    int b = blockIdx.y, p = blockIdx.x;
    int wi = p >> 3, wj = p & 7;
    int t = threadIdx.x;
    int lane = t & 63, wv = t >> 6;
    int l31 = lane & 31, hi = lane >> 5;

    if (t < 16) ridx_sh[t] = r_idx[(size_t)(b * 64 + p) * TOPK + t];
    for (int i = t; i < 64 * 16; i += 256) {
        int row = i >> 4, seg = i & 15;
        int y = wi * 8 + (row >> 3), x = wj * 8 + (row & 7);
        *reinterpret_cast<uint4*>(qsh + row * 272 + seg * 16) =
            *reinterpret_cast<const uint4*>(qb + ((size_t)(b * H + y) * W + x) * 128 + seg * 8);
    }
    __syncthreads();

    int hh = wv >> 1, qt = wv & 1;

    for (int pair = 0; pair < 4; pair++) {
        __syncthreads();
        for (int i = t; i < 2048; i += 256) {
            int h2 = i >> 10, kp = (i >> 2) & 255, q4 = i & 3;
            int reg = ridx_sh[kp >> 4], pos = kp & 15;
            int h = pair * 2 + h2;
            float4 v = *reinterpret_cast<const float4*>(
                kv_pix + (((size_t)(b * 64 + reg) * 16 + pos) * 256) + h * 16 + q4 * 4);
            uint2 pk;
            pk.x = (unsigned)f2bf(v.x) | ((unsigned)f2bf(v.y) << 16);
            pk.y = (unsigned)f2bf(v.z) | ((unsigned)f2bf(v.w) << 16);
            *reinterpret_cast<uint2*>(&Ksh[h2][kp * 48 + q4 * 8]) = pk;
        }
        for (int i = t; i < 2048; i += 256) {
            int h2 = i >> 10, d = (i >> 6) & 15, ck = i & 63;
            int sel = ck >> 2, p4 = (ck & 3) * 4;
            int reg = ridx_sh[sel];
            int h = pair * 2 + h2;
            uint2 v = *reinterpret_cast<const uint2*>(
                kvpT + (((size_t)(b * 64 + reg) * 128) + h * 16 + d) * 16 + p4);
            *reinterpret_cast<uint2*>(&VTsh[h2][d * 528 + (sel * 16 + p4) * 2]) = v;
        }
        __syncthreads();

        int h = pair * 2 + hh;
        bf16x8 qf = *reinterpret_cast<const bf16x8*>(
            qsh + (qt * 32 + l31) * 272 + h * 32 + hi * 16);
        float m_run = -INFINITY, l_run = 0.f;
        f32x16 opv;
#pragma unroll
        for (int r = 0; r < 16; r++) opv[r] = 0.f;
        f32x16 zf;
#pragma unroll
        for (int r = 0; r < 16; r++) zf[r] = 0.f;

        for (int t8 = 0; t8 < 8; t8++) {
            bf16x8 kf = *reinterpret_cast<const bf16x8*>(
                &Ksh[hh][(t8 * 32 + l31) * 48 + hi * 16]);
            f32x16 S = __builtin_amdgcn_mfma_f32_32x32x16_bf16(kf, qf, zf, 0, 0, 0);
            float tm = S[0];
#pragma unroll
            for (int r = 1; r < 16; r++) tm = fmaxf(tm, S[r]);
            tm = fmaxf(tm, __shfl_xor(tm, 32, 64));
            float m_new = fmaxf(m_run, tm);
            float corr = __expf(m_run - m_new);
            float p_[16], psum = 0.f;
#pragma unroll
            for (int r = 0; r < 16; r++) { p_[r] = __expf(S[r] - m_new); psum += p_[r]; }
            psum += __shfl_xor(psum, 32, 64);
            l_run = l_run * corr + psum;
            m_run = m_new;
#pragma unroll
            for (int r = 0; r < 16; r++) opv[r] *= corr;
            unsigned w_[8], pw_[8];
#pragma unroll
            for (int j = 0; j < 8; j++)
                w_[j] = (__float_as_uint(p_[2 * j]) >> 16) |
                        (__float_as_uint(p_[2 * j + 1]) & 0xFFFF0000u);
#pragma unroll
            for (int j = 0; j < 8; j++) pw_[j] = __shfl_xor(w_[j], 32, 64);
            union { unsigned u[4]; bf16x8 v; } fa0, fa1;
            fa0.u[0] = hi ? pw_[2] : w_[0];
            fa0.u[1] = hi ? pw_[3] : w_[1];
            fa0.u[2] = hi ? w_[2]  : pw_[0];
            fa0.u[3] = hi ? w_[3]  : pw_[1];
            fa1.u[0] = hi ? pw_[6] : w_[4];
            fa1.u[1] = hi ? pw_[7] : w_[5];
            fa1.u[2] = hi ? w_[6]  : pw_[4];
            fa1.u[3] = hi ? w_[7]  : pw_[5];
            const unsigned char* vb = &VTsh[hh][(l31 & 15) * 528 + t8 * 64];
            bf16x8 bf0 = *reinterpret_cast<const bf16x8*>(vb + hi * 16);
            bf16x8 bf1 = *reinterpret_cast<const bf16x8*>(vb + 32 + hi * 16);
            opv = __builtin_amdgcn_mfma_f32_32x32x16_bf16(fa0.v, bf0, opv, 0, 0, 0);
            opv = __builtin_amdgcn_mfma_f32_32x32x16_bf16(fa1.v, bf1, opv, 0, 0, 0);
        }
        denom_sh[wv][l31] = l_run;
        if (l31 < 16) {
#pragma unroll
            for (int r = 0; r < 16; r++) {
                int qr = (r & 3) + 8 * (r >> 2) + 4 * hi;
                float invd = 1.f / denom_sh[wv][qr];
                int q = qt * 32 + qr;
                int y = wi * 8 + (q >> 3), x = wj * 8 + (q & 7);
                o[((size_t)(b * H + y) * W + x) * 128 + h * 16 + l31] = opv[r] * invd;
            }
        }
    }
}

// ------------------------- NHWC v-half -> fp32 NCHW planes [B][C][64][64]
__global__ __launch_bounds__(256) void transpose_v_k(const float* __restrict__ kv,
                                                     float* __restrict__ vpl) {
    int b = blockIdx.y, y = blockIdx.x * 2 + (threadIdx.x >> 7);
    int c = threadIdx.x & 127;
    const float* src = kv + ((size_t)(b * H + y) * W) * 256 + 128 + c;
    float* dst = vpl + ((size_t)(b * C + c) * H + y) * W;
#pragma unroll
    for (int xg = 0; xg < 16; xg++) {
        float4 v;
        v.x = src[(xg * 4 + 0) * 256];
        v.y = src[(xg * 4 + 1) * 256];
        v.z = src[(xg * 4 + 2) * 256];
        v.w = src[(xg * 4 + 3) * 256];
        *reinterpret_cast<float4*>(dst + xg * 4) = v;
    }
}

// ------------------ LePE depthwise 5x5 on planes, LDS-tiled (writes lep planes)
__global__ __launch_bounds__(256) void lepe_plane_k(const float* __restrict__ vpl,
                                                    const float* __restrict__ w,
                                                    const float* __restrict__ bias,
                                                    float* __restrict__ lep) {
    __shared__ float tile[68][69];
    int c = blockIdx.x, b = blockIdx.y;
    int t = threadIdx.x;
    const float* plane = vpl + (size_t)(b * C + c) * 4096;
    for (int e = t; e < 68 * 68; e += 256) {
        int row = e / 68, col = e - row * 68;
        int gy = row - 2, gx = col - 2;
        tile[row][col] = (gy >= 0 && gy < 64 && gx >= 0 && gx < 64)
                         ? plane[gy * 64 + gx] : 0.f;
    }
    float wv[25];
#pragma unroll
    for (int j = 0; j < 25; j++) wv[j] = w[c * 25 + j];
    float bb = bias[c];
    __syncthreads();
    int y = t >> 2, x0 = (t & 3) * 16;
    float acc[16];
#pragma unroll
    for (int i = 0; i < 16; i++) acc[i] = bb;
#pragma unroll
    for (int dy = 0; dy < 5; dy++) {
        float vals[20];
#pragma unroll
        for (int j = 0; j < 20; j++) vals[j] = tile[y + dy][x0 + j];
#pragma unroll
        for (int dx = 0; dx < 5; dx++)
#pragma unroll
            for (int i = 0; i < 16; i++)
                acc[i] += vals[i + dx] * wv[dy * 5 + dx];
    }
    float* dst = lep + (size_t)(b * C + c) * 4096 + y * 64 + x0;
#pragma unroll
    for (int i = 0; i < 16; i += 4)
        *reinterpret_cast<float4*>(dst + i) =
            make_float4(acc[i], acc[i + 1], acc[i + 2], acc[i + 3]);
}

// -------------------- ((o_attn + lepe) @ Wo^T + b) + x, write NCHW output
__global__ __launch_bounds__(128) void epilogue_k(const float* __restrict__ o,
                                                  const float* __restrict__ lep,
                                                  const float* __restrict__ xbuf,
                                                  const float* __restrict__ woT,
                                                  const float* __restrict__ wo_b,
                                                  float* __restrict__ out) {
    __shared__ float ot[16][128];
    __shared__ float res[128][17];
    int b = blockIdx.z, y = blockIdx.y, x0 = blockIdx.x * 16;
    int t = threadIdx.x;
    size_t pixBase = (size_t)(b * H + y) * W + x0;
    const float* lrow = lep + (size_t)(b * C + t) * 4096 + y * 64 + x0;
    for (int p = 0; p < 16; p++)
        ot[p][t] = o[(pixBase + p) * 128 + t] + lrow[p];
    __syncthreads();
    float acc[16];
    float wb = wo_b[t];
#pragma unroll
    for (int p = 0; p < 16; p++) acc[p] = wb + xbuf[(pixBase + p) * 128 + t];
    for (int k = 0; k < 128; k += 4) {
        float w0 = woT[(k + 0) * 128 + t];
        float w1 = woT[(k + 1) * 128 + t];
        float w2 = woT[(k + 2) * 128 + t];
        float w3 = woT[(k + 3) * 128 + t];
#pragma unroll
        for (int p = 0; p < 16; p++) {
            const float4 av = *reinterpret_cast<const float4*>(&ot[p][k]);
            acc[p] += av.x * w0 + av.y * w1 + av.z * w2 + av.w * w3;
        }
    }
#pragma unroll
    for (int p = 0; p < 16; p++) res[t][p] = acc[p];
    __syncthreads();
    int xi = t & 15, cg = t >> 4;
    for (int i = 0; i < 16; i++) {
        int c = cg * 16 + i;
        out[((size_t)(b * C + c) * H + y) * W + x0 + xi] = res[c][xi];
    }
}

extern "C" void kernel_launch(void* const* d_in, const int* in_sizes, int n_in,
                              void* d_out, int out_size, void* d_ws, size_t ws_size,
                              hipStream_t stream) {
    const float* t1      = (const float*)d_in[0];
    const float* t2      = (const float*)d_in[1];
    const float* pos_w   = (const float*)d_in[2];
    const float* pos_b   = (const float*)d_in[3];
    const float* cat_w   = (const float*)d_in[4];
    const float* cat_b   = (const float*)d_in[5];
    const float* ln_cat_g= (const float*)d_in[6];
    const float* ln_cat_b= (const float*)d_in[7];
    const float* ln1_g   = (const float*)d_in[8];
    const float* ln1_b   = (const float*)d_in[9];
    const float* qkv_w   = (const float*)d_in[10];
    const float* qkv_b   = (const float*)d_in[11];
    const float* lepe_w  = (const float*)d_in[12];
    const float* lepe_b  = (const float*)d_in[13];
    const float* wo_w    = (const float*)d_in[14];
    const float* wo_b    = (const float*)d_in[15];

    float* ws    = (float*)d_ws;
    float* t1c   = ws + OFF_T1C;
    float* t2c   = ws + OFF_T2C;
    float* xbuf  = ws + OFF_X;
    ushort_t* qbuf = (ushort_t*)(ws + OFF_QB);
    float* kvbuf = ws + OFF_KV;
    float* kvpix = ws + OFF_KVP;
    ushort_t* kvpT = (ushort_t*)(ws + OFF_KVPT);
    float* m1    = ws + OFF_M1;
    float* m2    = ws + OFF_M2;
    float* qwin  = ws + OFF_QW;
    float* kwin  = ws + OFF_KW;
    int*   ridx  = (int*)(ws + OFF_RIDX);
    ushort_t* wcatB = (ushort_t*)(ws + OFF_WCB);
    ushort_t* qkvB  = (ushort_t*)(ws + OFF_QKVB);
    float* woT   = ws + OFF_WOT;
    float* obuf  = ws + OFF_O;    // alias of t1c (dead after ln_qkv q / win_mean)
    float* vpl   = ws + OFF_VPL;  // alias of t2c (dead after ln_qkv kv / win_mean)
    float* lep   = ws + OFF_LEP;  // alias of kvbuf (dead after pool_k + transpose_v)
    float* out   = (float*)d_out;

    transpose_weights<<<dim3((36 * 128 * 72 + 255) / 256), 256, 0, stream>>>(
        qkv_w, wo_w, cat_w, qkvB, woT, wcatB);
    pos_conv_k<<<dim3(2, 4, B * H), 256, 0, stream>>>(t1, pos_w, pos_b, t1c);
    pos_conv_k<<<dim3(2, 4, B * H), 256, 0, stream>>>(t2, pos_w, pos_b, t2c);
    catconv_mfma_k<<<dim3(4, 8, 8), 256, 0, stream>>>(
        t1c, t2c, wcatB, cat_b, ln_cat_g, ln_cat_b, xbuf);
    win_mean_k<<<dim3(64, B), 256, 0, stream>>>(t1c, t2c, ln1_g, ln1_b, m1, m2);
    route_gemm_k<<<dim3(8, B), 256, 0, stream>>>(m1, m2, qkv_w, qkv_b, qwin, kwin);
    route_k<<<dim3(64, B), 64, 0, stream>>>(qwin, kwin, ridx);
    ln_qkv_mfma_k<2, true><<<dim3(512), 256, 0, stream>>>(
        t1c, ln1_g, ln1_b, qkvB, 0, qkv_b, qbuf, nullptr);
    ln_qkv_mfma_k<4, false><<<dim3(512), 256, 0, stream>>>(
        t2c, ln1_g, ln1_b, qkvB, 128, qkv_b, nullptr, kvbuf);
    pool_k<<<dim3(64, B), 256, 0, stream>>>(kvbuf, kvpix, kvpT);
    transpose_v_k<<<dim3(32, B), 256, 0, stream>>>(kvbuf, vpl);
    attn_mfma_k<<<dim3(64, B), 256, 0, stream>>>(qbuf, kvpix, kvpT, ridx, obuf);
    lepe_plane_k<<<dim3(C, B), 256, 0, stream>>>(vpl, lepe_w, lepe_b, lep);
    epilogue_k<<<dim3(4, 64, 8), 128, 0, stream>>>(obuf, lep, xbuf, woT, wo_b, out);
}

// Round 5
// 271.755 us; speedup vs baseline: 3.9081x; 1.0712x over previous
//
#include <hip/hip_runtime.h>
#include <math.h>

typedef unsigned short ushort_t;
typedef __attribute__((ext_vector_type(4))) float f32x4;
typedef __attribute__((ext_vector_type(16))) float f32x16;
typedef __attribute__((ext_vector_type(8))) short bf16x8;

constexpr int B = 8, C = 128, H = 64, W = 64;
constexpr int HEADS = 8, TOPK = 16;
constexpr int P2 = 64;
constexpr float SCALE = 0.0883883476483184405f; // 128^-0.5

// workspace offsets (in floats)
constexpr size_t NPIX    = (size_t)B * H * W;            // 32768
constexpr size_t OFF_T1C = 0;                            // NHWC fp32 (B,H,W,128)
constexpr size_t OFF_T2C = OFF_T1C + NPIX * 128;
constexpr size_t OFF_X   = OFF_T2C + NPIX * 128;         // relu(LN(catconv)) fp32
constexpr size_t OFF_QB  = OFF_X   + NPIX * 128;         // q*SCALE bf16 (NPIX*128 shorts)
constexpr size_t OFF_KV  = OFF_QB  + NPIX * 64;          // kv fp32 (B,H,W,256)
constexpr size_t OFF_KVP = OFF_KV  + NPIX * 256;         // kv_pix fp32 (B,64,16,256)
constexpr size_t OFF_KVPT= OFF_KVP + (size_t)B * P2 * 16 * 256; // v^T bf16 [B,64,128,16]
constexpr size_t OFF_M1  = OFF_KVPT+ (size_t)B * P2 * 128 * 16 / 2;
constexpr size_t OFF_M2  = OFF_M1  + (size_t)B * P2 * 128;
constexpr size_t OFF_QW  = OFF_M2  + (size_t)B * P2 * 128;
constexpr size_t OFF_KW  = OFF_QW  + (size_t)B * P2 * 128;
constexpr size_t OFF_RIDX= OFF_KW  + (size_t)B * P2 * 128;      // int
constexpr size_t OFF_WCB = OFF_RIDX+ (size_t)B * P2 * TOPK;     // wcat2 bf16 [36][2][4][128][8]
constexpr size_t OFF_QKVB= OFF_WCB + (size_t)9 * 256 * 128;     // qkv_w bf16 [384][128]
constexpr size_t OFF_WOT = OFF_QKVB+ (size_t)384 * 128 / 2;     // [128][128] fp32
constexpr size_t OFF_O   = OFF_T1C;  // attention output aliases t1c
constexpr size_t OFF_VPL = OFF_T2C;  // v planes fp32 [B][C][64][64] alias t2c (dead)
constexpr size_t OFF_LEP = OFF_KV;   // lepe planes fp32 [B][C][64][64] alias kvbuf (dead)

__device__ inline ushort_t f2bf(float f) {
    unsigned u = __float_as_uint(f);
    unsigned r = u + 0x7FFFu + ((u >> 16) & 1u);
    return (ushort_t)(r >> 16);
}

// ---------------------------------------------------------------- weights prep
__global__ void transpose_weights(const float* __restrict__ qkv_w,
                                  const float* __restrict__ wo_w,
                                  const float* __restrict__ cat_w,
                                  ushort_t* __restrict__ qkvB,
                                  float* __restrict__ woT,
                                  ushort_t* __restrict__ wcat2) {
    int idx = blockIdx.x * 256 + threadIdx.x;
    if (idx < 384 * 128) {           // qkvB[n][k] bf16 (same layout as qkv_w)
        qkvB[idx] = f2bf(qkv_w[idx]);
    }
    if (idx < 128 * 128) {           // woT[k][n] = wo_w[n][k]
        int k = idx / 128, n = idx % 128;
        woT[idx] = wo_w[n * 128 + k];
    }
    if (idx < 36 * 8 * 128 * 8) {    // wcat2[((q*9+dd)*8+kk*4+lg)][n][i]
        int i  = idx & 7;
        int n  = (idx >> 3) & 127;
        int r  = idx >> 10;
        int lg = r & 3;
        int kk = (r >> 2) & 1;
        int sdd = r >> 3;            // 0..35
        int dd = sdd % 9, q = sdd / 9;
        int ci = q * 64 + kk * 32 + lg * 8 + i;
        wcat2[idx] = f2bf(cat_w[((size_t)n * 256 + ci) * 9 + dd]);
    }
}

// --------------------------------------- depthwise 3x3 + residual, NCHW->NHWC
__global__ __launch_bounds__(256) void pos_conv_k(const float* __restrict__ in,
                                                  const float* __restrict__ w,
                                                  const float* __restrict__ bias,
                                                  float* __restrict__ outNHWC) {
    __shared__ float tile[32][33];
    int b = blockIdx.z / H, y = blockIdx.z % H;
    int c0 = blockIdx.y * 32, x0 = blockIdx.x * 32;
    int tx = threadIdx.x & 31, tg = threadIdx.x >> 5;
    for (int i = 0; i < 4; i++) {
        int cl = tg * 4 + i, c = c0 + cl;
        const float* base = in + (size_t)(b * C + c) * H * W;
        float acc = base[y * W + x0 + tx];
        float wv[9];
#pragma unroll
        for (int j = 0; j < 9; j++) wv[j] = w[c * 9 + j];
#pragma unroll
        for (int dy = 0; dy < 3; dy++) {
            int yy = y + dy - 1;
            if (yy < 0 || yy >= H) continue;
#pragma unroll
            for (int dx = 0; dx < 3; dx++) {
                int xx = x0 + tx + dx - 1;
                if (xx < 0 || xx >= W) continue;
                acc += base[yy * W + xx] * wv[dy * 3 + dx];
            }
        }
        tile[cl][tx] = acc + bias[c];
    }
    __syncthreads();
    for (int i = 0; i < 4; i++) {
        int xl = tg * 4 + i;
        outNHWC[((size_t)(b * H + y) * W + x0 + xl) * 128 + c0 + tx] = tile[tx][xl];
    }
}

// ------------- cat-conv 256->128 3x3 implicit-GEMM MFMA + fused LN+ReLU (v2)
// 8x8 pixel tile (M=64) x N=128, 8 waves, B-frags streamed from L2 (no LDS stage)
__global__ __launch_bounds__(512) void catconv_mfma_k(
        const float* __restrict__ t1c, const float* __restrict__ t2c,
        const ushort_t* __restrict__ wcat2,
        const float* __restrict__ cat_b,
        const float* __restrict__ g, const float* __restrict__ beta,
        float* __restrict__ xbuf) {
    __shared__ __align__(16) unsigned char smem[64 * 132 * 4 + 2 * 64 * 4]; // >= 14400 halo
    int t = threadIdx.x;
    int lane = t & 63, wv = t >> 6;
    int mw = wv >> 2, nw = wv & 3;
    int l15 = lane & 15, lg = lane >> 4;
    int b = blockIdx.z, y0 = blockIdx.y * 8, x0 = blockIdx.x * 8;

    f32x4 acc[2][2];
#pragma unroll
    for (int m = 0; m < 2; m++)
#pragma unroll
        for (int cf = 0; cf < 2; cf++)
            acc[m][cf] = (f32x4){0.f, 0.f, 0.f, 0.f};

    // A-frag pixel coords (row-major 8x8 tile)
    int pyA[2], pxA[2];
#pragma unroll
    for (int m = 0; m < 2; m++) {
        int p = mw * 32 + m * 16 + l15;
        pyA[m] = p >> 3; pxA[m] = p & 7;
    }

    for (int q = 0; q < 4; q++) {
        __syncthreads();                       // prior quarter's readers done
        {   // stage 10x10 halo of 64-ci quarter, fp32 -> bf16
            const float* src = (q < 2 ? t1c : t2c) + (q & 1) * 64;
            for (int e = t; e < 1600; e += 512) {
                int pix = e >> 4, c4 = e & 15;
                int hy = pix / 10, hx = pix - hy * 10;
                int gy = y0 - 1 + hy, gx = x0 - 1 + hx;
                float4 v = make_float4(0.f, 0.f, 0.f, 0.f);
                if (gy >= 0 && gy < H && gx >= 0 && gx < W)
                    v = *reinterpret_cast<const float4*>(
                        src + ((size_t)(b * H + gy) * W + gx) * 128 + c4 * 4);
                uint2 pk;
                pk.x = (unsigned)f2bf(v.x) | ((unsigned)f2bf(v.y) << 16);
                pk.y = (unsigned)f2bf(v.z) | ((unsigned)f2bf(v.w) << 16);
                *reinterpret_cast<uint2*>(smem + pix * 144 + c4 * 8) = pk;
            }
        }
        __syncthreads();
#pragma unroll
        for (int dd = 0; dd < 9; dd++) {
            int dy = dd / 3, dx = dd - dy * 3;
            // B-frags from global (L2): wcat2[((q*9+dd)*8 + kk*4 + lg)][n][8]
            const ushort_t* wb = wcat2 + ((size_t)((q * 9 + dd) * 8 + lg) * 128) * 8;
            bf16x8 bfr[2][2];
#pragma unroll
            for (int kk = 0; kk < 2; kk++)
#pragma unroll
                for (int cf = 0; cf < 2; cf++)
                    bfr[kk][cf] = *reinterpret_cast<const bf16x8*>(
                        wb + (size_t)kk * 4096 + (nw * 32 + cf * 16 + l15) * 8);
            bf16x8 af[2][2];
#pragma unroll
            for (int m = 0; m < 2; m++)
#pragma unroll
                for (int kk = 0; kk < 2; kk++)
                    af[m][kk] = *reinterpret_cast<const bf16x8*>(
                        smem + ((pyA[m] + dy) * 10 + pxA[m] + dx) * 144 + kk * 64 + lg * 16);
#pragma unroll
            for (int m = 0; m < 2; m++)
#pragma unroll
                for (int cf = 0; cf < 2; cf++)
#pragma unroll
                    for (int kk = 0; kk < 2; kk++)
                        acc[m][cf] = __builtin_amdgcn_mfma_f32_16x16x32_bf16(
                            af[m][kk], bfr[kk][cf], acc[m][cf], 0, 0, 0);
        }
    }

    // ------- fused bias + LayerNorm(1e-5) + ReLU epilogue (LDS reuse) -------
    __syncthreads();
    float* res = (float*)smem;                     // [64][132]
    float* mstat = (float*)(smem + 64 * 132 * 4);  // mean[64], inv[64]
#pragma unroll
    for (int cf = 0; cf < 2; cf++) {
        int n = nw * 32 + cf * 16 + l15;
        float cb = cat_b[n];
#pragma unroll
        for (int m = 0; m < 2; m++)
#pragma unroll
            for (int i = 0; i < 4; i++)
                res[(mw * 32 + m * 16 + lg * 4 + i) * 132 + n] = acc[m][cf][i] + cb;
    }
    __syncthreads();
    {
        int pix = t >> 3, sub = t & 7;
        float s1 = 0.f;
#pragma unroll
        for (int j = 0; j < 16; j++) s1 += res[pix * 132 + sub + j * 8];
        s1 += __shfl_xor(s1, 1, 64);
        s1 += __shfl_xor(s1, 2, 64);
        s1 += __shfl_xor(s1, 4, 64);
        float mean = s1 * (1.f / 128.f);
        float s2 = 0.f;
#pragma unroll
        for (int j = 0; j < 16; j++) {
            float d = res[pix * 132 + sub + j * 8] - mean;
            s2 += d * d;
        }
        s2 += __shfl_xor(s2, 1, 64);
        s2 += __shfl_xor(s2, 2, 64);
        s2 += __shfl_xor(s2, 4, 64);
        float inv = rsqrtf(s2 * (1.f / 128.f) + 1e-5f);
        if (sub == 0) { mstat[pix] = mean; mstat[64 + pix] = inv; }
    }
    __syncthreads();
    {
        int c = t & 127, pg = t >> 7;   // 4 pixel groups
        float gg = g[c], bb = beta[c];
        for (int j = 0; j < 16; j++) {
            int p2 = j * 4 + pg;
            float v = (res[p2 * 132 + c] - mstat[p2]) * mstat[64 + p2] * gg + bb;
            int py = p2 >> 3, px = p2 & 7;
            xbuf[((size_t)(b * H + y0 + py) * W + x0 + px) * 128 + c] = fmaxf(v, 0.f);
        }
    }
}

// ------------------------ LN(1e-6) + QKV projection, bf16 MFMA (M=64 per block)
template<int NPW, bool QOUT>
__global__ __launch_bounds__(256) void ln_qkv_mfma_k(
        const float* __restrict__ in,
        const float* __restrict__ g, const float* __restrict__ beta,
        const ushort_t* __restrict__ wB,   // bf16 [384][128]
        int nOff,
        const float* __restrict__ bias,
        ushort_t* __restrict__ outQ,
        float* __restrict__ outKV) {
    __shared__ __align__(16) unsigned char ash[64 * 272];
    int t = threadIdx.x;
    int lane = t & 63, wv = t >> 6;
    size_t p0 = (size_t)blockIdx.x * 64;
    {
        int row = t >> 2, sub = t & 3;
        const float* src = in + (p0 + row) * 128 + sub * 32;
        float4 v[8];
        float s = 0.f;
#pragma unroll
        for (int j = 0; j < 8; j++) {
            v[j] = *reinterpret_cast<const float4*>(src + j * 4);
            s += v[j].x + v[j].y + v[j].z + v[j].w;
        }
        s += __shfl_xor(s, 1, 64); s += __shfl_xor(s, 2, 64);
        float mean = s * (1.f / 128.f);
        float s2 = 0.f;
#pragma unroll
        for (int j = 0; j < 8; j++) {
            float dx = v[j].x - mean, dy = v[j].y - mean;
            float dz = v[j].z - mean, dw = v[j].w - mean;
            s2 += dx * dx + dy * dy + dz * dz + dw * dw;
        }
        s2 += __shfl_xor(s2, 1, 64); s2 += __shfl_xor(s2, 2, 64);
        float inv = rsqrtf(s2 * (1.f / 128.f) + 1e-6f);
#pragma unroll
        for (int j = 0; j < 8; j++) {
            int c = sub * 32 + j * 4;
            float4 gv = *reinterpret_cast<const float4*>(g + c);
            float4 bv = *reinterpret_cast<const float4*>(beta + c);
            float o0 = (v[j].x - mean) * inv * gv.x + bv.x;
            float o1 = (v[j].y - mean) * inv * gv.y + bv.y;
            float o2 = (v[j].z - mean) * inv * gv.z + bv.z;
            float o3 = (v[j].w - mean) * inv * gv.w + bv.w;
            uint2 pk;
            pk.x = (unsigned)f2bf(o0) | ((unsigned)f2bf(o1) << 16);
            pk.y = (unsigned)f2bf(o2) | ((unsigned)f2bf(o3) << 16);
            *reinterpret_cast<uint2*>(ash + row * 272 + c * 2) = pk;
        }
    }
    __syncthreads();
    int l15 = lane & 15, lg = lane >> 4;
    f32x4 acc[4][NPW];
#pragma unroll
    for (int mt = 0; mt < 4; mt++)
#pragma unroll
        for (int nn = 0; nn < NPW; nn++)
            acc[mt][nn] = (f32x4){0.f, 0.f, 0.f, 0.f};
#pragma unroll
    for (int ks = 0; ks < 4; ks++) {
        bf16x8 af[4];
#pragma unroll
        for (int mt = 0; mt < 4; mt++)
            af[mt] = *reinterpret_cast<const bf16x8*>(
                ash + (mt * 16 + l15) * 272 + ks * 64 + lg * 16);
#pragma unroll
        for (int nn = 0; nn < NPW; nn++) {
            int n = nOff + (wv * NPW + nn) * 16 + l15;
            bf16x8 bfr = *reinterpret_cast<const bf16x8*>(
                wB + (size_t)n * 128 + ks * 32 + lg * 8);
#pragma unroll
            for (int mt = 0; mt < 4; mt++)
                acc[mt][nn] = __builtin_amdgcn_mfma_f32_16x16x32_bf16(
                    af[mt], bfr, acc[mt][nn], 0, 0, 0);
        }
    }
#pragma unroll
    for (int nn = 0; nn < NPW; nn++) {
        int cg = (wv * NPW + nn) * 16 + l15;
        float bv = bias[nOff + cg];
#pragma unroll
        for (int mt = 0; mt < 4; mt++) {
#pragma unroll
            for (int i = 0; i < 4; i++) {
                size_t pix = p0 + mt * 16 + lg * 4 + i;
                float val = acc[mt][nn][i] + bv;
                if (QOUT) outQ[pix * 128 + cg] = f2bf(val * SCALE);
                else      outKV[pix * 256 + cg] = val;
            }
        }
    }
}

// ------------------- exact fp32 window means of LN (routing path)
__global__ __launch_bounds__(256) void win_mean_k(
        const float* __restrict__ t1c, const float* __restrict__ t2c,
        const float* __restrict__ g, const float* __restrict__ beta,
        float* __restrict__ m1, float* __restrict__ m2) {
    __shared__ float mws[4][128];
    int b = blockIdx.y, win = blockIdx.x;
    int wi = win >> 3, wj = win & 7;
    int t = threadIdx.x, lane = t & 63, wv = t >> 6;
    int pixw = lane >> 2, sub = lane & 3;
    int p = wv * 16 + pixw;
    int y = wi * 8 + (p >> 3), x = wj * 8 + (p & 7);
    size_t base = ((size_t)(b * H + y) * W + x) * 128 + sub * 32;
    for (int which = 0; which < 2; which++) {
        const float* src = (which == 0 ? t1c : t2c) + base;
        float4 v[8];
        float s = 0.f;
#pragma unroll
        for (int j = 0; j < 8; j++) {
            v[j] = *reinterpret_cast<const float4*>(src + j * 4);
            s += v[j].x + v[j].y + v[j].z + v[j].w;
        }
        s += __shfl_xor(s, 1, 64); s += __shfl_xor(s, 2, 64);
        float mean = s * (1.f / 128.f);
        float s2 = 0.f;
#pragma unroll
        for (int j = 0; j < 8; j++) {
            float dx = v[j].x - mean, dy = v[j].y - mean;
            float dz = v[j].z - mean, dw = v[j].w - mean;
            s2 += dx * dx + dy * dy + dz * dz + dw * dw;
        }
        s2 += __shfl_xor(s2, 1, 64); s2 += __shfl_xor(s2, 2, 64);
        float inv = rsqrtf(s2 * (1.f / 128.f) + 1e-6f);
#pragma unroll
        for (int j = 0; j < 8; j++) {
            int c = sub * 32 + j * 4;
            float4 gv = *reinterpret_cast<const float4*>(g + c);
            float4 bv = *reinterpret_cast<const float4*>(beta + c);
            v[j].x = (v[j].x - mean) * inv * gv.x + bv.x;
            v[j].y = (v[j].y - mean) * inv * gv.y + bv.y;
            v[j].z = (v[j].z - mean) * inv * gv.z + bv.z;
            v[j].w = (v[j].w - mean) * inv * gv.w + bv.w;
        }
#pragma unroll
        for (int m = 4; m <= 32; m <<= 1) {
#pragma unroll
            for (int j = 0; j < 8; j++) {
                v[j].x += __shfl_xor(v[j].x, m, 64);
                v[j].y += __shfl_xor(v[j].y, m, 64);
                v[j].z += __shfl_xor(v[j].z, m, 64);
                v[j].w += __shfl_xor(v[j].w, m, 64);
            }
        }
        if (pixw == 0) {
#pragma unroll
            for (int j = 0; j < 8; j++)
                *reinterpret_cast<float4*>(&mws[wv][sub * 32 + j * 4]) = v[j];
        }
        __syncthreads();
        if (t < 128) {
            float mval = (mws[0][t] + mws[1][t] + mws[2][t] + mws[3][t]) * (1.f / 64.f);
            (which ? m2 : m1)[((size_t)b * 64 + win) * 128 + t] = mval;
        }
        __syncthreads();
    }
}

// ------------------- fp32 q_win/k_win projection (routing path, exact)
__global__ __launch_bounds__(256) void route_gemm_k(
        const float* __restrict__ m1, const float* __restrict__ m2,
        const float* __restrict__ qkv_w, const float* __restrict__ qkv_b,
        float* __restrict__ qwin, float* __restrict__ kwin) {
    __shared__ float msh[2][8][128];
    int b = blockIdx.y, ch = blockIdx.x;
    int t = threadIdx.x;
    for (int i = t; i < 8 * 128; i += 256) {
        int r = i >> 7, c = i & 127;
        msh[0][r][c] = m1[((size_t)b * 64 + ch * 8 + r) * 128 + c];
        msh[1][r][c] = m2[((size_t)b * 64 + ch * 8 + r) * 128 + c];
    }
    __syncthreads();
    int c = t;
    int which = c >> 7;
    const float* wrow = qkv_w + (size_t)c * 128;
    float acc[8];
#pragma unroll
    for (int r = 0; r < 8; r++) acc[r] = 0.f;
    for (int k = 0; k < 128; k++) {
        float wv_ = wrow[k];
#pragma unroll
        for (int r = 0; r < 8; r++) acc[r] += msh[which][r][k] * wv_;
    }
    float bv = qkv_b[c];
#pragma unroll
    for (int r = 0; r < 8; r++) {
        size_t o = ((size_t)b * 64 + ch * 8 + r) * 128 + (c & 127);
        (which ? kwin : qwin)[o] = acc[r] + bv;
    }
}

// --------------------------------------------- window pooling (kv_pix + v^T bf16)
__global__ __launch_bounds__(256) void pool_k(const float* __restrict__ kv,
                                              float* __restrict__ kv_pix,
                                              ushort_t* __restrict__ kvpT) {
    int b = blockIdx.y, wdw = blockIdx.x;
    int wi = wdw >> 3, wj = wdw & 7;
    int t = threadIdx.x;
    float vals[16];
    for (int ry = 0; ry < 4; ry++)
        for (int rx = 0; rx < 4; rx++) {
            float s = 0.f;
            for (int fy = 0; fy < 2; fy++)
                for (int fx = 0; fx < 2; fx++) {
                    int y = wi * 8 + ry * 2 + fy, x = wj * 8 + rx * 2 + fx;
                    s += kv[((size_t)(b * H + y) * W + x) * 256 + t];
                }
            float mv = s * 0.25f;
            kv_pix[((size_t)(b * 64 + wdw) * 16 + ry * 4 + rx) * 256 + t] = mv;
            vals[ry * 4 + rx] = mv;
        }
    if (t >= 128) {
        union { ushort_t u16[16]; uint4 u4[2]; } pk;
#pragma unroll
        for (int i = 0; i < 16; i++) pk.u16[i] = f2bf(vals[i]);
        size_t base = (((size_t)(b * 64 + wdw)) * 128 + (t - 128)) * 16;
        *reinterpret_cast<uint4*>(kvpT + base) = pk.u4[0];
        *reinterpret_cast<uint4*>(kvpT + base + 8) = pk.u4[1];
    }
}

// ------------------------------------------------ routing logits + top-16
__global__ __launch_bounds__(64) void route_k(const float* __restrict__ q_win,
                                              const float* __restrict__ k_win,
                                              int* __restrict__ r_idx) {
    int b = blockIdx.y, p = blockIdx.x, j = threadIdx.x;
    const float* qp = q_win + (size_t)(b * 64 + p) * 128;
    const float* kp = k_win + (size_t)(b * 64 + j) * 128;
    float lg = 0.f;
    for (int c = 0; c < 128; c++) lg += qp[c] * kp[c];
    lg *= SCALE;
    for (int it = 0; it < TOPK; it++) {
        float v = lg; int idx = j;
#pragma unroll
        for (int m = 32; m > 0; m >>= 1) {
            float ov = __shfl_xor(v, m, 64);
            int   oi = __shfl_xor(idx, m, 64);
            if (ov > v || (ov == v && oi < idx)) { v = ov; idx = oi; }
        }
        if (j == 0) r_idx[(size_t)(b * 64 + p) * TOPK + it] = idx;
        if (j == idx) lg = -__builtin_inff();
    }
}

// -------------------------------------------------- routed attention, bf16 MFMA
__global__ __launch_bounds__(256) void attn_mfma_k(
        const ushort_t* __restrict__ qb,     // bf16 q*SCALE [B,H,W,128]
        const float* __restrict__ kv_pix,    // fp32 [B,64,16,256]
        const ushort_t* __restrict__ kvpT,   // bf16 [B,64,128,16]
        const int* __restrict__ r_idx,
        float* __restrict__ o) {
    __shared__ __align__(16) unsigned char qsh[64 * 272];
    __shared__ __align__(16) unsigned char Ksh[2][256 * 48];
    __shared__ __align__(16) unsigned char VTsh[2][16 * 528];
    __shared__ int ridx_sh[16];
    __shared__ float denom_sh[4][32];

    int b = blockIdx.y, p = blockIdx.x;
    int wi = p >> 3, wj = p & 7;
    int t = threadIdx.x;
    int lane = t & 63, wv = t >> 6;
    int l31 = lane & 31, hi = lane >> 5;

    if (t < 16) ridx_sh[t] = r_idx[(size_t)(b * 64 + p) * TOPK + t];
    for (int i = t; i < 64 * 16; i += 256) {
        int row = i >> 4, seg = i & 15;
        int y = wi * 8 + (row >> 3), x = wj * 8 + (row & 7);
        *reinterpret_cast<uint4*>(qsh + row * 272 + seg * 16) =
            *reinterpret_cast<const uint4*>(qb + ((size_t)(b * H + y) * W + x) * 128 + seg * 8);
    }
    __syncthreads();

    int hh = wv >> 1, qt = wv & 1;

    for (int pair = 0; pair < 4; pair++) {
        __syncthreads();
        for (int i = t; i < 2048; i += 256) {
            int h2 = i >> 10, kp = (i >> 2) & 255, q4 = i & 3;
            int reg = ridx_sh[kp >> 4], pos = kp & 15;
            int h = pair * 2 + h2;
            float4 v = *reinterpret_cast<const float4*>(
                kv_pix + (((size_t)(b * 64 + reg) * 16 + pos) * 256) + h * 16 + q4 * 4);
            uint2 pk;
            pk.x = (unsigned)f2bf(v.x) | ((unsigned)f2bf(v.y) << 16);
            pk.y = (unsigned)f2bf(v.z) | ((unsigned)f2bf(v.w) << 16);
            *reinterpret_cast<uint2*>(&Ksh[h2][kp * 48 + q4 * 8]) = pk;
        }
        for (int i = t; i < 2048; i += 256) {
            int h2 = i >> 10, d = (i >> 6) & 15, ck = i & 63;
            int sel = ck >> 2, p4 = (ck & 3) * 4;
            int reg = ridx_sh[sel];
            int h = pair * 2 + h2;
            uint2 v = *reinterpret_cast<const uint2*>(
                kvpT + (((size_t)(b * 64 + reg) * 128) + h * 16 + d) * 16 + p4);
            *reinterpret_cast<uint2*>(&VTsh[h2][d * 528 + (sel * 16 + p4) * 2]) = v;
        }
        __syncthreads();

        int h = pair * 2 + hh;
        bf16x8 qf = *reinterpret_cast<const bf16x8*>(
            qsh + (qt * 32 + l31) * 272 + h * 32 + hi * 16);
        float m_run = -INFINITY, l_run = 0.f;
        f32x16 opv;
#pragma unroll
        for (int r = 0; r < 16; r++) opv[r] = 0.f;
        f32x16 zf;
#pragma unroll
        for (int r = 0; r < 16; r++) zf[r] = 0.f;

        for (int t8 = 0; t8 < 8; t8++) {
            bf16x8 kf = *reinterpret_cast<const bf16x8*>(
                &Ksh[hh][(t8 * 32 + l31) * 48 + hi * 16]);
            f32x16 S = __builtin_amdgcn_mfma_f32_32x32x16_bf16(kf, qf, zf, 0, 0, 0);
            float tm = S[0];
#pragma unroll
            for (int r = 1; r < 16; r++) tm = fmaxf(tm, S[r]);
            tm = fmaxf(tm, __shfl_xor(tm, 32, 64));
            float m_new = fmaxf(m_run, tm);
            float corr = __expf(m_run - m_new);
            float p_[16], psum = 0.f;
#pragma unroll
            for (int r = 0; r < 16; r++) { p_[r] = __expf(S[r] - m_new); psum += p_[r]; }
            psum += __shfl_xor(psum, 32, 64);
            l_run = l_run * corr + psum;
            m_run = m_new;
#pragma unroll
            for (int r = 0; r < 16; r++) opv[r] *= corr;
            unsigned w_[8], pw_[8];
#pragma unroll
            for (int j = 0; j < 8; j++)
                w_[j] = (__float_as_uint(p_[2 * j]) >> 16) |
                        (__float_as_uint(p_[2 * j + 1]) & 0xFFFF0000u);
#pragma unroll
            for (int j = 0; j < 8; j++) pw_[j] = __shfl_xor(w_[j], 32, 64);
            union { unsigned u[4]; bf16x8 v; } fa0, fa1;
            fa0.u[0] = hi ? pw_[2] : w_[0];
            fa0.u[1] = hi ? pw_[3] : w_[1];
            fa0.u[2] = hi ? w_[2]  : pw_[0];
            fa0.u[3] = hi ? w_[3]  : pw_[1];
            fa1.u[0] = hi ? pw_[6] : w_[4];
            fa1.u[1] = hi ? pw_[7] : w_[5];
            fa1.u[2] = hi ? w_[6]  : pw_[4];
            fa1.u[3] = hi ? w_[7]  : pw_[5];
            const unsigned char* vb = &VTsh[hh][(l31 & 15) * 528 + t8 * 64];
            bf16x8 bf0 = *reinterpret_cast<const bf16x8*>(vb + hi * 16);
            bf16x8 bf1 = *reinterpret_cast<const bf16x8*>(vb + 32 + hi * 16);
            opv = __builtin_amdgcn_mfma_f32_32x32x16_bf16(fa0.v, bf0, opv, 0, 0, 0);
            opv = __builtin_amdgcn_mfma_f32_32x32x16_bf16(fa1.v, bf1, opv, 0, 0, 0);
        }
        denom_sh[wv][l31] = l_run;
        if (l31 < 16) {
#pragma unroll
            for (int r = 0; r < 16; r++) {
                int qr = (r & 3) + 8 * (r >> 2) + 4 * hi;
                float invd = 1.f / denom_sh[wv][qr];
                int q = qt * 32 + qr;
                int y = wi * 8 + (q >> 3), x = wj * 8 + (q & 7);
                o[((size_t)(b * H + y) * W + x) * 128 + h * 16 + l31] = opv[r] * invd;
            }
        }
    }
}

// ------------------------- NHWC v-half -> fp32 NCHW planes [B][C][64][64]
__global__ __launch_bounds__(256) void transpose_v_k(const float* __restrict__ kv,
                                                     float* __restrict__ vpl) {
    int b = blockIdx.y, y = blockIdx.x * 2 + (threadIdx.x >> 7);
    int c = threadIdx.x & 127;
    const float* src = kv + ((size_t)(b * H + y) * W) * 256 + 128 + c;
    float* dst = vpl + ((size_t)(b * C + c) * H + y) * W;
#pragma unroll
    for (int xg = 0; xg < 16; xg++) {
        float4 v;
        v.x = src[(xg * 4 + 0) * 256];
        v.y = src[(xg * 4 + 1) * 256];
        v.z = src[(xg * 4 + 2) * 256];
        v.w = src[(xg * 4 + 3) * 256];
        *reinterpret_cast<float4*>(dst + xg * 4) = v;
    }
}

// ------------------ LePE depthwise 5x5 on planes, LDS-tiled (writes lep planes)
__global__ __launch_bounds__(256) void lepe_plane_k(const float* __restrict__ vpl,
                                                    const float* __restrict__ w,
                                                    const float* __restrict__ bias,
                                                    float* __restrict__ lep) {
    __shared__ float tile[68][69];
    int c = blockIdx.x, b = blockIdx.y;
    int t = threadIdx.x;
    const float* plane = vpl + (size_t)(b * C + c) * 4096;
    for (int e = t; e < 68 * 68; e += 256) {
        int row = e / 68, col = e - row * 68;
        int gy = row - 2, gx = col - 2;
        tile[row][col] = (gy >= 0 && gy < 64 && gx >= 0 && gx < 64)
                         ? plane[gy * 64 + gx] : 0.f;
    }
    float wv[25];
#pragma unroll
    for (int j = 0; j < 25; j++) wv[j] = w[c * 25 + j];
    float bb = bias[c];
    __syncthreads();
    int y = t >> 2, x0 = (t & 3) * 16;
    float acc[16];
#pragma unroll
    for (int i = 0; i < 16; i++) acc[i] = bb;
#pragma unroll
    for (int dy = 0; dy < 5; dy++) {
        float vals[20];
#pragma unroll
        for (int j = 0; j < 20; j++) vals[j] = tile[y + dy][x0 + j];
#pragma unroll
        for (int dx = 0; dx < 5; dx++)
#pragma unroll
            for (int i = 0; i < 16; i++)
                acc[i] += vals[i + dx] * wv[dy * 5 + dx];
    }
    float* dst = lep + (size_t)(b * C + c) * 4096 + y * 64 + x0;
#pragma unroll
    for (int i = 0; i < 16; i += 4)
        *reinterpret_cast<float4*>(dst + i) =
            make_float4(acc[i], acc[i + 1], acc[i + 2], acc[i + 3]);
}

// -------------------- ((o_attn + lepe) @ Wo^T + b) + x, write NCHW output
__global__ __launch_bounds__(128) void epilogue_k(const float* __restrict__ o,
                                                  const float* __restrict__ lep,
                                                  const float* __restrict__ xbuf,
                                                  const float* __restrict__ woT,
                                                  const float* __restrict__ wo_b,
                                                  float* __restrict__ out) {
    __shared__ float ot[16][128];
    __shared__ float res[128][17];
    int b = blockIdx.z, y = blockIdx.y, x0 = blockIdx.x * 16;
    int t = threadIdx.x;
    size_t pixBase = (size_t)(b * H + y) * W + x0;
    const float* lrow = lep + (size_t)(b * C + t) * 4096 + y * 64 + x0;
    for (int p = 0; p < 16; p++)
        ot[p][t] = o[(pixBase + p) * 128 + t] + lrow[p];
    __syncthreads();
    float acc[16];
    float wb = wo_b[t];
#pragma unroll
    for (int p = 0; p < 16; p++) acc[p] = wb + xbuf[(pixBase + p) * 128 + t];
    for (int k = 0; k < 128; k += 4) {
        float w0 = woT[(k + 0) * 128 + t];
        float w1 = woT[(k + 1) * 128 + t];
        float w2 = woT[(k + 2) * 128 + t];
        float w3 = woT[(k + 3) * 128 + t];
#pragma unroll
        for (int p = 0; p < 16; p++) {
            const float4 av = *reinterpret_cast<const float4*>(&ot[p][k]);
            acc[p] += av.x * w0 + av.y * w1 + av.z * w2 + av.w * w3;
        }
    }
#pragma unroll
    for (int p = 0; p < 16; p++) res[t][p] = acc[p];
    __syncthreads();
    int xi = t & 15, cg = t >> 4;
    for (int i = 0; i < 16; i++) {
        int c = cg * 16 + i;
        out[((size_t)(b * C + c) * H + y) * W + x0 + xi] = res[c][xi];
    }
}

extern "C" void kernel_launch(void* const* d_in, const int* in_sizes, int n_in,
                              void* d_out, int out_size, void* d_ws, size_t ws_size,
                              hipStream_t stream) {
    const float* t1      = (const float*)d_in[0];
    const float* t2      = (const float*)d_in[1];
    const float* pos_w   = (const float*)d_in[2];
    const float* pos_b   = (const float*)d_in[3];
    const float* cat_w   = (const float*)d_in[4];
    const float* cat_b   = (const float*)d_in[5];
    const float* ln_cat_g= (const float*)d_in[6];
    const float* ln_cat_b= (const float*)d_in[7];
    const float* ln1_g   = (const float*)d_in[8];
    const float* ln1_b   = (const float*)d_in[9];
    const float* qkv_w   = (const float*)d_in[10];
    const float* qkv_b   = (const float*)d_in[11];
    const float* lepe_w  = (const float*)d_in[12];
    const float* lepe_b  = (const float*)d_in[13];
    const float* wo_w    = (const float*)d_in[14];
    const float* wo_b    = (const float*)d_in[15];

    float* ws    = (float*)d_ws;
    float* t1c   = ws + OFF_T1C;
    float* t2c   = ws + OFF_T2C;
    float* xbuf  = ws + OFF_X;
    ushort_t* qbuf = (ushort_t*)(ws + OFF_QB);
    float* kvbuf = ws + OFF_KV;
    float* kvpix = ws + OFF_KVP;
    ushort_t* kvpT = (ushort_t*)(ws + OFF_KVPT);
    float* m1    = ws + OFF_M1;
    float* m2    = ws + OFF_M2;
    float* qwin  = ws + OFF_QW;
    float* kwin  = ws + OFF_KW;
    int*   ridx  = (int*)(ws + OFF_RIDX);
    ushort_t* wcat2 = (ushort_t*)(ws + OFF_WCB);
    ushort_t* qkvB  = (ushort_t*)(ws + OFF_QKVB);
    float* woT   = ws + OFF_WOT;
    float* obuf  = ws + OFF_O;    // alias of t1c (dead after ln_qkv q / win_mean)
    float* vpl   = ws + OFF_VPL;  // alias of t2c (dead after ln_qkv kv / win_mean)
    float* lep   = ws + OFF_LEP;  // alias of kvbuf (dead after pool_k + transpose_v)
    float* out   = (float*)d_out;

    transpose_weights<<<dim3((36 * 8 * 128 * 8 + 255) / 256), 256, 0, stream>>>(
        qkv_w, wo_w, cat_w, qkvB, woT, wcat2);
    pos_conv_k<<<dim3(2, 4, B * H), 256, 0, stream>>>(t1, pos_w, pos_b, t1c);
    pos_conv_k<<<dim3(2, 4, B * H), 256, 0, stream>>>(t2, pos_w, pos_b, t2c);
    catconv_mfma_k<<<dim3(8, 8, 8), 512, 0, stream>>>(
        t1c, t2c, wcat2, cat_b, ln_cat_g, ln_cat_b, xbuf);
    win_mean_k<<<dim3(64, B), 256, 0, stream>>>(t1c, t2c, ln1_g, ln1_b, m1, m2);
    route_gemm_k<<<dim3(8, B), 256, 0, stream>>>(m1, m2, qkv_w, qkv_b, qwin, kwin);
    route_k<<<dim3(64, B), 64, 0, stream>>>(qwin, kwin, ridx);
    ln_qkv_mfma_k<2, true><<<dim3(512), 256, 0, stream>>>(
        t1c, ln1_g, ln1_b, qkvB, 0, qkv_b, qbuf, nullptr);
    ln_qkv_mfma_k<4, false><<<dim3(512), 256, 0, stream>>>(
        t2c, ln1_g, ln1_b, qkvB, 128, qkv_b, nullptr, kvbuf);
    pool_k<<<dim3(64, B), 256, 0, stream>>>(kvbuf, kvpix, kvpT);
    transpose_v_k<<<dim3(32, B), 256, 0, stream>>>(kvbuf, vpl);
    attn_mfma_k<<<dim3(64, B), 256, 0, stream>>>(qbuf, kvpix, kvpT, ridx, obuf);
    lepe_plane_k<<<dim3(C, B), 256, 0, stream>>>(vpl, lepe_w, lepe_b, lep);
    epilogue_k<<<dim3(4, 64, 8), 128, 0, stream>>>(obuf, lep, xbuf, woT, wo_b, out);
}

// Round 6
// 249.527 us; speedup vs baseline: 4.2562x; 1.0891x over previous
//
#include <hip/hip_runtime.h>
#include <math.h>

typedef unsigned short ushort_t;
typedef __attribute__((ext_vector_type(4))) float f32x4;
typedef __attribute__((ext_vector_type(16))) float f32x16;
typedef __attribute__((ext_vector_type(8))) short bf16x8;

constexpr int B = 8, C = 128, H = 64, W = 64;
constexpr int HEADS = 8, TOPK = 16;
constexpr int P2 = 64;
constexpr float SCALE = 0.0883883476483184405f; // 128^-0.5

// workspace offsets (in floats)
constexpr size_t NPIX    = (size_t)B * H * W;            // 32768
constexpr size_t OFF_T1C = 0;                            // NHWC fp32 (B,H,W,128)
constexpr size_t OFF_T2C = OFF_T1C + NPIX * 128;
constexpr size_t OFF_X   = OFF_T2C + NPIX * 128;         // relu(LN(catconv)) fp32
constexpr size_t OFF_QB  = OFF_X   + NPIX * 128;         // q*SCALE bf16 (NPIX*128 shorts)
constexpr size_t OFF_KV  = OFF_QB  + NPIX * 64;          // kv fp32 (B,H,W,256)
constexpr size_t OFF_KVP = OFF_KV  + NPIX * 256;         // K bf16 [B,64,16,128] (reuses old kv_pix slot)
constexpr size_t OFF_KVPT= OFF_KVP + (size_t)B * P2 * 16 * 256; // v^T bf16 [B,64,128,16]
constexpr size_t OFF_M1  = OFF_KVPT+ (size_t)B * P2 * 128 * 16 / 2;
constexpr size_t OFF_M2  = OFF_M1  + (size_t)B * P2 * 128;
constexpr size_t OFF_QW  = OFF_M2  + (size_t)B * P2 * 128;
constexpr size_t OFF_KW  = OFF_QW  + (size_t)B * P2 * 128;
constexpr size_t OFF_RIDX= OFF_KW  + (size_t)B * P2 * 128;      // int
constexpr size_t OFF_WCB = OFF_RIDX+ (size_t)B * P2 * TOPK;     // wcat2 bf16 [36][2][4][128][8]
constexpr size_t OFF_QKVB= OFF_WCB + (size_t)9 * 256 * 128;     // qkv_w bf16 [384][128]
constexpr size_t OFF_WOT = OFF_QKVB+ (size_t)384 * 128 / 2;     // [128][128] fp32
constexpr size_t OFF_O   = OFF_T1C;  // attention output aliases t1c
constexpr size_t OFF_VPL = OFF_T2C;  // v planes fp32 [B][C][64][64] alias t2c (dead)
constexpr size_t OFF_LEP = OFF_KV;   // lepe planes fp32 [B][C][64][64] alias kvbuf (dead)

__device__ inline ushort_t f2bf(float f) {
    unsigned u = __float_as_uint(f);
    unsigned r = u + 0x7FFFu + ((u >> 16) & 1u);
    return (ushort_t)(r >> 16);
}

// ---------------------------------------------------------------- weights prep
__global__ void transpose_weights(const float* __restrict__ qkv_w,
                                  const float* __restrict__ wo_w,
                                  const float* __restrict__ cat_w,
                                  ushort_t* __restrict__ qkvB,
                                  float* __restrict__ woT,
                                  ushort_t* __restrict__ wcat2) {
    int idx = blockIdx.x * 256 + threadIdx.x;
    if (idx < 384 * 128) {           // qkvB[n][k] bf16 (same layout as qkv_w)
        qkvB[idx] = f2bf(qkv_w[idx]);
    }
    if (idx < 128 * 128) {           // woT[k][n] = wo_w[n][k]
        int k = idx / 128, n = idx % 128;
        woT[idx] = wo_w[n * 128 + k];
    }
    if (idx < 36 * 8 * 128 * 8) {    // wcat2[((q*9+dd)*8+kk*4+lg)][n][i]
        int i  = idx & 7;
        int n  = (idx >> 3) & 127;
        int r  = idx >> 10;
        int lg = r & 3;
        int kk = (r >> 2) & 1;
        int sdd = r >> 3;            // 0..35
        int dd = sdd % 9, q = sdd / 9;
        int ci = q * 64 + kk * 32 + lg * 8 + i;
        wcat2[idx] = f2bf(cat_w[((size_t)n * 256 + ci) * 9 + dd]);
    }
}

// --------------------------------------- depthwise 3x3 + residual, NCHW->NHWC
__global__ __launch_bounds__(256) void pos_conv_k(const float* __restrict__ in,
                                                  const float* __restrict__ w,
                                                  const float* __restrict__ bias,
                                                  float* __restrict__ outNHWC) {
    __shared__ float tile[32][33];
    int b = blockIdx.z / H, y = blockIdx.z % H;
    int c0 = blockIdx.y * 32, x0 = blockIdx.x * 32;
    int tx = threadIdx.x & 31, tg = threadIdx.x >> 5;
    for (int i = 0; i < 4; i++) {
        int cl = tg * 4 + i, c = c0 + cl;
        const float* base = in + (size_t)(b * C + c) * H * W;
        float acc = base[y * W + x0 + tx];
        float wv[9];
#pragma unroll
        for (int j = 0; j < 9; j++) wv[j] = w[c * 9 + j];
#pragma unroll
        for (int dy = 0; dy < 3; dy++) {
            int yy = y + dy - 1;
            if (yy < 0 || yy >= H) continue;
#pragma unroll
            for (int dx = 0; dx < 3; dx++) {
                int xx = x0 + tx + dx - 1;
                if (xx < 0 || xx >= W) continue;
                acc += base[yy * W + xx] * wv[dy * 3 + dx];
            }
        }
        tile[cl][tx] = acc + bias[c];
    }
    __syncthreads();
    for (int i = 0; i < 4; i++) {
        int xl = tg * 4 + i;
        outNHWC[((size_t)(b * H + y) * W + x0 + xl) * 128 + c0 + tx] = tile[tx][xl];
    }
}

// ------------- cat-conv 256->128 3x3 implicit-GEMM MFMA + fused LN+ReLU (v2)
__global__ __launch_bounds__(512) void catconv_mfma_k(
        const float* __restrict__ t1c, const float* __restrict__ t2c,
        const ushort_t* __restrict__ wcat2,
        const float* __restrict__ cat_b,
        const float* __restrict__ g, const float* __restrict__ beta,
        float* __restrict__ xbuf) {
    __shared__ __align__(16) unsigned char smem[64 * 132 * 4 + 2 * 64 * 4];
    int t = threadIdx.x;
    int lane = t & 63, wv = t >> 6;
    int mw = wv >> 2, nw = wv & 3;
    int l15 = lane & 15, lg = lane >> 4;
    int b = blockIdx.z, y0 = blockIdx.y * 8, x0 = blockIdx.x * 8;

    f32x4 acc[2][2];
#pragma unroll
    for (int m = 0; m < 2; m++)
#pragma unroll
        for (int cf = 0; cf < 2; cf++)
            acc[m][cf] = (f32x4){0.f, 0.f, 0.f, 0.f};

    int pyA[2], pxA[2];
#pragma unroll
    for (int m = 0; m < 2; m++) {
        int p = mw * 32 + m * 16 + l15;
        pyA[m] = p >> 3; pxA[m] = p & 7;
    }

    for (int q = 0; q < 4; q++) {
        __syncthreads();
        {
            const float* src = (q < 2 ? t1c : t2c) + (q & 1) * 64;
            for (int e = t; e < 1600; e += 512) {
                int pix = e >> 4, c4 = e & 15;
                int hy = pix / 10, hx = pix - hy * 10;
                int gy = y0 - 1 + hy, gx = x0 - 1 + hx;
                float4 v = make_float4(0.f, 0.f, 0.f, 0.f);
                if (gy >= 0 && gy < H && gx >= 0 && gx < W)
                    v = *reinterpret_cast<const float4*>(
                        src + ((size_t)(b * H + gy) * W + gx) * 128 + c4 * 4);
                uint2 pk;
                pk.x = (unsigned)f2bf(v.x) | ((unsigned)f2bf(v.y) << 16);
                pk.y = (unsigned)f2bf(v.z) | ((unsigned)f2bf(v.w) << 16);
                *reinterpret_cast<uint2*>(smem + pix * 144 + c4 * 8) = pk;
            }
        }
        __syncthreads();
#pragma unroll
        for (int dd = 0; dd < 9; dd++) {
            int dy = dd / 3, dx = dd - dy * 3;
            const ushort_t* wb = wcat2 + ((size_t)((q * 9 + dd) * 8 + lg) * 128) * 8;
            bf16x8 bfr[2][2];
#pragma unroll
            for (int kk = 0; kk < 2; kk++)
#pragma unroll
                for (int cf = 0; cf < 2; cf++)
                    bfr[kk][cf] = *reinterpret_cast<const bf16x8*>(
                        wb + (size_t)kk * 4096 + (nw * 32 + cf * 16 + l15) * 8);
            bf16x8 af[2][2];
#pragma unroll
            for (int m = 0; m < 2; m++)
#pragma unroll
                for (int kk = 0; kk < 2; kk++)
                    af[m][kk] = *reinterpret_cast<const bf16x8*>(
                        smem + ((pyA[m] + dy) * 10 + pxA[m] + dx) * 144 + kk * 64 + lg * 16);
#pragma unroll
            for (int m = 0; m < 2; m++)
#pragma unroll
                for (int cf = 0; cf < 2; cf++)
#pragma unroll
                    for (int kk = 0; kk < 2; kk++)
                        acc[m][cf] = __builtin_amdgcn_mfma_f32_16x16x32_bf16(
                            af[m][kk], bfr[kk][cf], acc[m][cf], 0, 0, 0);
        }
    }

    __syncthreads();
    float* res = (float*)smem;
    float* mstat = (float*)(smem + 64 * 132 * 4);
#pragma unroll
    for (int cf = 0; cf < 2; cf++) {
        int n = nw * 32 + cf * 16 + l15;
        float cb = cat_b[n];
#pragma unroll
        for (int m = 0; m < 2; m++)
#pragma unroll
            for (int i = 0; i < 4; i++)
                res[(mw * 32 + m * 16 + lg * 4 + i) * 132 + n] = acc[m][cf][i] + cb;
    }
    __syncthreads();
    {
        int pix = t >> 3, sub = t & 7;
        float s1 = 0.f;
#pragma unroll
        for (int j = 0; j < 16; j++) s1 += res[pix * 132 + sub + j * 8];
        s1 += __shfl_xor(s1, 1, 64);
        s1 += __shfl_xor(s1, 2, 64);
        s1 += __shfl_xor(s1, 4, 64);
        float mean = s1 * (1.f / 128.f);
        float s2 = 0.f;
#pragma unroll
        for (int j = 0; j < 16; j++) {
            float d = res[pix * 132 + sub + j * 8] - mean;
            s2 += d * d;
        }
        s2 += __shfl_xor(s2, 1, 64);
        s2 += __shfl_xor(s2, 2, 64);
        s2 += __shfl_xor(s2, 4, 64);
        float inv = rsqrtf(s2 * (1.f / 128.f) + 1e-5f);
        if (sub == 0) { mstat[pix] = mean; mstat[64 + pix] = inv; }
    }
    __syncthreads();
    {
        int c = t & 127, pg = t >> 7;
        float gg = g[c], bb = beta[c];
        for (int j = 0; j < 16; j++) {
            int p2 = j * 4 + pg;
            float v = (res[p2 * 132 + c] - mstat[p2]) * mstat[64 + p2] * gg + bb;
            int py = p2 >> 3, px = p2 & 7;
            xbuf[((size_t)(b * H + y0 + py) * W + x0 + px) * 128 + c] = fmaxf(v, 0.f);
        }
    }
}

// ------------------------ LN(1e-6) + QKV projection, bf16 MFMA (M=64 per block)
template<int NPW, bool QOUT>
__global__ __launch_bounds__(256) void ln_qkv_mfma_k(
        const float* __restrict__ in,
        const float* __restrict__ g, const float* __restrict__ beta,
        const ushort_t* __restrict__ wB,   // bf16 [384][128]
        int nOff,
        const float* __restrict__ bias,
        ushort_t* __restrict__ outQ,
        float* __restrict__ outKV) {
    __shared__ __align__(16) unsigned char ash[64 * 272];
    int t = threadIdx.x;
    int lane = t & 63, wv = t >> 6;
    size_t p0 = (size_t)blockIdx.x * 64;
    {
        int row = t >> 2, sub = t & 3;
        const float* src = in + (p0 + row) * 128 + sub * 32;
        float4 v[8];
        float s = 0.f;
#pragma unroll
        for (int j = 0; j < 8; j++) {
            v[j] = *reinterpret_cast<const float4*>(src + j * 4);
            s += v[j].x + v[j].y + v[j].z + v[j].w;
        }
        s += __shfl_xor(s, 1, 64); s += __shfl_xor(s, 2, 64);
        float mean = s * (1.f / 128.f);
        float s2 = 0.f;
#pragma unroll
        for (int j = 0; j < 8; j++) {
            float dx = v[j].x - mean, dy = v[j].y - mean;
            float dz = v[j].z - mean, dw = v[j].w - mean;
            s2 += dx * dx + dy * dy + dz * dz + dw * dw;
        }
        s2 += __shfl_xor(s2, 1, 64); s2 += __shfl_xor(s2, 2, 64);
        float inv = rsqrtf(s2 * (1.f / 128.f) + 1e-6f);
#pragma unroll
        for (int j = 0; j < 8; j++) {
            int c = sub * 32 + j * 4;
            float4 gv = *reinterpret_cast<const float4*>(g + c);
            float4 bv = *reinterpret_cast<const float4*>(beta + c);
            float o0 = (v[j].x - mean) * inv * gv.x + bv.x;
            float o1 = (v[j].y - mean) * inv * gv.y + bv.y;
            float o2 = (v[j].z - mean) * inv * gv.z + bv.z;
            float o3 = (v[j].w - mean) * inv * gv.w + bv.w;
            uint2 pk;
            pk.x = (unsigned)f2bf(o0) | ((unsigned)f2bf(o1) << 16);
            pk.y = (unsigned)f2bf(o2) | ((unsigned)f2bf(o3) << 16);
            *reinterpret_cast<uint2*>(ash + row * 272 + c * 2) = pk;
        }
    }
    __syncthreads();
    int l15 = lane & 15, lg = lane >> 4;
    f32x4 acc[4][NPW];
#pragma unroll
    for (int mt = 0; mt < 4; mt++)
#pragma unroll
        for (int nn = 0; nn < NPW; nn++)
            acc[mt][nn] = (f32x4){0.f, 0.f, 0.f, 0.f};
#pragma unroll
    for (int ks = 0; ks < 4; ks++) {
        bf16x8 af[4];
#pragma unroll
        for (int mt = 0; mt < 4; mt++)
            af[mt] = *reinterpret_cast<const bf16x8*>(
                ash + (mt * 16 + l15) * 272 + ks * 64 + lg * 16);
#pragma unroll
        for (int nn = 0; nn < NPW; nn++) {
            int n = nOff + (wv * NPW + nn) * 16 + l15;
            bf16x8 bfr = *reinterpret_cast<const bf16x8*>(
                wB + (size_t)n * 128 + ks * 32 + lg * 8);
#pragma unroll
            for (int mt = 0; mt < 4; mt++)
                acc[mt][nn] = __builtin_amdgcn_mfma_f32_16x16x32_bf16(
                    af[mt], bfr, acc[mt][nn], 0, 0, 0);
        }
    }
#pragma unroll
    for (int nn = 0; nn < NPW; nn++) {
        int cg = (wv * NPW + nn) * 16 + l15;
        float bv = bias[nOff + cg];
#pragma unroll
        for (int mt = 0; mt < 4; mt++) {
#pragma unroll
            for (int i = 0; i < 4; i++) {
                size_t pix = p0 + mt * 16 + lg * 4 + i;
                float val = acc[mt][nn][i] + bv;
                if (QOUT) outQ[pix * 128 + cg] = f2bf(val * SCALE);
                else      outKV[pix * 256 + cg] = val;
            }
        }
    }
}

// ------------------- exact fp32 window means of LN (routing path)
__global__ __launch_bounds__(256) void win_mean_k(
        const float* __restrict__ t1c, const float* __restrict__ t2c,
        const float* __restrict__ g, const float* __restrict__ beta,
        float* __restrict__ m1, float* __restrict__ m2) {
    __shared__ float mws[4][128];
    int b = blockIdx.y, win = blockIdx.x;
    int wi = win >> 3, wj = win & 7;
    int t = threadIdx.x, lane = t & 63, wv = t >> 6;
    int pixw = lane >> 2, sub = lane & 3;
    int p = wv * 16 + pixw;
    int y = wi * 8 + (p >> 3), x = wj * 8 + (p & 7);
    size_t base = ((size_t)(b * H + y) * W + x) * 128 + sub * 32;
    for (int which = 0; which < 2; which++) {
        const float* src = (which == 0 ? t1c : t2c) + base;
        float4 v[8];
        float s = 0.f;
#pragma unroll
        for (int j = 0; j < 8; j++) {
            v[j] = *reinterpret_cast<const float4*>(src + j * 4);
            s += v[j].x + v[j].y + v[j].z + v[j].w;
        }
        s += __shfl_xor(s, 1, 64); s += __shfl_xor(s, 2, 64);
        float mean = s * (1.f / 128.f);
        float s2 = 0.f;
#pragma unroll
        for (int j = 0; j < 8; j++) {
            float dx = v[j].x - mean, dy = v[j].y - mean;
            float dz = v[j].z - mean, dw = v[j].w - mean;
            s2 += dx * dx + dy * dy + dz * dz + dw * dw;
        }
        s2 += __shfl_xor(s2, 1, 64); s2 += __shfl_xor(s2, 2, 64);
        float inv = rsqrtf(s2 * (1.f / 128.f) + 1e-6f);
#pragma unroll
        for (int j = 0; j < 8; j++) {
            int c = sub * 32 + j * 4;
            float4 gv = *reinterpret_cast<const float4*>(g + c);
            float4 bv = *reinterpret_cast<const float4*>(beta + c);
            v[j].x = (v[j].x - mean) * inv * gv.x + bv.x;
            v[j].y = (v[j].y - mean) * inv * gv.y + bv.y;
            v[j].z = (v[j].z - mean) * inv * gv.z + bv.z;
            v[j].w = (v[j].w - mean) * inv * gv.w + bv.w;
        }
#pragma unroll
        for (int m = 4; m <= 32; m <<= 1) {
#pragma unroll
            for (int j = 0; j < 8; j++) {
                v[j].x += __shfl_xor(v[j].x, m, 64);
                v[j].y += __shfl_xor(v[j].y, m, 64);
                v[j].z += __shfl_xor(v[j].z, m, 64);
                v[j].w += __shfl_xor(v[j].w, m, 64);
            }
        }
        if (pixw == 0) {
#pragma unroll
            for (int j = 0; j < 8; j++)
                *reinterpret_cast<float4*>(&mws[wv][sub * 32 + j * 4]) = v[j];
        }
        __syncthreads();
        if (t < 128) {
            float mval = (mws[0][t] + mws[1][t] + mws[2][t] + mws[3][t]) * (1.f / 64.f);
            (which ? m2 : m1)[((size_t)b * 64 + win) * 128 + t] = mval;
        }
        __syncthreads();
    }
}

// ------------------- fp32 q_win/k_win projection (routing path, exact)
__global__ __launch_bounds__(256) void route_gemm_k(
        const float* __restrict__ m1, const float* __restrict__ m2,
        const float* __restrict__ qkv_w, const float* __restrict__ qkv_b,
        float* __restrict__ qwin, float* __restrict__ kwin) {
    __shared__ float msh[2][8][128];
    int b = blockIdx.y, ch = blockIdx.x;
    int t = threadIdx.x;
    for (int i = t; i < 8 * 128; i += 256) {
        int r = i >> 7, c = i & 127;
        msh[0][r][c] = m1[((size_t)b * 64 + ch * 8 + r) * 128 + c];
        msh[1][r][c] = m2[((size_t)b * 64 + ch * 8 + r) * 128 + c];
    }
    __syncthreads();
    int c = t;
    int which = c >> 7;
    const float* wrow = qkv_w + (size_t)c * 128;
    float acc[8];
#pragma unroll
    for (int r = 0; r < 8; r++) acc[r] = 0.f;
    for (int k = 0; k < 128; k++) {
        float wv_ = wrow[k];
#pragma unroll
        for (int r = 0; r < 8; r++) acc[r] += msh[which][r][k] * wv_;
    }
    float bv = qkv_b[c];
#pragma unroll
    for (int r = 0; r < 8; r++) {
        size_t o = ((size_t)b * 64 + ch * 8 + r) * 128 + (c & 127);
        (which ? kwin : qwin)[o] = acc[r] + bv;
    }
}

// ----------------- window pooling: K bf16 [B,64,16,128] + v^T bf16 [B,64,128,16]
__global__ __launch_bounds__(256) void pool_k(const float* __restrict__ kv,
                                              ushort_t* __restrict__ kb,
                                              ushort_t* __restrict__ kvpT) {
    int b = blockIdx.y, wdw = blockIdx.x;
    int wi = wdw >> 3, wj = wdw & 7;
    int t = threadIdx.x;
    float vals[16];
    for (int ry = 0; ry < 4; ry++)
        for (int rx = 0; rx < 4; rx++) {
            float s = 0.f;
            for (int fy = 0; fy < 2; fy++)
                for (int fx = 0; fx < 2; fx++) {
                    int y = wi * 8 + ry * 2 + fy, x = wj * 8 + rx * 2 + fx;
                    s += kv[((size_t)(b * H + y) * W + x) * 256 + t];
                }
            vals[ry * 4 + rx] = s * 0.25f;
        }
    if (t < 128) {
        // K channels -> bf16 [pos][128]
#pragma unroll
        for (int pos = 0; pos < 16; pos++)
            kb[(((size_t)(b * 64 + wdw)) * 16 + pos) * 128 + t] = f2bf(vals[pos]);
    } else {
        union { ushort_t u16[16]; uint4 u4[2]; } pk;
#pragma unroll
        for (int i = 0; i < 16; i++) pk.u16[i] = f2bf(vals[i]);
        size_t base = (((size_t)(b * 64 + wdw)) * 128 + (t - 128)) * 16;
        *reinterpret_cast<uint4*>(kvpT + base) = pk.u4[0];
        *reinterpret_cast<uint4*>(kvpT + base + 8) = pk.u4[1];
    }
}

// ------------------------------------------------ routing logits + top-16
__global__ __launch_bounds__(64) void route_k(const float* __restrict__ q_win,
                                              const float* __restrict__ k_win,
                                              int* __restrict__ r_idx) {
    int b = blockIdx.y, p = blockIdx.x, j = threadIdx.x;
    const float* qp = q_win + (size_t)(b * 64 + p) * 128;
    const float* kp = k_win + (size_t)(b * 64 + j) * 128;
    float lg = 0.f;
    for (int c = 0; c < 128; c++) lg += qp[c] * kp[c];
    lg *= SCALE;
    for (int it = 0; it < TOPK; it++) {
        float v = lg; int idx = j;
#pragma unroll
        for (int m = 32; m > 0; m >>= 1) {
            float ov = __shfl_xor(v, m, 64);
            int   oi = __shfl_xor(idx, m, 64);
            if (ov > v || (ov == v && oi < idx)) { v = ov; idx = oi; }
        }
        if (j == 0) r_idx[(size_t)(b * 64 + p) * TOPK + it] = idx;
        if (j == idx) lg = -__builtin_inff();
    }
}

// ---------------- routed attention v3: staging-free, all frags direct from L2
__global__ __launch_bounds__(256) void attn_mfma_k(
        const ushort_t* __restrict__ qb,     // bf16 q*SCALE [B,H,W,128]
        const ushort_t* __restrict__ kb,     // bf16 [B,64,16,128]
        const ushort_t* __restrict__ kvpT,   // bf16 [B,64,128,16]
        const int* __restrict__ r_idx,
        float* __restrict__ o) {
    __shared__ int ridx_sh[16];
    __shared__ float denom_sh[4][32];

    int b = blockIdx.z, p = blockIdx.x, pair = blockIdx.y;
    int wi = p >> 3, wj = p & 7;
    int t = threadIdx.x;
    int lane = t & 63, wv = t >> 6;
    int l31 = lane & 31, hi = lane >> 5;

    if (t < 16) ridx_sh[t] = r_idx[(size_t)(b * 64 + p) * TOPK + t];
    __syncthreads();

    int hh = wv >> 1, qt = wv & 1;
    int h = pair * 2 + hh;

    int q = qt * 32 + l31;
    int qy = wi * 8 + (q >> 3), qx = wj * 8 + (q & 7);
    bf16x8 qf = *reinterpret_cast<const bf16x8*>(
        qb + ((size_t)(b * H + qy) * W + qx) * 128 + h * 16 + hi * 8);

    const ushort_t* kb_b = kb + (size_t)b * 64 * 16 * 128 + h * 16 + hi * 8;
    const ushort_t* vt_b = kvpT + (size_t)b * 64 * 128 * 16 + (h * 16 + (l31 & 15)) * 16 + hi * 8;

    float m_run = -INFINITY, l_run = 0.f;
    f32x16 opv;
#pragma unroll
    for (int r = 0; r < 16; r++) opv[r] = 0.f;
    f32x16 zf;
#pragma unroll
    for (int r = 0; r < 16; r++) zf[r] = 0.f;

    // prologue loads (t8 = 0)
    bf16x8 kf = *reinterpret_cast<const bf16x8*>(
        kb_b + ((size_t)ridx_sh[l31 >> 4] * 16 + (l31 & 15)) * 128);
    bf16x8 v0 = *reinterpret_cast<const bf16x8*>(vt_b + (size_t)ridx_sh[0] * 2048);
    bf16x8 v1 = *reinterpret_cast<const bf16x8*>(vt_b + (size_t)ridx_sh[1] * 2048);

    for (int t8 = 0; t8 < 8; t8++) {
        bf16x8 kfn = kf, v0n = v0, v1n = v1;
        if (t8 < 7) {   // prefetch next tile's frags (hides L2 latency under softmax)
            kfn = *reinterpret_cast<const bf16x8*>(
                kb_b + ((size_t)ridx_sh[2 * t8 + 2 + (l31 >> 4)] * 16 + (l31 & 15)) * 128);
            v0n = *reinterpret_cast<const bf16x8*>(vt_b + (size_t)ridx_sh[2 * t8 + 2] * 2048);
            v1n = *reinterpret_cast<const bf16x8*>(vt_b + (size_t)ridx_sh[2 * t8 + 3] * 2048);
        }
        f32x16 S = __builtin_amdgcn_mfma_f32_32x32x16_bf16(kf, qf, zf, 0, 0, 0);
        float tm = S[0];
#pragma unroll
        for (int r = 1; r < 16; r++) tm = fmaxf(tm, S[r]);
        tm = fmaxf(tm, __shfl_xor(tm, 32, 64));
        float m_new = fmaxf(m_run, tm);
        float corr = __expf(m_run - m_new);
        float p_[16], psum = 0.f;
#pragma unroll
        for (int r = 0; r < 16; r++) { p_[r] = __expf(S[r] - m_new); psum += p_[r]; }
        psum += __shfl_xor(psum, 32, 64);
        l_run = l_run * corr + psum;
        m_run = m_new;
#pragma unroll
        for (int r = 0; r < 16; r++) opv[r] *= corr;
        unsigned w_[8], pw_[8];
#pragma unroll
        for (int j = 0; j < 8; j++)
            w_[j] = (__float_as_uint(p_[2 * j]) >> 16) |
                    (__float_as_uint(p_[2 * j + 1]) & 0xFFFF0000u);
#pragma unroll
        for (int j = 0; j < 8; j++) pw_[j] = __shfl_xor(w_[j], 32, 64);
        union { unsigned u[4]; bf16x8 v; } fa0, fa1;
        fa0.u[0] = hi ? pw_[2] : w_[0];
        fa0.u[1] = hi ? pw_[3] : w_[1];
        fa0.u[2] = hi ? w_[2]  : pw_[0];
        fa0.u[3] = hi ? w_[3]  : pw_[1];
        fa1.u[0] = hi ? pw_[6] : w_[4];
        fa1.u[1] = hi ? pw_[7] : w_[5];
        fa1.u[2] = hi ? w_[6]  : pw_[4];
        fa1.u[3] = hi ? w_[7]  : pw_[5];
        opv = __builtin_amdgcn_mfma_f32_32x32x16_bf16(fa0.v, v0, opv, 0, 0, 0);
        opv = __builtin_amdgcn_mfma_f32_32x32x16_bf16(fa1.v, v1, opv, 0, 0, 0);
        kf = kfn; v0 = v0n; v1 = v1n;
    }
    denom_sh[wv][l31] = l_run;   // both hi-halves hold identical l_run
    if (l31 < 16) {
#pragma unroll
        for (int r = 0; r < 16; r++) {
            int qr = (r & 3) + 8 * (r >> 2) + 4 * hi;
            float invd = 1.f / denom_sh[wv][qr];
            int qq = qt * 32 + qr;
            int y = wi * 8 + (qq >> 3), x = wj * 8 + (qq & 7);
            o[((size_t)(b * H + y) * W + x) * 128 + h * 16 + l31] = opv[r] * invd;
        }
    }
}

// ------------------------- NHWC v-half -> fp32 NCHW planes [B][C][64][64]
__global__ __launch_bounds__(256) void transpose_v_k(const float* __restrict__ kv,
                                                     float* __restrict__ vpl) {
    int b = blockIdx.y, y = blockIdx.x * 2 + (threadIdx.x >> 7);
    int c = threadIdx.x & 127;
    const float* src = kv + ((size_t)(b * H + y) * W) * 256 + 128 + c;
    float* dst = vpl + ((size_t)(b * C + c) * H + y) * W;
#pragma unroll
    for (int xg = 0; xg < 16; xg++) {
        float4 v;
        v.x = src[(xg * 4 + 0) * 256];
        v.y = src[(xg * 4 + 1) * 256];
        v.z = src[(xg * 4 + 2) * 256];
        v.w = src[(xg * 4 + 3) * 256];
        *reinterpret_cast<float4*>(dst + xg * 4) = v;
    }
}

// ------------------ LePE depthwise 5x5 on planes, LDS-tiled (writes lep planes)
__global__ __launch_bounds__(256) void lepe_plane_k(const float* __restrict__ vpl,
                                                    const float* __restrict__ w,
                                                    const float* __restrict__ bias,
                                                    float* __restrict__ lep) {
    __shared__ float tile[68][69];
    int c = blockIdx.x, b = blockIdx.y;
    int t = threadIdx.x;
    const float* plane = vpl + (size_t)(b * C + c) * 4096;
    for (int e = t; e < 68 * 68; e += 256) {
        int row = e / 68, col = e - row * 68;
        int gy = row - 2, gx = col - 2;
        tile[row][col] = (gy >= 0 && gy < 64 && gx >= 0 && gx < 64)
                         ? plane[gy * 64 + gx] : 0.f;
    }
    float wv[25];
#pragma unroll
    for (int j = 0; j < 25; j++) wv[j] = w[c * 25 + j];
    float bb = bias[c];
    __syncthreads();
    int y = t >> 2, x0 = (t & 3) * 16;
    float acc[16];
#pragma unroll
    for (int i = 0; i < 16; i++) acc[i] = bb;
#pragma unroll
    for (int dy = 0; dy < 5; dy++) {
        float vals[20];
#pragma unroll
        for (int j = 0; j < 20; j++) vals[j] = tile[y + dy][x0 + j];
#pragma unroll
        for (int dx = 0; dx < 5; dx++)
#pragma unroll
            for (int i = 0; i < 16; i++)
                acc[i] += vals[i + dx] * wv[dy * 5 + dx];
    }
    float* dst = lep + (size_t)(b * C + c) * 4096 + y * 64 + x0;
#pragma unroll
    for (int i = 0; i < 16; i += 4)
        *reinterpret_cast<float4*>(dst + i) =
            make_float4(acc[i], acc[i + 1], acc[i + 2], acc[i + 3]);
}

// -------------------- ((o_attn + lepe) @ Wo^T + b) + x, write NCHW output
__global__ __launch_bounds__(128) void epilogue_k(const float* __restrict__ o,
                                                  const float* __restrict__ lep,
                                                  const float* __restrict__ xbuf,
                                                  const float* __restrict__ woT,
                                                  const float* __restrict__ wo_b,
                                                  float* __restrict__ out) {
    __shared__ float ot[16][128];
    __shared__ float res[128][17];
    int b = blockIdx.z, y = blockIdx.y, x0 = blockIdx.x * 16;
    int t = threadIdx.x;
    size_t pixBase = (size_t)(b * H + y) * W + x0;
    const float* lrow = lep + (size_t)(b * C + t) * 4096 + y * 64 + x0;
    for (int p = 0; p < 16; p++)
        ot[p][t] = o[(pixBase + p) * 128 + t] + lrow[p];
    __syncthreads();
    float acc[16];
    float wb = wo_b[t];
#pragma unroll
    for (int p = 0; p < 16; p++) acc[p] = wb + xbuf[(pixBase + p) * 128 + t];
    for (int k = 0; k < 128; k += 4) {
        float w0 = woT[(k + 0) * 128 + t];
        float w1 = woT[(k + 1) * 128 + t];
        float w2 = woT[(k + 2) * 128 + t];
        float w3 = woT[(k + 3) * 128 + t];
#pragma unroll
        for (int p = 0; p < 16; p++) {
            const float4 av = *reinterpret_cast<const float4*>(&ot[p][k]);
            acc[p] += av.x * w0 + av.y * w1 + av.z * w2 + av.w * w3;
        }
    }
#pragma unroll
    for (int p = 0; p < 16; p++) res[t][p] = acc[p];
    __syncthreads();
    int xi = t & 15, cg = t >> 4;
    for (int i = 0; i < 16; i++) {
        int c = cg * 16 + i;
        out[((size_t)(b * C + c) * H + y) * W + x0 + xi] = res[c][xi];
    }
}

extern "C" void kernel_launch(void* const* d_in, const int* in_sizes, int n_in,
                              void* d_out, int out_size, void* d_ws, size_t ws_size,
                              hipStream_t stream) {
    const float* t1      = (const float*)d_in[0];
    const float* t2      = (const float*)d_in[1];
    const float* pos_w   = (const float*)d_in[2];
    const float* pos_b   = (const float*)d_in[3];
    const float* cat_w   = (const float*)d_in[4];
    const float* cat_b   = (const float*)d_in[5];
    const float* ln_cat_g= (const float*)d_in[6];
    const float* ln_cat_b= (const float*)d_in[7];
    const float* ln1_g   = (const float*)d_in[8];
    const float* ln1_b   = (const float*)d_in[9];
    const float* qkv_w   = (const float*)d_in[10];
    const float* qkv_b   = (const float*)d_in[11];
    const float* lepe_w  = (const float*)d_in[12];
    const float* lepe_b  = (const float*)d_in[13];
    const float* wo_w    = (const float*)d_in[14];
    const float* wo_b    = (const float*)d_in[15];

    float* ws    = (float*)d_ws;
    float* t1c   = ws + OFF_T1C;
    float* t2c   = ws + OFF_T2C;
    float* xbuf  = ws + OFF_X;
    ushort_t* qbuf = (ushort_t*)(ws + OFF_QB);
    float* kvbuf = ws + OFF_KV;
    ushort_t* kb   = (ushort_t*)(ws + OFF_KVP);
    ushort_t* kvpT = (ushort_t*)(ws + OFF_KVPT);
    float* m1    = ws + OFF_M1;
    float* m2    = ws + OFF_M2;
    float* qwin  = ws + OFF_QW;
    float* kwin  = ws + OFF_KW;
    int*   ridx  = (int*)(ws + OFF_RIDX);
    ushort_t* wcat2 = (ushort_t*)(ws + OFF_WCB);
    ushort_t* qkvB  = (ushort_t*)(ws + OFF_QKVB);
    float* woT   = ws + OFF_WOT;
    float* obuf  = ws + OFF_O;    // alias of t1c (dead after ln_qkv q / win_mean)
    float* vpl   = ws + OFF_VPL;  // alias of t2c (dead after ln_qkv kv / win_mean)
    float* lep   = ws + OFF_LEP;  // alias of kvbuf (dead after pool_k + transpose_v)
    float* out   = (float*)d_out;

    transpose_weights<<<dim3((36 * 8 * 128 * 8 + 255) / 256), 256, 0, stream>>>(
        qkv_w, wo_w, cat_w, qkvB, woT, wcat2);
    pos_conv_k<<<dim3(2, 4, B * H), 256, 0, stream>>>(t1, pos_w, pos_b, t1c);
    pos_conv_k<<<dim3(2, 4, B * H), 256, 0, stream>>>(t2, pos_w, pos_b, t2c);
    catconv_mfma_k<<<dim3(8, 8, 8), 512, 0, stream>>>(
        t1c, t2c, wcat2, cat_b, ln_cat_g, ln_cat_b, xbuf);
    win_mean_k<<<dim3(64, B), 256, 0, stream>>>(t1c, t2c, ln1_g, ln1_b, m1, m2);
    route_gemm_k<<<dim3(8, B), 256, 0, stream>>>(m1, m2, qkv_w, qkv_b, qwin, kwin);
    route_k<<<dim3(64, B), 64, 0, stream>>>(qwin, kwin, ridx);
    ln_qkv_mfma_k<2, true><<<dim3(512), 256, 0, stream>>>(
        t1c, ln1_g, ln1_b, qkvB, 0, qkv_b, qbuf, nullptr);
    ln_qkv_mfma_k<4, false><<<dim3(512), 256, 0, stream>>>(
        t2c, ln1_g, ln1_b, qkvB, 128, qkv_b, nullptr, kvbuf);
    pool_k<<<dim3(64, B), 256, 0, stream>>>(kvbuf, kb, kvpT);
    transpose_v_k<<<dim3(32, B), 256, 0, stream>>>(kvbuf, vpl);
    attn_mfma_k<<<dim3(64, 4, B), 256, 0, stream>>>(qbuf, kb, kvpT, ridx, obuf);
    lepe_plane_k<<<dim3(C, B), 256, 0, stream>>>(vpl, lepe_w, lepe_b, lep);
    epilogue_k<<<dim3(4, 64, 8), 128, 0, stream>>>(obuf, lep, xbuf, woT, wo_b, out);
}

// Round 7
// 206.039 us; speedup vs baseline: 5.1546x; 1.2111x over previous
//
#include <hip/hip_runtime.h>
#include <math.h>

typedef unsigned short ushort_t;
typedef __attribute__((ext_vector_type(4))) float f32x4;
typedef __attribute__((ext_vector_type(16))) float f32x16;
typedef __attribute__((ext_vector_type(8))) short bf16x8;

constexpr int B = 8, C = 128, H = 64, W = 64;
constexpr int HEADS = 8, TOPK = 16;
constexpr int P2 = 64;
constexpr float SCALE = 0.0883883476483184405f; // 128^-0.5

// workspace offsets (in floats)
constexpr size_t NPIX    = (size_t)B * H * W;            // 32768
constexpr size_t OFF_T1C = 0;                            // NHWC fp32 (B,H,W,128); later: o bf16
constexpr size_t OFF_T2C = OFF_T1C + NPIX * 128;         // NHWC fp32; later: v planes bf16
constexpr size_t OFF_X   = OFF_T2C + NPIX * 128;         // xbuf bf16 [pix][128]
constexpr size_t OFF_QB  = OFF_X   + NPIX * 128;         // q*SCALE bf16
constexpr size_t OFF_KV  = OFF_QB  + NPIX * 64;          // kv bf16 [pix][256]; later: lep planes bf16
constexpr size_t OFF_KVP = OFF_KV  + NPIX * 256;         // K bf16 [B,64,16,128]
constexpr size_t OFF_RW1 = OFF_KVP + 524288;             // rowsums q  [B][8][64][128] fp32
constexpr size_t OFF_RW2 = OFF_RW1 + 524288;             // rowsums kv [B][8][64][128] fp32
constexpr size_t OFF_KVPT= OFF_KVP + (size_t)B * P2 * 16 * 256; // v^T bf16 [B,64,128,16]
constexpr size_t OFF_QW  = OFF_KVPT+ (size_t)B * P2 * 128 * 16 / 2;
constexpr size_t OFF_KW  = OFF_QW  + (size_t)B * P2 * 128;
constexpr size_t OFF_RIDX= OFF_KW  + (size_t)B * P2 * 128;      // int
constexpr size_t OFF_WCB = OFF_RIDX+ (size_t)B * P2 * TOPK;     // wcat2 bf16 [36][2][4][128][8]
constexpr size_t OFF_QKVB= OFF_WCB + (size_t)9 * 256 * 128;     // qkv_w bf16 [384][128]
constexpr size_t OFF_WOB = OFF_QKVB+ (size_t)384 * 128 / 2;     // wo bf16 [128][128]

__device__ inline ushort_t f2bf(float f) {
    unsigned u = __float_as_uint(f);
    unsigned r = u + 0x7FFFu + ((u >> 16) & 1u);
    return (ushort_t)(r >> 16);
}
__device__ inline float bf2f(ushort_t u) {
    return __uint_as_float((unsigned)u << 16);
}

// ---------------------------------------------------------------- weights prep
__global__ void transpose_weights(const float* __restrict__ qkv_w,
                                  const float* __restrict__ wo_w,
                                  const float* __restrict__ cat_w,
                                  ushort_t* __restrict__ qkvB,
                                  ushort_t* __restrict__ woB,
                                  ushort_t* __restrict__ wcat2) {
    int idx = blockIdx.x * 256 + threadIdx.x;
    if (idx < 384 * 128) qkvB[idx] = f2bf(qkv_w[idx]);   // [n][k]
    if (idx < 128 * 128) woB[idx]  = f2bf(wo_w[idx]);    // [n][k]
    if (idx < 36 * 8 * 128 * 8) {    // wcat2[((q*9+dd)*8+kk*4+lg)][n][i]
        int i  = idx & 7;
        int n  = (idx >> 3) & 127;
        int r  = idx >> 10;
        int lg = r & 3;
        int kk = (r >> 2) & 1;
        int sdd = r >> 3;
        int dd = sdd % 9, q = sdd / 9;
        int ci = q * 64 + kk * 32 + lg * 8 + i;
        wcat2[idx] = f2bf(cat_w[((size_t)n * 256 + ci) * 9 + dd]);
    }
}

// --------------------------------------- depthwise 3x3 + residual, NCHW->NHWC
__global__ __launch_bounds__(256) void pos_conv_k(const float* __restrict__ in,
                                                  const float* __restrict__ w,
                                                  const float* __restrict__ bias,
                                                  float* __restrict__ outNHWC) {
    __shared__ float tile[32][33];
    int b = blockIdx.z / H, y = blockIdx.z % H;
    int c0 = blockIdx.y * 32, x0 = blockIdx.x * 32;
    int tx = threadIdx.x & 31, tg = threadIdx.x >> 5;
    for (int i = 0; i < 4; i++) {
        int cl = tg * 4 + i, c = c0 + cl;
        const float* base = in + (size_t)(b * C + c) * H * W;
        float acc = base[y * W + x0 + tx];
        float wv[9];
#pragma unroll
        for (int j = 0; j < 9; j++) wv[j] = w[c * 9 + j];
#pragma unroll
        for (int dy = 0; dy < 3; dy++) {
            int yy = y + dy - 1;
            if (yy < 0 || yy >= H) continue;
#pragma unroll
            for (int dx = 0; dx < 3; dx++) {
                int xx = x0 + tx + dx - 1;
                if (xx < 0 || xx >= W) continue;
                acc += base[yy * W + xx] * wv[dy * 3 + dx];
            }
        }
        tile[cl][tx] = acc + bias[c];
    }
    __syncthreads();
    for (int i = 0; i < 4; i++) {
        int xl = tg * 4 + i;
        outNHWC[((size_t)(b * H + y) * W + x0 + xl) * 128 + c0 + tx] = tile[tx][xl];
    }
}

// ------------- cat-conv 256->128 3x3 implicit-GEMM MFMA + fused LN+ReLU
__global__ __launch_bounds__(512) void catconv_mfma_k(
        const float* __restrict__ t1c, const float* __restrict__ t2c,
        const ushort_t* __restrict__ wcat2,
        const float* __restrict__ cat_b,
        const float* __restrict__ g, const float* __restrict__ beta,
        ushort_t* __restrict__ xbuf) {
    __shared__ __align__(16) unsigned char smem[64 * 132 * 4 + 2 * 64 * 4];
    int t = threadIdx.x;
    int lane = t & 63, wv = t >> 6;
    int mw = wv >> 2, nw = wv & 3;
    int l15 = lane & 15, lg = lane >> 4;
    int b = blockIdx.z, y0 = blockIdx.y * 8, x0 = blockIdx.x * 8;

    f32x4 acc[2][2];
#pragma unroll
    for (int m = 0; m < 2; m++)
#pragma unroll
        for (int cf = 0; cf < 2; cf++)
            acc[m][cf] = (f32x4){0.f, 0.f, 0.f, 0.f};

    int pyA[2], pxA[2];
#pragma unroll
    for (int m = 0; m < 2; m++) {
        int p = mw * 32 + m * 16 + l15;
        pyA[m] = p >> 3; pxA[m] = p & 7;
    }

    for (int q = 0; q < 4; q++) {
        __syncthreads();
        {
            const float* src = (q < 2 ? t1c : t2c) + (q & 1) * 64;
            for (int e = t; e < 1600; e += 512) {
                int pix = e >> 4, c4 = e & 15;
                int hy = pix / 10, hx = pix - hy * 10;
                int gy = y0 - 1 + hy, gx = x0 - 1 + hx;
                float4 v = make_float4(0.f, 0.f, 0.f, 0.f);
                if (gy >= 0 && gy < H && gx >= 0 && gx < W)
                    v = *reinterpret_cast<const float4*>(
                        src + ((size_t)(b * H + gy) * W + gx) * 128 + c4 * 4);
                uint2 pk;
                pk.x = (unsigned)f2bf(v.x) | ((unsigned)f2bf(v.y) << 16);
                pk.y = (unsigned)f2bf(v.z) | ((unsigned)f2bf(v.w) << 16);
                *reinterpret_cast<uint2*>(smem + pix * 144 + c4 * 8) = pk;
            }
        }
        __syncthreads();
#pragma unroll
        for (int dd = 0; dd < 9; dd++) {
            int dy = dd / 3, dx = dd - dy * 3;
            const ushort_t* wb = wcat2 + ((size_t)((q * 9 + dd) * 8 + lg) * 128) * 8;
            bf16x8 bfr[2][2];
#pragma unroll
            for (int kk = 0; kk < 2; kk++)
#pragma unroll
                for (int cf = 0; cf < 2; cf++)
                    bfr[kk][cf] = *reinterpret_cast<const bf16x8*>(
                        wb + (size_t)kk * 4096 + (nw * 32 + cf * 16 + l15) * 8);
            bf16x8 af[2][2];
#pragma unroll
            for (int m = 0; m < 2; m++)
#pragma unroll
                for (int kk = 0; kk < 2; kk++)
                    af[m][kk] = *reinterpret_cast<const bf16x8*>(
                        smem + ((pyA[m] + dy) * 10 + pxA[m] + dx) * 144 + kk * 64 + lg * 16);
#pragma unroll
            for (int m = 0; m < 2; m++)
#pragma unroll
                for (int cf = 0; cf < 2; cf++)
#pragma unroll
                    for (int kk = 0; kk < 2; kk++)
                        acc[m][cf] = __builtin_amdgcn_mfma_f32_16x16x32_bf16(
                            af[m][kk], bfr[kk][cf], acc[m][cf], 0, 0, 0);
        }
    }

    __syncthreads();
    float* res = (float*)smem;
    float* mstat = (float*)(smem + 64 * 132 * 4);
#pragma unroll
    for (int cf = 0; cf < 2; cf++) {
        int n = nw * 32 + cf * 16 + l15;
        float cb = cat_b[n];
#pragma unroll
        for (int m = 0; m < 2; m++)
#pragma unroll
            for (int i = 0; i < 4; i++)
                res[(mw * 32 + m * 16 + lg * 4 + i) * 132 + n] = acc[m][cf][i] + cb;
    }
    __syncthreads();
    {
        int pix = t >> 3, sub = t & 7;
        float s1 = 0.f;
#pragma unroll
        for (int j = 0; j < 16; j++) s1 += res[pix * 132 + sub + j * 8];
        s1 += __shfl_xor(s1, 1, 64);
        s1 += __shfl_xor(s1, 2, 64);
        s1 += __shfl_xor(s1, 4, 64);
        float mean = s1 * (1.f / 128.f);
        float s2 = 0.f;
#pragma unroll
        for (int j = 0; j < 16; j++) {
            float d = res[pix * 132 + sub + j * 8] - mean;
            s2 += d * d;
        }
        s2 += __shfl_xor(s2, 1, 64);
        s2 += __shfl_xor(s2, 2, 64);
        s2 += __shfl_xor(s2, 4, 64);
        float inv = rsqrtf(s2 * (1.f / 128.f) + 1e-5f);
        if (sub == 0) { mstat[pix] = mean; mstat[64 + pix] = inv; }
    }
    __syncthreads();
    {
        int c = t & 127, pg = t >> 7;
        float gg = g[c], bb = beta[c];
        for (int j = 0; j < 16; j++) {
            int p2 = j * 4 + pg;
            float v = (res[p2 * 132 + c] - mstat[p2]) * mstat[64 + p2] * gg + bb;
            int py = p2 >> 3, px = p2 & 7;
            xbuf[((size_t)(b * H + y0 + py) * W + x0 + px) * 128 + c] = f2bf(fmaxf(v, 0.f));
        }
    }
}

// ---- LN(1e-6) + QKV projection, bf16 MFMA; also emits window-row partial sums
template<int NPW, bool QOUT>
__global__ __launch_bounds__(256) void ln_qkv_mfma_k(
        const float* __restrict__ in,
        const float* __restrict__ g, const float* __restrict__ beta,
        const ushort_t* __restrict__ wB,   // bf16 [384][128]
        int nOff,
        const float* __restrict__ bias,
        ushort_t* __restrict__ outQ,
        ushort_t* __restrict__ outKV,
        float* __restrict__ rw) {          // [B][8 wj][64 y][128] row-window sums of LN
    __shared__ __align__(16) unsigned char ash[64 * 272];
    int t = threadIdx.x;
    int lane = t & 63, wv = t >> 6;
    size_t p0 = (size_t)blockIdx.x * 64;
    int bb_ = blockIdx.x >> 6, yy_ = blockIdx.x & 63;
    {
        int row = t >> 2, sub = t & 3;     // row = x coordinate
        const float* src = in + (p0 + row) * 128 + sub * 32;
        float4 v[8];
        float s = 0.f;
#pragma unroll
        for (int j = 0; j < 8; j++) {
            v[j] = *reinterpret_cast<const float4*>(src + j * 4);
            s += v[j].x + v[j].y + v[j].z + v[j].w;
        }
        s += __shfl_xor(s, 1, 64); s += __shfl_xor(s, 2, 64);
        float mean = s * (1.f / 128.f);
        float s2 = 0.f;
#pragma unroll
        for (int j = 0; j < 8; j++) {
            float dx = v[j].x - mean, dy = v[j].y - mean;
            float dz = v[j].z - mean, dw = v[j].w - mean;
            s2 += dx * dx + dy * dy + dz * dz + dw * dw;
        }
        s2 += __shfl_xor(s2, 1, 64); s2 += __shfl_xor(s2, 2, 64);
        float inv = rsqrtf(s2 * (1.f / 128.f) + 1e-6f);
        int wj = wv * 2 + (lane >> 5);
        bool writer = (lane & 28) == 0;
        float* rwp = rw + (((size_t)(bb_ * 8 + wj) * 64 + yy_) * 128) + sub * 32;
#pragma unroll
        for (int j = 0; j < 8; j++) {
            int c = sub * 32 + j * 4;
            float4 gv = *reinterpret_cast<const float4*>(g + c);
            float4 bv = *reinterpret_cast<const float4*>(beta + c);
            float o0 = (v[j].x - mean) * inv * gv.x + bv.x;
            float o1 = (v[j].y - mean) * inv * gv.y + bv.y;
            float o2 = (v[j].z - mean) * inv * gv.z + bv.z;
            float o3 = (v[j].w - mean) * inv * gv.w + bv.w;
            uint2 pk;
            pk.x = (unsigned)f2bf(o0) | ((unsigned)f2bf(o1) << 16);
            pk.y = (unsigned)f2bf(o2) | ((unsigned)f2bf(o3) << 16);
            *reinterpret_cast<uint2*>(ash + row * 272 + c * 2) = pk;
            // window-row partial sums (reduce over 8 x's: lane bits 2..4)
            float r0 = o0, r1 = o1, r2 = o2, r3 = o3;
#pragma unroll
            for (int m = 4; m <= 16; m <<= 1) {
                r0 += __shfl_xor(r0, m, 64);
                r1 += __shfl_xor(r1, m, 64);
                r2 += __shfl_xor(r2, m, 64);
                r3 += __shfl_xor(r3, m, 64);
            }
            if (writer)
                *reinterpret_cast<float4*>(rwp + j * 4) = make_float4(r0, r1, r2, r3);
        }
    }
    __syncthreads();
    int l15 = lane & 15, lg = lane >> 4;
    f32x4 acc[4][NPW];
#pragma unroll
    for (int mt = 0; mt < 4; mt++)
#pragma unroll
        for (int nn = 0; nn < NPW; nn++)
            acc[mt][nn] = (f32x4){0.f, 0.f, 0.f, 0.f};
#pragma unroll
    for (int ks = 0; ks < 4; ks++) {
        bf16x8 af[4];
#pragma unroll
        for (int mt = 0; mt < 4; mt++)
            af[mt] = *reinterpret_cast<const bf16x8*>(
                ash + (mt * 16 + l15) * 272 + ks * 64 + lg * 16);
#pragma unroll
        for (int nn = 0; nn < NPW; nn++) {
            int n = nOff + (wv * NPW + nn) * 16 + l15;
            bf16x8 bfr = *reinterpret_cast<const bf16x8*>(
                wB + (size_t)n * 128 + ks * 32 + lg * 8);
#pragma unroll
            for (int mt = 0; mt < 4; mt++)
                acc[mt][nn] = __builtin_amdgcn_mfma_f32_16x16x32_bf16(
                    af[mt], bfr, acc[mt][nn], 0, 0, 0);
        }
    }
#pragma unroll
    for (int nn = 0; nn < NPW; nn++) {
        int cg = (wv * NPW + nn) * 16 + l15;
        float bv = bias[nOff + cg];
#pragma unroll
        for (int mt = 0; mt < 4; mt++) {
#pragma unroll
            for (int i = 0; i < 4; i++) {
                size_t pix = p0 + mt * 16 + lg * 4 + i;
                float val = acc[mt][nn][i] + bv;
                if (QOUT) outQ[pix * 128 + cg] = f2bf(val * SCALE);
                else      outKV[pix * 256 + cg] = f2bf(val);
            }
        }
    }
}

// -------- fp32 q_win/k_win projection; reduces rowsums (8 rows/window) on load
__global__ __launch_bounds__(256) void route_gemm_k(
        const float* __restrict__ rw1, const float* __restrict__ rw2,
        const float* __restrict__ qkv_w, const float* __restrict__ qkv_b,
        float* __restrict__ qwin, float* __restrict__ kwin) {
    __shared__ float msh[2][8][128];
    int b = blockIdx.y, wi = blockIdx.x;   // windows win = wi*8 + r
    int t = threadIdx.x;
    for (int i = t; i < 8 * 128; i += 256) {
        int r = i >> 7, c = i & 127;
        size_t off = (((size_t)(b * 8 + r) * 64) + wi * 8) * 128 + c;
        float s1 = 0.f, s2 = 0.f;
#pragma unroll
        for (int rr = 0; rr < 8; rr++) {
            s1 += rw1[off + rr * 128];
            s2 += rw2[off + rr * 128];
        }
        msh[0][r][c] = s1 * (1.f / 64.f);
        msh[1][r][c] = s2 * (1.f / 64.f);
    }
    __syncthreads();
    int c = t;
    int which = c >> 7;
    const float* wrow = qkv_w + (size_t)c * 128;
    float acc[8];
#pragma unroll
    for (int r = 0; r < 8; r++) acc[r] = 0.f;
    for (int k = 0; k < 128; k++) {
        float wv_ = wrow[k];
#pragma unroll
        for (int r = 0; r < 8; r++) acc[r] += msh[which][r][k] * wv_;
    }
    float bv = qkv_b[c];
#pragma unroll
    for (int r = 0; r < 8; r++) {
        size_t o = ((size_t)b * 64 + wi * 8 + r) * 128 + (c & 127);
        (which ? kwin : qwin)[o] = acc[r] + bv;
    }
}

// ----------------- window pooling: K bf16 [B,64,16,128] + v^T bf16 [B,64,128,16]
__global__ __launch_bounds__(256) void pool_k(const ushort_t* __restrict__ kv,
                                              ushort_t* __restrict__ kb,
                                              ushort_t* __restrict__ kvpT) {
    int b = blockIdx.y, wdw = blockIdx.x;
    int wi = wdw >> 3, wj = wdw & 7;
    int t = threadIdx.x;
    float vals[16];
    for (int ry = 0; ry < 4; ry++)
        for (int rx = 0; rx < 4; rx++) {
            float s = 0.f;
            for (int fy = 0; fy < 2; fy++)
                for (int fx = 0; fx < 2; fx++) {
                    int y = wi * 8 + ry * 2 + fy, x = wj * 8 + rx * 2 + fx;
                    s += bf2f(kv[((size_t)(b * H + y) * W + x) * 256 + t]);
                }
            vals[ry * 4 + rx] = s * 0.25f;
        }
    if (t < 128) {
#pragma unroll
        for (int pos = 0; pos < 16; pos++)
            kb[(((size_t)(b * 64 + wdw)) * 16 + pos) * 128 + t] = f2bf(vals[pos]);
    } else {
        union { ushort_t u16[16]; uint4 u4[2]; } pk;
#pragma unroll
        for (int i = 0; i < 16; i++) pk.u16[i] = f2bf(vals[i]);
        size_t base = (((size_t)(b * 64 + wdw)) * 128 + (t - 128)) * 16;
        *reinterpret_cast<uint4*>(kvpT + base) = pk.u4[0];
        *reinterpret_cast<uint4*>(kvpT + base + 8) = pk.u4[1];
    }
}

// ------------------------------------------------ routing logits + top-16
__global__ __launch_bounds__(64) void route_k(const float* __restrict__ q_win,
                                              const float* __restrict__ k_win,
                                              int* __restrict__ r_idx) {
    int b = blockIdx.y, p = blockIdx.x, j = threadIdx.x;
    const float* qp = q_win + (size_t)(b * 64 + p) * 128;
    const float* kp = k_win + (size_t)(b * 64 + j) * 128;
    float lg = 0.f;
    for (int c = 0; c < 128; c++) lg += qp[c] * kp[c];
    lg *= SCALE;
    for (int it = 0; it < TOPK; it++) {
        float v = lg; int idx = j;
#pragma unroll
        for (int m = 32; m > 0; m >>= 1) {
            float ov = __shfl_xor(v, m, 64);
            int   oi = __shfl_xor(idx, m, 64);
            if (ov > v || (ov == v && oi < idx)) { v = ov; idx = oi; }
        }
        if (j == 0) r_idx[(size_t)(b * 64 + p) * TOPK + it] = idx;
        if (j == idx) lg = -__builtin_inff();
    }
}

// ---------------- routed attention: staging-free, all frags direct from L2
__global__ __launch_bounds__(256) void attn_mfma_k(
        const ushort_t* __restrict__ qb,     // bf16 q*SCALE [B,H,W,128]
        const ushort_t* __restrict__ kb,     // bf16 [B,64,16,128]
        const ushort_t* __restrict__ kvpT,   // bf16 [B,64,128,16]
        const int* __restrict__ r_idx,
        ushort_t* __restrict__ o) {          // bf16 [pix][128]
    __shared__ int ridx_sh[16];
    __shared__ float denom_sh[4][32];

    int b = blockIdx.z, p = blockIdx.x, pair = blockIdx.y;
    int wi = p >> 3, wj = p & 7;
    int t = threadIdx.x;
    int lane = t & 63, wv = t >> 6;
    int l31 = lane & 31, hi = lane >> 5;

    if (t < 16) ridx_sh[t] = r_idx[(size_t)(b * 64 + p) * TOPK + t];
    __syncthreads();

    int hh = wv >> 1, qt = wv & 1;
    int h = pair * 2 + hh;

    int q = qt * 32 + l31;
    int qy = wi * 8 + (q >> 3), qx = wj * 8 + (q & 7);
    bf16x8 qf = *reinterpret_cast<const bf16x8*>(
        qb + ((size_t)(b * H + qy) * W + qx) * 128 + h * 16 + hi * 8);

    const ushort_t* kb_b = kb + (size_t)b * 64 * 16 * 128 + h * 16 + hi * 8;
    const ushort_t* vt_b = kvpT + (size_t)b * 64 * 128 * 16 + (h * 16 + (l31 & 15)) * 16 + hi * 8;

    float m_run = -INFINITY, l_run = 0.f;
    f32x16 opv;
#pragma unroll
    for (int r = 0; r < 16; r++) opv[r] = 0.f;
    f32x16 zf;
#pragma unroll
    for (int r = 0; r < 16; r++) zf[r] = 0.f;

    bf16x8 kf = *reinterpret_cast<const bf16x8*>(
        kb_b + ((size_t)ridx_sh[l31 >> 4] * 16 + (l31 & 15)) * 128);
    bf16x8 v0 = *reinterpret_cast<const bf16x8*>(vt_b + (size_t)ridx_sh[0] * 2048);
    bf16x8 v1 = *reinterpret_cast<const bf16x8*>(vt_b + (size_t)ridx_sh[1] * 2048);

    for (int t8 = 0; t8 < 8; t8++) {
        bf16x8 kfn = kf, v0n = v0, v1n = v1;
        if (t8 < 7) {
            kfn = *reinterpret_cast<const bf16x8*>(
                kb_b + ((size_t)ridx_sh[2 * t8 + 2 + (l31 >> 4)] * 16 + (l31 & 15)) * 128);
            v0n = *reinterpret_cast<const bf16x8*>(vt_b + (size_t)ridx_sh[2 * t8 + 2] * 2048);
            v1n = *reinterpret_cast<const bf16x8*>(vt_b + (size_t)ridx_sh[2 * t8 + 3] * 2048);
        }
        f32x16 S = __builtin_amdgcn_mfma_f32_32x32x16_bf16(kf, qf, zf, 0, 0, 0);
        float tm = S[0];
#pragma unroll
        for (int r = 1; r < 16; r++) tm = fmaxf(tm, S[r]);
        tm = fmaxf(tm, __shfl_xor(tm, 32, 64));
        float m_new = fmaxf(m_run, tm);
        float corr = __expf(m_run - m_new);
        float p_[16], psum = 0.f;
#pragma unroll
        for (int r = 0; r < 16; r++) { p_[r] = __expf(S[r] - m_new); psum += p_[r]; }
        psum += __shfl_xor(psum, 32, 64);
        l_run = l_run * corr + psum;
        m_run = m_new;
#pragma unroll
        for (int r = 0; r < 16; r++) opv[r] *= corr;
        unsigned w_[8], pw_[8];
#pragma unroll
        for (int j = 0; j < 8; j++)
            w_[j] = (__float_as_uint(p_[2 * j]) >> 16) |
                    (__float_as_uint(p_[2 * j + 1]) & 0xFFFF0000u);
#pragma unroll
        for (int j = 0; j < 8; j++) pw_[j] = __shfl_xor(w_[j], 32, 64);
        union { unsigned u[4]; bf16x8 v; } fa0, fa1;
        fa0.u[0] = hi ? pw_[2] : w_[0];
        fa0.u[1] = hi ? pw_[3] : w_[1];
        fa0.u[2] = hi ? w_[2]  : pw_[0];
        fa0.u[3] = hi ? w_[3]  : pw_[1];
        fa1.u[0] = hi ? pw_[6] : w_[4];
        fa1.u[1] = hi ? pw_[7] : w_[5];
        fa1.u[2] = hi ? w_[6]  : pw_[4];
        fa1.u[3] = hi ? w_[7]  : pw_[5];
        opv = __builtin_amdgcn_mfma_f32_32x32x16_bf16(fa0.v, v0, opv, 0, 0, 0);
        opv = __builtin_amdgcn_mfma_f32_32x32x16_bf16(fa1.v, v1, opv, 0, 0, 0);
        kf = kfn; v0 = v0n; v1 = v1n;
    }
    denom_sh[wv][l31] = l_run;
    if (l31 < 16) {
#pragma unroll
        for (int r = 0; r < 16; r++) {
            int qr = (r & 3) + 8 * (r >> 2) + 4 * hi;
            float invd = 1.f / denom_sh[wv][qr];
            int qq = qt * 32 + qr;
            int y = wi * 8 + (qq >> 3), x = wj * 8 + (qq & 7);
            o[((size_t)(b * H + y) * W + x) * 128 + h * 16 + l31] = f2bf(opv[r] * invd);
        }
    }
}

// ------------------------- NHWC v-half bf16 -> bf16 planes [B][C][64][64]
__global__ __launch_bounds__(256) void transpose_v_k(const ushort_t* __restrict__ kv,
                                                     ushort_t* __restrict__ vpl) {
    int b = blockIdx.y, y = blockIdx.x * 2 + (threadIdx.x >> 7);
    int c = threadIdx.x & 127;
    const ushort_t* src = kv + ((size_t)(b * H + y) * W) * 256 + 128 + c;
    ushort_t* dst = vpl + ((size_t)(b * C + c) * H + y) * W;
#pragma unroll
    for (int xg = 0; xg < 8; xg++) {
        union { ushort_t u16[8]; uint4 u4; } pk;
#pragma unroll
        for (int j = 0; j < 8; j++) pk.u16[j] = src[(xg * 8 + j) * 256];
        *reinterpret_cast<uint4*>(dst + xg * 8) = pk.u4;
    }
}

// ------------------ LePE depthwise 5x5 on bf16 planes, LDS-tiled, bf16 out
__global__ __launch_bounds__(256) void lepe_plane_k(const ushort_t* __restrict__ vpl,
                                                    const float* __restrict__ w,
                                                    const float* __restrict__ bias,
                                                    ushort_t* __restrict__ lep) {
    __shared__ float tile[68][69];
    int c = blockIdx.x, b = blockIdx.y;
    int t = threadIdx.x;
    const ushort_t* plane = vpl + (size_t)(b * C + c) * 4096;
    for (int e = t; e < 68 * 68; e += 256) {
        int row = e / 68, col = e - row * 68;
        int gy = row - 2, gx = col - 2;
        tile[row][col] = (gy >= 0 && gy < 64 && gx >= 0 && gx < 64)
                         ? bf2f(plane[gy * 64 + gx]) : 0.f;
    }
    float wv[25];
#pragma unroll
    for (int j = 0; j < 25; j++) wv[j] = w[c * 25 + j];
    float bb = bias[c];
    __syncthreads();
    int y = t >> 2, x0 = (t & 3) * 16;
    float acc[16];
#pragma unroll
    for (int i = 0; i < 16; i++) acc[i] = bb;
#pragma unroll
    for (int dy = 0; dy < 5; dy++) {
        float vals[20];
#pragma unroll
        for (int j = 0; j < 20; j++) vals[j] = tile[y + dy][x0 + j];
#pragma unroll
        for (int dx = 0; dx < 5; dx++)
#pragma unroll
            for (int i = 0; i < 16; i++)
                acc[i] += vals[i + dx] * wv[dy * 5 + dx];
    }
    ushort_t* dst = lep + (size_t)(b * C + c) * 4096 + y * 64 + x0;
    union { ushort_t u16[16]; uint4 u4[2]; } pk;
#pragma unroll
    for (int i = 0; i < 16; i++) pk.u16[i] = f2bf(acc[i]);
    *reinterpret_cast<uint4*>(dst) = pk.u4[0];
    *reinterpret_cast<uint4*>(dst + 8) = pk.u4[1];
}

// ---- epilogue: ((o + lepe) @ Wo^T + b) + x, bf16 MFMA, NCHW store via LDS
__global__ __launch_bounds__(256) void epilogue_mfma_k(
        const ushort_t* __restrict__ o,      // bf16 [pix][128]
        const ushort_t* __restrict__ lep,    // bf16 planes [B][C][64][64]
        const ushort_t* __restrict__ xbuf,   // bf16 [pix][128]
        const ushort_t* __restrict__ woB,    // bf16 [128][128]
        const float* __restrict__ wo_b,
        float* __restrict__ out) {
    __shared__ __align__(16) unsigned char smem[128 * 68 * 4]; // 34816 B
    ushort_t* ash = (ushort_t*)smem;         // [64][136] bf16 (o+lep)
    float* res = (float*)smem;               // [128][68] fp32 (after MFMA)
    int t = threadIdx.x, lane = t & 63, wv = t >> 6;
    int bid = blockIdx.x;
    int b = bid >> 6, y = bid & 63;
    size_t p0 = (size_t)bid * 64;

    // phase A: lep plane-rows -> ash transposed
#pragma unroll
    for (int k = 0; k < 4; k++) {
        int e = k * 256 + t;                 // 1024 uint4 chunks
        int c = e >> 3, xg = e & 7;
        union { uint4 u4; ushort_t u16[8]; } v;
        v.u4 = *reinterpret_cast<const uint4*>(
            lep + (((size_t)(b * C + c) * 64 + y) * 64) + xg * 8);
#pragma unroll
        for (int j = 0; j < 8; j++) ash[(xg * 8 + j) * 136 + c] = v.u16[j];
    }
    __syncthreads();
    // phase B: add o (bf16) in fp32, write back bf16
    {
        int x = t >> 2, sub = t & 3;
        const ushort_t* op = o + (p0 + x) * 128 + sub * 32;
        ushort_t* ap = ash + x * 136 + sub * 32;
#pragma unroll
        for (int jj = 0; jj < 4; jj++) {
            union { uint4 u4; ushort_t u16[8]; } ov, lv;
            ov.u4 = *reinterpret_cast<const uint4*>(op + jj * 8);
            lv.u4 = *reinterpret_cast<const uint4*>(ap + jj * 8);
#pragma unroll
            for (int j = 0; j < 8; j++)
                lv.u16[j] = f2bf(bf2f(ov.u16[j]) + bf2f(lv.u16[j]));
            *reinterpret_cast<uint4*>(ap + jj * 8) = lv.u4;
        }
    }
    __syncthreads();
    // MFMA: M=64 pixels x N=128 x K=128
    int l15 = lane & 15, lg = lane >> 4;
    f32x4 acc[4][2];
#pragma unroll
    for (int mt = 0; mt < 4; mt++)
#pragma unroll
        for (int nn = 0; nn < 2; nn++)
            acc[mt][nn] = (f32x4){0.f, 0.f, 0.f, 0.f};
#pragma unroll
    for (int ks = 0; ks < 4; ks++) {
        bf16x8 af[4];
#pragma unroll
        for (int mt = 0; mt < 4; mt++)
            af[mt] = *reinterpret_cast<const bf16x8*>(
                ash + (mt * 16 + l15) * 136 + ks * 32 + lg * 8);
#pragma unroll
        for (int nn = 0; nn < 2; nn++) {
            int n = (wv * 2 + nn) * 16 + l15;
            bf16x8 bfr = *reinterpret_cast<const bf16x8*>(
                woB + (size_t)n * 128 + ks * 32 + lg * 8);
#pragma unroll
            for (int mt = 0; mt < 4; mt++)
                acc[mt][nn] = __builtin_amdgcn_mfma_f32_16x16x32_bf16(
                    af[mt], bfr, acc[mt][nn], 0, 0, 0);
        }
    }
    __syncthreads();   // ash dead; res takes over LDS
#pragma unroll
    for (int nn = 0; nn < 2; nn++) {
        int n = (wv * 2 + nn) * 16 + l15;
        float wb = wo_b[n];
#pragma unroll
        for (int mt = 0; mt < 4; mt++)
#pragma unroll
            for (int i = 0; i < 4; i++) {
                int r = mt * 16 + lg * 4 + i;
                float xb = bf2f(xbuf[(p0 + r) * 128 + n]);
                res[n * 68 + r] = acc[mt][nn][i] + wb + xb;
            }
    }
    __syncthreads();
    {
        int c = t >> 1, x0 = (t & 1) * 32;
        float* dst = out + ((size_t)(b * C + c) * 64 + y) * 64 + x0;
#pragma unroll
        for (int gblk = 0; gblk < 8; gblk++)
            *reinterpret_cast<float4*>(dst + gblk * 4) =
                *reinterpret_cast<const float4*>(&res[c * 68 + x0 + gblk * 4]);
    }
}

extern "C" void kernel_launch(void* const* d_in, const int* in_sizes, int n_in,
                              void* d_out, int out_size, void* d_ws, size_t ws_size,
                              hipStream_t stream) {
    const float* t1      = (const float*)d_in[0];
    const float* t2      = (const float*)d_in[1];
    const float* pos_w   = (const float*)d_in[2];
    const float* pos_b   = (const float*)d_in[3];
    const float* cat_w   = (const float*)d_in[4];
    const float* cat_b   = (const float*)d_in[5];
    const float* ln_cat_g= (const float*)d_in[6];
    const float* ln_cat_b= (const float*)d_in[7];
    const float* ln1_g   = (const float*)d_in[8];
    const float* ln1_b   = (const float*)d_in[9];
    const float* qkv_w   = (const float*)d_in[10];
    const float* qkv_b   = (const float*)d_in[11];
    const float* lepe_w  = (const float*)d_in[12];
    const float* lepe_b  = (const float*)d_in[13];
    const float* wo_w    = (const float*)d_in[14];
    const float* wo_b    = (const float*)d_in[15];

    float* ws    = (float*)d_ws;
    float* t1c   = ws + OFF_T1C;
    float* t2c   = ws + OFF_T2C;
    ushort_t* xbuf = (ushort_t*)(ws + OFF_X);
    ushort_t* qbuf = (ushort_t*)(ws + OFF_QB);
    ushort_t* kvbuf= (ushort_t*)(ws + OFF_KV);
    ushort_t* kb   = (ushort_t*)(ws + OFF_KVP);
    float* rw1   = ws + OFF_RW1;
    float* rw2   = ws + OFF_RW2;
    ushort_t* kvpT = (ushort_t*)(ws + OFF_KVPT);
    float* qwin  = ws + OFF_QW;
    float* kwin  = ws + OFF_KW;
    int*   ridx  = (int*)(ws + OFF_RIDX);
    ushort_t* wcat2 = (ushort_t*)(ws + OFF_WCB);
    ushort_t* qkvB  = (ushort_t*)(ws + OFF_QKVB);
    ushort_t* woB   = (ushort_t*)(ws + OFF_WOB);
    ushort_t* obuf  = (ushort_t*)(ws + OFF_T1C);  // alias t1c (dead after ln_qkv q)
    ushort_t* vpl   = (ushort_t*)(ws + OFF_T2C);  // alias t2c (dead after ln_qkv kv)
    ushort_t* lep   = (ushort_t*)(ws + OFF_KV);   // alias kvbuf (dead after pool+transpose)
    float* out   = (float*)d_out;

    transpose_weights<<<dim3((36 * 8 * 128 * 8 + 255) / 256), 256, 0, stream>>>(
        qkv_w, wo_w, cat_w, qkvB, woB, wcat2);
    pos_conv_k<<<dim3(2, 4, B * H), 256, 0, stream>>>(t1, pos_w, pos_b, t1c);
    pos_conv_k<<<dim3(2, 4, B * H), 256, 0, stream>>>(t2, pos_w, pos_b, t2c);
    catconv_mfma_k<<<dim3(8, 8, 8), 512, 0, stream>>>(
        t1c, t2c, wcat2, cat_b, ln_cat_g, ln_cat_b, xbuf);
    ln_qkv_mfma_k<2, true><<<dim3(512), 256, 0, stream>>>(
        t1c, ln1_g, ln1_b, qkvB, 0, qkv_b, qbuf, nullptr, rw1);
    ln_qkv_mfma_k<4, false><<<dim3(512), 256, 0, stream>>>(
        t2c, ln1_g, ln1_b, qkvB, 128, qkv_b, nullptr, kvbuf, rw2);
    route_gemm_k<<<dim3(8, B), 256, 0, stream>>>(rw1, rw2, qkv_w, qkv_b, qwin, kwin);
    route_k<<<dim3(64, B), 64, 0, stream>>>(qwin, kwin, ridx);
    pool_k<<<dim3(64, B), 256, 0, stream>>>(kvbuf, kb, kvpT);
    transpose_v_k<<<dim3(32, B), 256, 0, stream>>>(kvbuf, vpl);
    attn_mfma_k<<<dim3(64, 4, B), 256, 0, stream>>>(qbuf, kb, kvpT, ridx, obuf);
    lepe_plane_k<<<dim3(C, B), 256, 0, stream>>>(vpl, lepe_w, lepe_b, lep);
    epilogue_mfma_k<<<dim3(512), 256, 0, stream>>>(obuf, lep, xbuf, woB, wo_b, out);
}

// Round 8
// 167.113 us; speedup vs baseline: 6.3552x; 1.2329x over previous
//
#include <hip/hip_runtime.h>
#include <math.h>

typedef unsigned short ushort_t;
typedef __attribute__((ext_vector_type(4))) float f32x4;
typedef __attribute__((ext_vector_type(16))) float f32x16;
typedef __attribute__((ext_vector_type(8))) short bf16x8;

constexpr int B = 8, C = 128, H = 64, W = 64;
constexpr int HEADS = 8, TOPK = 16;
constexpr int P2 = 64;
constexpr float SCALE = 0.0883883476483184405f; // 128^-0.5

// workspace offsets (in floats)
constexpr size_t NPIX    = (size_t)B * H * W;            // 32768
constexpr size_t OFF_T1C = 0;                            // NHWC fp32; later: o bf16
constexpr size_t OFF_T2C = OFF_T1C + NPIX * 128;         // NHWC fp32; later: v planes bf16
constexpr size_t OFF_X   = OFF_T2C + NPIX * 128;         // xbuf bf16 [pix][128]
constexpr size_t OFF_QB  = OFF_X   + NPIX * 128;         // q*SCALE bf16
constexpr size_t OFF_KV  = OFF_QB  + NPIX * 64;          // kv bf16 [pix][256]; later: lep planes bf16
constexpr size_t OFF_KVP = OFF_KV  + NPIX * 256;         // K bf16 [B,64,16,128]
constexpr size_t OFF_RW1 = OFF_KVP + 524288;             // rowsums q  [B][8][64][128] fp32
constexpr size_t OFF_RW2 = OFF_RW1 + 524288;             // rowsums kv [B][8][64][128] fp32
constexpr size_t OFF_KVPT= OFF_KVP + (size_t)B * P2 * 16 * 256; // v^T bf16 [B,64,128,16]
constexpr size_t OFF_QW  = OFF_KVPT+ (size_t)B * P2 * 128 * 16 / 2;
constexpr size_t OFF_KW  = OFF_QW  + (size_t)B * P2 * 128;
constexpr size_t OFF_RIDX= OFF_KW  + (size_t)B * P2 * 128;      // int
constexpr size_t OFF_WCB = OFF_RIDX+ (size_t)B * P2 * TOPK;     // wcat2 bf16 [36][2][4][128][8]
constexpr size_t OFF_QKVB= OFF_WCB + (size_t)9 * 256 * 128;     // qkv_w bf16 [384][128]
constexpr size_t OFF_WOB = OFF_QKVB+ (size_t)384 * 128 / 2;     // wo bf16 [128][128]

__device__ inline ushort_t f2bf(float f) {
    unsigned u = __float_as_uint(f);
    unsigned r = u + 0x7FFFu + ((u >> 16) & 1u);
    return (ushort_t)(r >> 16);
}
__device__ inline float bf2f(ushort_t u) {
    return __uint_as_float((unsigned)u << 16);
}

// ---------------------------------------------------------------- weights prep
__global__ void transpose_weights(const float* __restrict__ qkv_w,
                                  const float* __restrict__ wo_w,
                                  const float* __restrict__ cat_w,
                                  ushort_t* __restrict__ qkvB,
                                  ushort_t* __restrict__ woB,
                                  ushort_t* __restrict__ wcat2) {
    int idx = blockIdx.x * 256 + threadIdx.x;
    if (idx < 384 * 128) qkvB[idx] = f2bf(qkv_w[idx]);   // [n][k]
    if (idx < 128 * 128) woB[idx]  = f2bf(wo_w[idx]);    // [n][k]
    if (idx < 36 * 8 * 128 * 8) {    // wcat2[((q*9+dd)*8+kk*4+lg)][n][i]
        int i  = idx & 7;
        int n  = (idx >> 3) & 127;
        int r  = idx >> 10;
        int lg = r & 3;
        int kk = (r >> 2) & 1;
        int sdd = r >> 3;
        int dd = sdd % 9, q = sdd / 9;
        int ci = q * 64 + kk * 32 + lg * 8 + i;
        wcat2[idx] = f2bf(cat_w[((size_t)n * 256 + ci) * 9 + dd]);
    }
}

// -------- depthwise 3x3 + residual, NCHW->NHWC; both tensors, 4 rows/block
__global__ __launch_bounds__(256) void pos_conv_k(
        const float* __restrict__ t1, const float* __restrict__ t2,
        const float* __restrict__ w, const float* __restrict__ bias,
        float* __restrict__ out1, float* __restrict__ out2) {
    __shared__ float tile[4][32][33];
    int z = blockIdx.z;
    int which = z >> 7, rem = z & 127;
    int b = rem >> 4, y0 = (rem & 15) * 4;
    const float* in = which ? t2 : t1;
    float* outNHWC = which ? out2 : out1;
    int c0 = blockIdx.y * 32, x0 = blockIdx.x * 32;
    int tx = threadIdx.x & 31, tg = threadIdx.x >> 5;
    int x = x0 + tx;
    for (int i = 0; i < 4; i++) {
        int cl = tg * 4 + i, c = c0 + cl;
        const float* base = in + (size_t)(b * C + c) * H * W;
        float wv[9];
#pragma unroll
        for (int j = 0; j < 9; j++) wv[j] = w[c * 9 + j];
        float rows[6][3];
#pragma unroll
        for (int yy = 0; yy < 6; yy++) {
            int gy = y0 - 1 + yy;
            bool yok = (gy >= 0 && gy < H);
#pragma unroll
            for (int dx = 0; dx < 3; dx++) {
                int gx = x + dx - 1;
                rows[yy][dx] = (yok && gx >= 0 && gx < W) ? base[gy * W + gx] : 0.f;
            }
        }
        float bb = bias[c];
#pragma unroll
        for (int k = 0; k < 4; k++) {
            float acc = rows[k + 1][1] + bb;   // residual (center) + bias
#pragma unroll
            for (int dy = 0; dy < 3; dy++)
#pragma unroll
                for (int dx = 0; dx < 3; dx++)
                    acc += rows[k + dy][dx] * wv[dy * 3 + dx];
            tile[k][cl][tx] = acc;
        }
    }
    __syncthreads();
    for (int k = 0; k < 4; k++)
        for (int i = 0; i < 4; i++) {
            int xl = tg * 4 + i;
            outNHWC[((size_t)(b * H + y0 + k) * W + x0 + xl) * 128 + c0 + tx] =
                tile[k][tx][xl];
        }
}

// ------------- cat-conv 256->128 3x3 implicit-GEMM MFMA + fused LN+ReLU
__global__ __launch_bounds__(512) void catconv_mfma_k(
        const float* __restrict__ t1c, const float* __restrict__ t2c,
        const ushort_t* __restrict__ wcat2,
        const float* __restrict__ cat_b,
        const float* __restrict__ g, const float* __restrict__ beta,
        ushort_t* __restrict__ xbuf) {
    __shared__ __align__(16) unsigned char smem[64 * 132 * 4 + 2 * 64 * 4];
    int t = threadIdx.x;
    int lane = t & 63, wv = t >> 6;
    int mw = wv >> 2, nw = wv & 3;
    int l15 = lane & 15, lg = lane >> 4;
    int b = blockIdx.z, y0 = blockIdx.y * 8, x0 = blockIdx.x * 8;

    f32x4 acc[2][2];
#pragma unroll
    for (int m = 0; m < 2; m++)
#pragma unroll
        for (int cf = 0; cf < 2; cf++)
            acc[m][cf] = (f32x4){0.f, 0.f, 0.f, 0.f};

    int pyA[2], pxA[2];
#pragma unroll
    for (int m = 0; m < 2; m++) {
        int p = mw * 32 + m * 16 + l15;
        pyA[m] = p >> 3; pxA[m] = p & 7;
    }

    for (int q = 0; q < 4; q++) {
        __syncthreads();
        {
            const float* src = (q < 2 ? t1c : t2c) + (q & 1) * 64;
            for (int e = t; e < 1600; e += 512) {
                int pix = e >> 4, c4 = e & 15;
                int hy = pix / 10, hx = pix - hy * 10;
                int gy = y0 - 1 + hy, gx = x0 - 1 + hx;
                float4 v = make_float4(0.f, 0.f, 0.f, 0.f);
                if (gy >= 0 && gy < H && gx >= 0 && gx < W)
                    v = *reinterpret_cast<const float4*>(
                        src + ((size_t)(b * H + gy) * W + gx) * 128 + c4 * 4);
                uint2 pk;
                pk.x = (unsigned)f2bf(v.x) | ((unsigned)f2bf(v.y) << 16);
                pk.y = (unsigned)f2bf(v.z) | ((unsigned)f2bf(v.w) << 16);
                *reinterpret_cast<uint2*>(smem + pix * 144 + c4 * 8) = pk;
            }
        }
        __syncthreads();
#pragma unroll
        for (int dd = 0; dd < 9; dd++) {
            int dy = dd / 3, dx = dd - dy * 3;
            const ushort_t* wb = wcat2 + ((size_t)((q * 9 + dd) * 8 + lg) * 128) * 8;
            bf16x8 bfr[2][2];
#pragma unroll
            for (int kk = 0; kk < 2; kk++)
#pragma unroll
                for (int cf = 0; cf < 2; cf++)
                    bfr[kk][cf] = *reinterpret_cast<const bf16x8*>(
                        wb + (size_t)kk * 4096 + (nw * 32 + cf * 16 + l15) * 8);
            bf16x8 af[2][2];
#pragma unroll
            for (int m = 0; m < 2; m++)
#pragma unroll
                for (int kk = 0; kk < 2; kk++)
                    af[m][kk] = *reinterpret_cast<const bf16x8*>(
                        smem + ((pyA[m] + dy) * 10 + pxA[m] + dx) * 144 + kk * 64 + lg * 16);
#pragma unroll
            for (int m = 0; m < 2; m++)
#pragma unroll
                for (int cf = 0; cf < 2; cf++)
#pragma unroll
                    for (int kk = 0; kk < 2; kk++)
                        acc[m][cf] = __builtin_amdgcn_mfma_f32_16x16x32_bf16(
                            af[m][kk], bfr[kk][cf], acc[m][cf], 0, 0, 0);
        }
    }

    __syncthreads();
    float* res = (float*)smem;
    float* mstat = (float*)(smem + 64 * 132 * 4);
#pragma unroll
    for (int cf = 0; cf < 2; cf++) {
        int n = nw * 32 + cf * 16 + l15;
        float cb = cat_b[n];
#pragma unroll
        for (int m = 0; m < 2; m++)
#pragma unroll
            for (int i = 0; i < 4; i++)
                res[(mw * 32 + m * 16 + lg * 4 + i) * 132 + n] = acc[m][cf][i] + cb;
    }
    __syncthreads();
    {
        int pix = t >> 3, sub = t & 7;
        float s1 = 0.f;
#pragma unroll
        for (int j = 0; j < 16; j++) s1 += res[pix * 132 + sub + j * 8];
        s1 += __shfl_xor(s1, 1, 64);
        s1 += __shfl_xor(s1, 2, 64);
        s1 += __shfl_xor(s1, 4, 64);
        float mean = s1 * (1.f / 128.f);
        float s2 = 0.f;
#pragma unroll
        for (int j = 0; j < 16; j++) {
            float d = res[pix * 132 + sub + j * 8] - mean;
            s2 += d * d;
        }
        s2 += __shfl_xor(s2, 1, 64);
        s2 += __shfl_xor(s2, 2, 64);
        s2 += __shfl_xor(s2, 4, 64);
        float inv = rsqrtf(s2 * (1.f / 128.f) + 1e-5f);
        if (sub == 0) { mstat[pix] = mean; mstat[64 + pix] = inv; }
    }
    __syncthreads();
    {
        int c = t & 127, pg = t >> 7;
        float gg = g[c], bb = beta[c];
        for (int j = 0; j < 16; j++) {
            int p2 = j * 4 + pg;
            float v = (res[p2 * 132 + c] - mstat[p2]) * mstat[64 + p2] * gg + bb;
            int py = p2 >> 3, px = p2 & 7;
            xbuf[((size_t)(b * H + y0 + py) * W + x0 + px) * 128 + c] = f2bf(fmaxf(v, 0.f));
        }
    }
}

// ---- LN(1e-6) + QKV projection (both streams in one kernel) + window rowsums
__global__ __launch_bounds__(256) void ln_qkv_both_k(
        const float* __restrict__ t1c, const float* __restrict__ t2c,
        const float* __restrict__ g, const float* __restrict__ beta,
        const ushort_t* __restrict__ wB,   // bf16 [384][128]
        const float* __restrict__ bias,
        ushort_t* __restrict__ outQ,
        ushort_t* __restrict__ outKV,
        float* __restrict__ rw1, float* __restrict__ rw2) {
    __shared__ __align__(16) unsigned char ash[64 * 272];
    int t = threadIdx.x;
    int lane = t & 63, wv = t >> 6;
    int which = blockIdx.y;
    const float* in = which ? t2c : t1c;
    float* rw = which ? rw2 : rw1;
    size_t p0 = (size_t)blockIdx.x * 64;
    int bb_ = blockIdx.x >> 6, yy_ = blockIdx.x & 63;
    {
        int row = t >> 2, sub = t & 3;     // row = x coordinate
        const float* src = in + (p0 + row) * 128 + sub * 32;
        float4 v[8];
        float s = 0.f;
#pragma unroll
        for (int j = 0; j < 8; j++) {
            v[j] = *reinterpret_cast<const float4*>(src + j * 4);
            s += v[j].x + v[j].y + v[j].z + v[j].w;
        }
        s += __shfl_xor(s, 1, 64); s += __shfl_xor(s, 2, 64);
        float mean = s * (1.f / 128.f);
        float s2 = 0.f;
#pragma unroll
        for (int j = 0; j < 8; j++) {
            float dx = v[j].x - mean, dy = v[j].y - mean;
            float dz = v[j].z - mean, dw = v[j].w - mean;
            s2 += dx * dx + dy * dy + dz * dz + dw * dw;
        }
        s2 += __shfl_xor(s2, 1, 64); s2 += __shfl_xor(s2, 2, 64);
        float inv = rsqrtf(s2 * (1.f / 128.f) + 1e-6f);
        int wj = wv * 2 + (lane >> 5);
        bool writer = (lane & 28) == 0;
        float* rwp = rw + (((size_t)(bb_ * 8 + wj) * 64 + yy_) * 128) + sub * 32;
#pragma unroll
        for (int j = 0; j < 8; j++) {
            int c = sub * 32 + j * 4;
            float4 gv = *reinterpret_cast<const float4*>(g + c);
            float4 bv = *reinterpret_cast<const float4*>(beta + c);
            float o0 = (v[j].x - mean) * inv * gv.x + bv.x;
            float o1 = (v[j].y - mean) * inv * gv.y + bv.y;
            float o2 = (v[j].z - mean) * inv * gv.z + bv.z;
            float o3 = (v[j].w - mean) * inv * gv.w + bv.w;
            uint2 pk;
            pk.x = (unsigned)f2bf(o0) | ((unsigned)f2bf(o1) << 16);
            pk.y = (unsigned)f2bf(o2) | ((unsigned)f2bf(o3) << 16);
            *reinterpret_cast<uint2*>(ash + row * 272 + c * 2) = pk;
            float r0 = o0, r1 = o1, r2 = o2, r3 = o3;
#pragma unroll
            for (int m = 4; m <= 16; m <<= 1) {
                r0 += __shfl_xor(r0, m, 64);
                r1 += __shfl_xor(r1, m, 64);
                r2 += __shfl_xor(r2, m, 64);
                r3 += __shfl_xor(r3, m, 64);
            }
            if (writer)
                *reinterpret_cast<float4*>(rwp + j * 4) = make_float4(r0, r1, r2, r3);
        }
    }
    __syncthreads();
    int l15 = lane & 15, lg = lane >> 4;
    if (which == 0) {
        // q path: N=128, NPW=2
        f32x4 acc[4][2];
#pragma unroll
        for (int mt = 0; mt < 4; mt++)
#pragma unroll
            for (int nn = 0; nn < 2; nn++)
                acc[mt][nn] = (f32x4){0.f, 0.f, 0.f, 0.f};
#pragma unroll
        for (int ks = 0; ks < 4; ks++) {
            bf16x8 af[4];
#pragma unroll
            for (int mt = 0; mt < 4; mt++)
                af[mt] = *reinterpret_cast<const bf16x8*>(
                    ash + (mt * 16 + l15) * 272 + ks * 64 + lg * 16);
#pragma unroll
            for (int nn = 0; nn < 2; nn++) {
                int n = (wv * 2 + nn) * 16 + l15;
                bf16x8 bfr = *reinterpret_cast<const bf16x8*>(
                    wB + (size_t)n * 128 + ks * 32 + lg * 8);
#pragma unroll
                for (int mt = 0; mt < 4; mt++)
                    acc[mt][nn] = __builtin_amdgcn_mfma_f32_16x16x32_bf16(
                        af[mt], bfr, acc[mt][nn], 0, 0, 0);
            }
        }
#pragma unroll
        for (int nn = 0; nn < 2; nn++) {
            int cg = (wv * 2 + nn) * 16 + l15;
            float bv = bias[cg];
#pragma unroll
            for (int mt = 0; mt < 4; mt++)
#pragma unroll
                for (int i = 0; i < 4; i++) {
                    size_t pix = p0 + mt * 16 + lg * 4 + i;
                    outQ[pix * 128 + cg] = f2bf((acc[mt][nn][i] + bv) * SCALE);
                }
        }
    } else {
        // kv path: N=256, NPW=4, nOff=128
        f32x4 acc[4][4];
#pragma unroll
        for (int mt = 0; mt < 4; mt++)
#pragma unroll
            for (int nn = 0; nn < 4; nn++)
                acc[mt][nn] = (f32x4){0.f, 0.f, 0.f, 0.f};
#pragma unroll
        for (int ks = 0; ks < 4; ks++) {
            bf16x8 af[4];
#pragma unroll
            for (int mt = 0; mt < 4; mt++)
                af[mt] = *reinterpret_cast<const bf16x8*>(
                    ash + (mt * 16 + l15) * 272 + ks * 64 + lg * 16);
#pragma unroll
            for (int nn = 0; nn < 4; nn++) {
                int n = 128 + (wv * 4 + nn) * 16 + l15;
                bf16x8 bfr = *reinterpret_cast<const bf16x8*>(
                    wB + (size_t)n * 128 + ks * 32 + lg * 8);
#pragma unroll
                for (int mt = 0; mt < 4; mt++)
                    acc[mt][nn] = __builtin_amdgcn_mfma_f32_16x16x32_bf16(
                        af[mt], bfr, acc[mt][nn], 0, 0, 0);
            }
        }
#pragma unroll
        for (int nn = 0; nn < 4; nn++) {
            int cg = (wv * 4 + nn) * 16 + l15;
            float bv = bias[128 + cg];
#pragma unroll
            for (int mt = 0; mt < 4; mt++)
#pragma unroll
                for (int i = 0; i < 4; i++) {
                    size_t pix = p0 + mt * 16 + lg * 4 + i;
                    outKV[pix * 256 + cg] = f2bf(acc[mt][nn][i] + bv);
                }
        }
    }
}

// -------- fp32 q_win/k_win projection; reduces rowsums (8 rows/window) on load
__global__ __launch_bounds__(256) void route_gemm_k(
        const float* __restrict__ rw1, const float* __restrict__ rw2,
        const float* __restrict__ qkv_w, const float* __restrict__ qkv_b,
        float* __restrict__ qwin, float* __restrict__ kwin) {
    __shared__ float msh[2][8][128];
    int b = blockIdx.y, wi = blockIdx.x;   // windows win = wi*8 + r
    int t = threadIdx.x;
    for (int i = t; i < 8 * 128; i += 256) {
        int r = i >> 7, c = i & 127;
        size_t off = (((size_t)(b * 8 + r) * 64) + wi * 8) * 128 + c;
        float s1 = 0.f, s2 = 0.f;
#pragma unroll
        for (int rr = 0; rr < 8; rr++) {
            s1 += rw1[off + rr * 128];
            s2 += rw2[off + rr * 128];
        }
        msh[0][r][c] = s1 * (1.f / 64.f);
        msh[1][r][c] = s2 * (1.f / 64.f);
    }
    __syncthreads();
    int c = t;
    int which = c >> 7;
    const float* wrow = qkv_w + (size_t)c * 128;
    float acc[8];
#pragma unroll
    for (int r = 0; r < 8; r++) acc[r] = 0.f;
    for (int k = 0; k < 128; k++) {
        float wv_ = wrow[k];
#pragma unroll
        for (int r = 0; r < 8; r++) acc[r] += msh[which][r][k] * wv_;
    }
    float bv = qkv_b[c];
#pragma unroll
    for (int r = 0; r < 8; r++) {
        size_t o = ((size_t)b * 64 + wi * 8 + r) * 128 + (c & 127);
        (which ? kwin : qwin)[o] = acc[r] + bv;
    }
}

// ------------------------------------------------ routing logits + top-16
__global__ __launch_bounds__(64) void route_k(const float* __restrict__ q_win,
                                              const float* __restrict__ k_win,
                                              int* __restrict__ r_idx) {
    int b = blockIdx.y, p = blockIdx.x, j = threadIdx.x;
    const float* qp = q_win + (size_t)(b * 64 + p) * 128;
    const float* kp = k_win + (size_t)(b * 64 + j) * 128;
    float lg = 0.f;
    for (int c = 0; c < 128; c++) lg += qp[c] * kp[c];
    lg *= SCALE;
    for (int it = 0; it < TOPK; it++) {
        float v = lg; int idx = j;
#pragma unroll
        for (int m = 32; m > 0; m >>= 1) {
            float ov = __shfl_xor(v, m, 64);
            int   oi = __shfl_xor(idx, m, 64);
            if (ov > v || (ov == v && oi < idx)) { v = ov; idx = oi; }
        }
        if (j == 0) r_idx[(size_t)(b * 64 + p) * TOPK + it] = idx;
        if (j == idx) lg = -__builtin_inff();
    }
}

// -------- pooling (K bf16 + v^T bf16) fused with v-plane transpose (vpl bf16)
__global__ __launch_bounds__(256) void pool_v_k(const ushort_t* __restrict__ kv,
                                                ushort_t* __restrict__ kb,
                                                ushort_t* __restrict__ kvpT,
                                                ushort_t* __restrict__ vpl) {
    int b = blockIdx.y, wdw = blockIdx.x;
    int wi = wdw >> 3, wj = wdw & 7;
    int t = threadIdx.x;
    if (t < 128) {
        float vals[16];
        for (int ry = 0; ry < 4; ry++)
            for (int rx = 0; rx < 4; rx++) {
                float s = 0.f;
                for (int fy = 0; fy < 2; fy++)
                    for (int fx = 0; fx < 2; fx++) {
                        int y = wi * 8 + ry * 2 + fy, x = wj * 8 + rx * 2 + fx;
                        s += bf2f(kv[((size_t)(b * H + y) * W + x) * 256 + t]);
                    }
                vals[ry * 4 + rx] = s * 0.25f;
            }
#pragma unroll
        for (int pos = 0; pos < 16; pos++)
            kb[(((size_t)(b * 64 + wdw)) * 16 + pos) * 128 + t] = f2bf(vals[pos]);
    } else {
        int c = t - 128;
        float ps[4][4];
#pragma unroll
        for (int i = 0; i < 4; i++)
#pragma unroll
            for (int j = 0; j < 4; j++) ps[i][j] = 0.f;
        for (int y = 0; y < 8; y++) {
            union { ushort_t u16[8]; uint4 u4; } raw;
#pragma unroll
            for (int x = 0; x < 8; x++) {
                raw.u16[x] = kv[((size_t)(b * H + wi * 8 + y) * W + wj * 8 + x) * 256 + 128 + c];
                ps[y >> 1][x >> 1] += bf2f(raw.u16[x]);
            }
            *reinterpret_cast<uint4*>(
                vpl + ((size_t)(b * C + c) * H + wi * 8 + y) * W + wj * 8) = raw.u4;
        }
        union { ushort_t u16[16]; uint4 u4[2]; } pk;
#pragma unroll
        for (int ry = 0; ry < 4; ry++)
#pragma unroll
            for (int rx = 0; rx < 4; rx++)
                pk.u16[ry * 4 + rx] = f2bf(ps[ry][rx] * 0.25f);
        size_t base = (((size_t)(b * 64 + wdw)) * 128 + c) * 16;
        *reinterpret_cast<uint4*>(kvpT + base) = pk.u4[0];
        *reinterpret_cast<uint4*>(kvpT + base + 8) = pk.u4[1];
    }
}

// ---------------- routed attention: staging-free, all frags direct from L2
__global__ __launch_bounds__(256) void attn_mfma_k(
        const ushort_t* __restrict__ qb,     // bf16 q*SCALE [B,H,W,128]
        const ushort_t* __restrict__ kb,     // bf16 [B,64,16,128]
        const ushort_t* __restrict__ kvpT,   // bf16 [B,64,128,16]
        const int* __restrict__ r_idx,
        ushort_t* __restrict__ o) {          // bf16 [pix][128]
    __shared__ int ridx_sh[16];
    __shared__ float denom_sh[4][32];

    int b = blockIdx.z, p = blockIdx.x, pair = blockIdx.y;
    int wi = p >> 3, wj = p & 7;
    int t = threadIdx.x;
    int lane = t & 63, wv = t >> 6;
    int l31 = lane & 31, hi = lane >> 5;

    if (t < 16) ridx_sh[t] = r_idx[(size_t)(b * 64 + p) * TOPK + t];
    __syncthreads();

    int hh = wv >> 1, qt = wv & 1;
    int h = pair * 2 + hh;

    int q = qt * 32 + l31;
    int qy = wi * 8 + (q >> 3), qx = wj * 8 + (q & 7);
    bf16x8 qf = *reinterpret_cast<const bf16x8*>(
        qb + ((size_t)(b * H + qy) * W + qx) * 128 + h * 16 + hi * 8);

    const ushort_t* kb_b = kb + (size_t)b * 64 * 16 * 128 + h * 16 + hi * 8;
    const ushort_t* vt_b = kvpT + (size_t)b * 64 * 128 * 16 + (h * 16 + (l31 & 15)) * 16 + hi * 8;

    float m_run = -INFINITY, l_run = 0.f;
    f32x16 opv;
#pragma unroll
    for (int r = 0; r < 16; r++) opv[r] = 0.f;
    f32x16 zf;
#pragma unroll
    for (int r = 0; r < 16; r++) zf[r] = 0.f;

    bf16x8 kf = *reinterpret_cast<const bf16x8*>(
        kb_b + ((size_t)ridx_sh[l31 >> 4] * 16 + (l31 & 15)) * 128);
    bf16x8 v0 = *reinterpret_cast<const bf16x8*>(vt_b + (size_t)ridx_sh[0] * 2048);
    bf16x8 v1 = *reinterpret_cast<const bf16x8*>(vt_b + (size_t)ridx_sh[1] * 2048);

    for (int t8 = 0; t8 < 8; t8++) {
        bf16x8 kfn = kf, v0n = v0, v1n = v1;
        if (t8 < 7) {
            kfn = *reinterpret_cast<const bf16x8*>(
                kb_b + ((size_t)ridx_sh[2 * t8 + 2 + (l31 >> 4)] * 16 + (l31 & 15)) * 128);
            v0n = *reinterpret_cast<const bf16x8*>(vt_b + (size_t)ridx_sh[2 * t8 + 2] * 2048);
            v1n = *reinterpret_cast<const bf16x8*>(vt_b + (size_t)ridx_sh[2 * t8 + 3] * 2048);
        }
        f32x16 S = __builtin_amdgcn_mfma_f32_32x32x16_bf16(kf, qf, zf, 0, 0, 0);
        float tm = S[0];
#pragma unroll
        for (int r = 1; r < 16; r++) tm = fmaxf(tm, S[r]);
        tm = fmaxf(tm, __shfl_xor(tm, 32, 64));
        float m_new = fmaxf(m_run, tm);
        float corr = __expf(m_run - m_new);
        float p_[16], psum = 0.f;
#pragma unroll
        for (int r = 0; r < 16; r++) { p_[r] = __expf(S[r] - m_new); psum += p_[r]; }
        psum += __shfl_xor(psum, 32, 64);
        l_run = l_run * corr + psum;
        m_run = m_new;
#pragma unroll
        for (int r = 0; r < 16; r++) opv[r] *= corr;
        unsigned w_[8], pw_[8];
#pragma unroll
        for (int j = 0; j < 8; j++)
            w_[j] = (__float_as_uint(p_[2 * j]) >> 16) |
                    (__float_as_uint(p_[2 * j + 1]) & 0xFFFF0000u);
#pragma unroll
        for (int j = 0; j < 8; j++) pw_[j] = __shfl_xor(w_[j], 32, 64);
        union { unsigned u[4]; bf16x8 v; } fa0, fa1;
        fa0.u[0] = hi ? pw_[2] : w_[0];
        fa0.u[1] = hi ? pw_[3] : w_[1];
        fa0.u[2] = hi ? w_[2]  : pw_[0];
        fa0.u[3] = hi ? w_[3]  : pw_[1];
        fa1.u[0] = hi ? pw_[6] : w_[4];
        fa1.u[1] = hi ? pw_[7] : w_[5];
        fa1.u[2] = hi ? w_[6]  : pw_[4];
        fa1.u[3] = hi ? w_[7]  : pw_[5];
        opv = __builtin_amdgcn_mfma_f32_32x32x16_bf16(fa0.v, v0, opv, 0, 0, 0);
        opv = __builtin_amdgcn_mfma_f32_32x32x16_bf16(fa1.v, v1, opv, 0, 0, 0);
        kf = kfn; v0 = v0n; v1 = v1n;
    }
    denom_sh[wv][l31] = l_run;
    if (l31 < 16) {
#pragma unroll
        for (int r = 0; r < 16; r++) {
            int qr = (r & 3) + 8 * (r >> 2) + 4 * hi;
            float invd = 1.f / denom_sh[wv][qr];
            int qq = qt * 32 + qr;
            int y = wi * 8 + (qq >> 3), x = wj * 8 + (qq & 7);
            o[((size_t)(b * H + y) * W + x) * 128 + h * 16 + l31] = f2bf(opv[r] * invd);
        }
    }
}

// ------------------ LePE depthwise 5x5 on bf16 planes, LDS-tiled, bf16 out
__global__ __launch_bounds__(256) void lepe_plane_k(const ushort_t* __restrict__ vpl,
                                                    const float* __restrict__ w,
                                                    const float* __restrict__ bias,
                                                    ushort_t* __restrict__ lep) {
    __shared__ float tile[68][69];
    int c = blockIdx.x, b = blockIdx.y;
    int t = threadIdx.x;
    const ushort_t* plane = vpl + (size_t)(b * C + c) * 4096;
    for (int e = t; e < 68 * 68; e += 256) {
        int row = e / 68, col = e - row * 68;
        int gy = row - 2, gx = col - 2;
        tile[row][col] = (gy >= 0 && gy < 64 && gx >= 0 && gx < 64)
                         ? bf2f(plane[gy * 64 + gx]) : 0.f;
    }
    float wv[25];
#pragma unroll
    for (int j = 0; j < 25; j++) wv[j] = w[c * 25 + j];
    float bb = bias[c];
    __syncthreads();
    int y = t >> 2, x0 = (t & 3) * 16;
    float acc[16];
#pragma unroll
    for (int i = 0; i < 16; i++) acc[i] = bb;
#pragma unroll
    for (int dy = 0; dy < 5; dy++) {
        float vals[20];
#pragma unroll
        for (int j = 0; j < 20; j++) vals[j] = tile[y + dy][x0 + j];
#pragma unroll
        for (int dx = 0; dx < 5; dx++)
#pragma unroll
            for (int i = 0; i < 16; i++)
                acc[i] += vals[i + dx] * wv[dy * 5 + dx];
    }
    ushort_t* dst = lep + (size_t)(b * C + c) * 4096 + y * 64 + x0;
    union { ushort_t u16[16]; uint4 u4[2]; } pk;
#pragma unroll
    for (int i = 0; i < 16; i++) pk.u16[i] = f2bf(acc[i]);
    *reinterpret_cast<uint4*>(dst) = pk.u4[0];
    *reinterpret_cast<uint4*>(dst + 8) = pk.u4[1];
}

// ---- epilogue: ((o + lepe) @ Wo^T + b) + x, bf16 MFMA, NCHW store via LDS
__global__ __launch_bounds__(256) void epilogue_mfma_k(
        const ushort_t* __restrict__ o,      // bf16 [pix][128]
        const ushort_t* __restrict__ lep,    // bf16 planes [B][C][64][64]
        const ushort_t* __restrict__ xbuf,   // bf16 [pix][128]
        const ushort_t* __restrict__ woB,    // bf16 [128][128]
        const float* __restrict__ wo_b,
        float* __restrict__ out) {
    __shared__ __align__(16) unsigned char smem[128 * 68 * 4]; // 34816 B
    ushort_t* ash = (ushort_t*)smem;         // [64][136] bf16 (o+lep)
    float* res = (float*)smem;               // [128][68] fp32 (after MFMA)
    int t = threadIdx.x, lane = t & 63, wv = t >> 6;
    int bid = blockIdx.x;
    int b = bid >> 6, y = bid & 63;
    size_t p0 = (size_t)bid * 64;

#pragma unroll
    for (int k = 0; k < 4; k++) {
        int e = k * 256 + t;
        int c = e >> 3, xg = e & 7;
        union { uint4 u4; ushort_t u16[8]; } v;
        v.u4 = *reinterpret_cast<const uint4*>(
            lep + (((size_t)(b * C + c) * 64 + y) * 64) + xg * 8);
#pragma unroll
        for (int j = 0; j < 8; j++) ash[(xg * 8 + j) * 136 + c] = v.u16[j];
    }
    __syncthreads();
    {
        int x = t >> 2, sub = t & 3;
        const ushort_t* op = o + (p0 + x) * 128 + sub * 32;
        ushort_t* ap = ash + x * 136 + sub * 32;
#pragma unroll
        for (int jj = 0; jj < 4; jj++) {
            union { uint4 u4; ushort_t u16[8]; } ov, lv;
            ov.u4 = *reinterpret_cast<const uint4*>(op + jj * 8);
            lv.u4 = *reinterpret_cast<const uint4*>(ap + jj * 8);
#pragma unroll
            for (int j = 0; j < 8; j++)
                lv.u16[j] = f2bf(bf2f(ov.u16[j]) + bf2f(lv.u16[j]));
            *reinterpret_cast<uint4*>(ap + jj * 8) = lv.u4;
        }
    }
    __syncthreads();
    int l15 = lane & 15, lg = lane >> 4;
    f32x4 acc[4][2];
#pragma unroll
    for (int mt = 0; mt < 4; mt++)
#pragma unroll
        for (int nn = 0; nn < 2; nn++)
            acc[mt][nn] = (f32x4){0.f, 0.f, 0.f, 0.f};
#pragma unroll
    for (int ks = 0; ks < 4; ks++) {
        bf16x8 af[4];
#pragma unroll
        for (int mt = 0; mt < 4; mt++)
            af[mt] = *reinterpret_cast<const bf16x8*>(
                ash + (mt * 16 + l15) * 136 + ks * 32 + lg * 8);
#pragma unroll
        for (int nn = 0; nn < 2; nn++) {
            int n = (wv * 2 + nn) * 16 + l15;
            bf16x8 bfr = *reinterpret_cast<const bf16x8*>(
                woB + (size_t)n * 128 + ks * 32 + lg * 8);
#pragma unroll
            for (int mt = 0; mt < 4; mt++)
                acc[mt][nn] = __builtin_amdgcn_mfma_f32_16x16x32_bf16(
                    af[mt], bfr, acc[mt][nn], 0, 0, 0);
        }
    }
    __syncthreads();
#pragma unroll
    for (int nn = 0; nn < 2; nn++) {
        int n = (wv * 2 + nn) * 16 + l15;
        float wb = wo_b[n];
#pragma unroll
        for (int mt = 0; mt < 4; mt++)
#pragma unroll
            for (int i = 0; i < 4; i++) {
                int r = mt * 16 + lg * 4 + i;
                float xb = bf2f(xbuf[(p0 + r) * 128 + n]);
                res[n * 68 + r] = acc[mt][nn][i] + wb + xb;
            }
    }
    __syncthreads();
    {
        int c = t >> 1, x0 = (t & 1) * 32;
        float* dst = out + ((size_t)(b * C + c) * 64 + y) * 64 + x0;
#pragma unroll
        for (int gblk = 0; gblk < 8; gblk++)
            *reinterpret_cast<float4*>(dst + gblk * 4) =
                *reinterpret_cast<const float4*>(&res[c * 68 + x0 + gblk * 4]);
    }
}

extern "C" void kernel_launch(void* const* d_in, const int* in_sizes, int n_in,
                              void* d_out, int out_size, void* d_ws, size_t ws_size,
                              hipStream_t stream) {
    const float* t1      = (const float*)d_in[0];
    const float* t2      = (const float*)d_in[1];
    const float* pos_w   = (const float*)d_in[2];
    const float* pos_b   = (const float*)d_in[3];
    const float* cat_w   = (const float*)d_in[4];
    const float* cat_b   = (const float*)d_in[5];
    const float* ln_cat_g= (const float*)d_in[6];
    const float* ln_cat_b= (const float*)d_in[7];
    const float* ln1_g   = (const float*)d_in[8];
    const float* ln1_b   = (const float*)d_in[9];
    const float* qkv_w   = (const float*)d_in[10];
    const float* qkv_b   = (const float*)d_in[11];
    const float* lepe_w  = (const float*)d_in[12];
    const float* lepe_b  = (const float*)d_in[13];
    const float* wo_w    = (const float*)d_in[14];
    const float* wo_b    = (const float*)d_in[15];

    float* ws    = (float*)d_ws;
    float* t1c   = ws + OFF_T1C;
    float* t2c   = ws + OFF_T2C;
    ushort_t* xbuf = (ushort_t*)(ws + OFF_X);
    ushort_t* qbuf = (ushort_t*)(ws + OFF_QB);
    ushort_t* kvbuf= (ushort_t*)(ws + OFF_KV);
    ushort_t* kb   = (ushort_t*)(ws + OFF_KVP);
    float* rw1   = ws + OFF_RW1;
    float* rw2   = ws + OFF_RW2;
    ushort_t* kvpT = (ushort_t*)(ws + OFF_KVPT);
    float* qwin  = ws + OFF_QW;
    float* kwin  = ws + OFF_KW;
    int*   ridx  = (int*)(ws + OFF_RIDX);
    ushort_t* wcat2 = (ushort_t*)(ws + OFF_WCB);
    ushort_t* qkvB  = (ushort_t*)(ws + OFF_QKVB);
    ushort_t* woB   = (ushort_t*)(ws + OFF_WOB);
    ushort_t* obuf  = (ushort_t*)(ws + OFF_T1C);  // alias t1c (dead after ln_qkv q)
    ushort_t* vpl   = (ushort_t*)(ws + OFF_T2C);  // alias t2c (dead after ln_qkv kv)
    ushort_t* lep   = (ushort_t*)(ws + OFF_KV);   // alias kvbuf (dead after pool_v)
    float* out   = (float*)d_out;

    transpose_weights<<<dim3((36 * 8 * 128 * 8 + 255) / 256), 256, 0, stream>>>(
        qkv_w, wo_w, cat_w, qkvB, woB, wcat2);
    pos_conv_k<<<dim3(2, 4, 256), 256, 0, stream>>>(t1, t2, pos_w, pos_b, t1c, t2c);
    catconv_mfma_k<<<dim3(8, 8, 8), 512, 0, stream>>>(
        t1c, t2c, wcat2, cat_b, ln_cat_g, ln_cat_b, xbuf);
    ln_qkv_both_k<<<dim3(512, 2), 256, 0, stream>>>(
        t1c, t2c, ln1_g, ln1_b, qkvB, qkv_b, qbuf, kvbuf, rw1, rw2);
    route_gemm_k<<<dim3(8, B), 256, 0, stream>>>(rw1, rw2, qkv_w, qkv_b, qwin, kwin);
    route_k<<<dim3(64, B), 64, 0, stream>>>(qwin, kwin, ridx);
    pool_v_k<<<dim3(64, B), 256, 0, stream>>>(kvbuf, kb, kvpT, vpl);
    attn_mfma_k<<<dim3(64, 4, B), 256, 0, stream>>>(qbuf, kb, kvpT, ridx, obuf);
    lepe_plane_k<<<dim3(C, B), 256, 0, stream>>>(vpl, lepe_w, lepe_b, lep);
    epilogue_mfma_k<<<dim3(512), 256, 0, stream>>>(obuf, lep, xbuf, woB, wo_b, out);
}